// Round 6
// baseline (444.078 us; speedup 1.0000x reference)
//
#include <hip/hip_runtime.h>
#include <hip/hip_bf16.h>

#define NE 768
#define NH 12
#define HD 64
#define BB 4
#define TT 2048
#define ROWS (BB*TT)  // 8192

typedef __attribute__((ext_vector_type(8))) short bf16x8;
typedef __attribute__((ext_vector_type(4))) float f32x4;

__device__ __forceinline__ short f2bf(float f) {
  __hip_bfloat16 h = __float2bfloat16(f);
  union { __hip_bfloat16 h; short s; } u; u.h = h; return u.s;
}

__device__ __forceinline__ void gload16(const void* g, void* l) {
  __builtin_amdgcn_global_load_lds(
      (const __attribute__((address_space(1))) void*)g,
      (__attribute__((address_space(3))) void*)l,
      16, 0, 0);
}

// ---------------- weight convert + transpose: W[K][N] f32 -> Wt[N][K] bf16 ----
__global__ __launch_bounds__(256) void wtrans_kernel(
    const float* __restrict__ W, short* __restrict__ Wt, int K, int N) {
  __shared__ short tile[64 * 65];
  int k0 = blockIdx.x * 64, n0 = blockIdx.y * 64;
  int t = threadIdx.x;
#pragma unroll
  for (int p = 0; p < 16; ++p) {
    int idx = p * 256 + t;
    int r = idx >> 6, c = idx & 63;
    tile[r * 65 + c] = f2bf(W[(size_t)(k0 + r) * N + n0 + c]);
  }
  __syncthreads();
#pragma unroll
  for (int p = 0; p < 16; ++p) {
    int idx = p * 256 + t;
    int rr = idx >> 6, cc = idx & 63;
    Wt[(size_t)(n0 + rr) * K + k0 + cc] = tile[cc * 65 + rr];
  }
}

// ---------------- V transpose: qkv V-part -> Vt[bh][hd][tloc] bf16 ----------
__global__ __launch_bounds__(256) void vtrans_kernel(
    const short* __restrict__ qkv, short* __restrict__ vt) {
  __shared__ short tile[64 * 65];
  int bh = blockIdx.x;
  int b = bh / NH, h = bh % NH;
  int t0 = blockIdx.y * 64;
  int t = threadIdx.x;
#pragma unroll
  for (int p = 0; p < 16; ++p) {
    int idx = p * 256 + t;
    int r = idx >> 6, c = idx & 63;   // r = tloc, c = hd
    tile[r * 65 + c] =
        qkv[(size_t)(b * TT + t0 + r) * (3 * NE) + 2 * NE + h * HD + c];
  }
  __syncthreads();
#pragma unroll
  for (int p = 0; p < 16; ++p) {
    int idx = p * 256 + t;
    int rr = idx >> 6, cc = idx & 63; // rr = hd, cc = tloc
    vt[(size_t)bh * HD * TT + (size_t)rr * TT + t0 + cc] = tile[cc * 65 + rr];
  }
}

// ---------------- LayerNorm: fp32 in -> bf16 out, one wave per row ----------
__global__ __launch_bounds__(64) void ln_kernel(
    const float* __restrict__ x, const float* __restrict__ g,
    const float* __restrict__ b, short* __restrict__ out) {
  int row = blockIdx.x, l = threadIdx.x;
  const float* xr = x + (size_t)row * NE;
  float4 v[3];
  float s = 0.f, ss = 0.f;
#pragma unroll
  for (int i = 0; i < 3; ++i) {
    v[i] = *reinterpret_cast<const float4*>(xr + l * 4 + i * 256);
    s += v[i].x + v[i].y + v[i].z + v[i].w;
    ss += v[i].x * v[i].x + v[i].y * v[i].y + v[i].z * v[i].z + v[i].w * v[i].w;
  }
#pragma unroll
  for (int m = 1; m < 64; m <<= 1) {
    s += __shfl_xor(s, m);
    ss += __shfl_xor(ss, m);
  }
  float mu = s * (1.0f / NE);
  float var = ss * (1.0f / NE) - mu * mu;
  float rstd = rsqrtf(var + 1e-5f);
#pragma unroll
  for (int i = 0; i < 3; ++i) {
    float4 gv = *reinterpret_cast<const float4*>(g + l * 4 + i * 256);
    float4 bv = *reinterpret_cast<const float4*>(b + l * 4 + i * 256);
    short4 o;
    o.x = f2bf((v[i].x - mu) * rstd * gv.x + bv.x);
    o.y = f2bf((v[i].y - mu) * rstd * gv.y + bv.y);
    o.z = f2bf((v[i].z - mu) * rstd * gv.z + bv.z);
    o.w = f2bf((v[i].w - mu) * rstd * gv.w + bv.w);
    *reinterpret_cast<short4*>(out + (size_t)row * NE + l * 4 + i * 256) = o;
  }
}

// ---------------- GEMM 128x128: C = A[M][K] * Bt[N][K]^T + epi --------------
template <int EPI>
__global__ __launch_bounds__(256) void gemm_kernel(
    const short* __restrict__ A, const short* __restrict__ Bt,
    const float* __restrict__ bias, const float* __restrict__ resid,
    void* __restrict__ Cout, int M, int N, int K) {
  __shared__ short As[128 * 32];
  __shared__ short Bs[128 * 32];
  int t = threadIdx.x;
  int w = t >> 6, l = t & 63;
  int wr = w >> 1, wc = w & 1;
  int bn = blockIdx.x, bm = blockIdx.y;
  int lr = l & 15, lkb = (l >> 4) * 8;

  f32x4 acc[4][4];
#pragma unroll
  for (int i = 0; i < 4; ++i)
#pragma unroll
    for (int j = 0; j < 4; ++j) acc[i][j] = (f32x4){0.f, 0.f, 0.f, 0.f};

  const short* ga = A + (size_t)(bm * 128 + (t >> 2)) * K + (t & 3) * 8;
  const short* gb = Bt + (size_t)(bn * 128 + (t >> 2)) * K + (t & 3) * 8;
  short* lA = As + t * 8;
  short* lB = Bs + t * 8;
  int nk = K >> 5;
  for (int kt = 0; kt < nk; ++kt) {
    __syncthreads();
    gload16(ga, lA);
    gload16(ga + (size_t)64 * K, lA + 64 * 32);
    gload16(gb, lB);
    gload16(gb + (size_t)64 * K, lB + 64 * 32);
    ga += 32; gb += 32;
    __syncthreads();
    bf16x8 af[4], bfr[4];
#pragma unroll
    for (int i = 0; i < 4; ++i)
      af[i] = *reinterpret_cast<const bf16x8*>(As + (wr * 64 + i * 16 + lr) * 32 + lkb);
#pragma unroll
    for (int j = 0; j < 4; ++j)
      bfr[j] = *reinterpret_cast<const bf16x8*>(Bs + (wc * 64 + j * 16 + lr) * 32 + lkb);
#pragma unroll
    for (int i = 0; i < 4; ++i)
#pragma unroll
      for (int j = 0; j < 4; ++j)
        acc[i][j] = __builtin_amdgcn_mfma_f32_16x16x32_bf16(af[i], bfr[j], acc[i][j], 0, 0, 0);
  }

  int rbase = bm * 128 + wr * 64;
  int cbase = bn * 128 + wc * 64;
#pragma unroll
  for (int i = 0; i < 4; ++i) {
#pragma unroll
    for (int r = 0; r < 4; ++r) {
      int row = rbase + i * 16 + (l >> 4) * 4 + r;
#pragma unroll
      for (int j = 0; j < 4; ++j) {
        int col = cbase + j * 16 + lr;
        float v = acc[i][j][r] + bias[col];
        if (EPI == 0) {
          ((short*)Cout)[(size_t)row * N + col] = f2bf(v);
        } else if (EPI == 1) {
          v = 0.5f * v * (1.0f + erff(v * 0.70710678118654752f));
          ((short*)Cout)[(size_t)row * N + col] = f2bf(v);
        } else {
          ((float*)Cout)[(size_t)row * N + col] = v + resid[(size_t)row * N + col];
        }
      }
    }
  }
}

// ---------------- GEMM 128x64 (for thin-N): 4 waves x (32 rows x 64 cols) ---
template <int EPI>
__global__ __launch_bounds__(256) void gemm64_kernel(
    const short* __restrict__ A, const short* __restrict__ Bt,
    const float* __restrict__ bias, const float* __restrict__ resid,
    void* __restrict__ Cout, int M, int N, int K) {
  __shared__ short As[128 * 32];
  __shared__ short Bs[64 * 32];
  int t = threadIdx.x;
  int w = t >> 6, l = t & 63;
  int bn = blockIdx.x, bm = blockIdx.y;
  int lr = l & 15, lkb = (l >> 4) * 8;

  f32x4 acc[2][4];
#pragma unroll
  for (int i = 0; i < 2; ++i)
#pragma unroll
    for (int j = 0; j < 4; ++j) acc[i][j] = (f32x4){0.f, 0.f, 0.f, 0.f};

  const short* ga = A + (size_t)(bm * 128 + (t >> 2)) * K + (t & 3) * 8;
  const short* gb = Bt + (size_t)(bn * 64 + (t >> 2)) * K + (t & 3) * 8;
  short* lA = As + t * 8;
  short* lB = Bs + t * 8;  // 256 threads x 16B = 64 rows x 32
  int nk = K >> 5;
  for (int kt = 0; kt < nk; ++kt) {
    __syncthreads();
    gload16(ga, lA);
    gload16(ga + (size_t)64 * K, lA + 64 * 32);
    gload16(gb, lB);
    ga += 32; gb += 32;
    __syncthreads();
    bf16x8 af[2], bfr[4];
#pragma unroll
    for (int i = 0; i < 2; ++i)
      af[i] = *reinterpret_cast<const bf16x8*>(As + (w * 32 + i * 16 + lr) * 32 + lkb);
#pragma unroll
    for (int j = 0; j < 4; ++j)
      bfr[j] = *reinterpret_cast<const bf16x8*>(Bs + (j * 16 + lr) * 32 + lkb);
#pragma unroll
    for (int i = 0; i < 2; ++i)
#pragma unroll
      for (int j = 0; j < 4; ++j)
        acc[i][j] = __builtin_amdgcn_mfma_f32_16x16x32_bf16(af[i], bfr[j], acc[i][j], 0, 0, 0);
  }

  int rbase = bm * 128 + w * 32;
  int cbase = bn * 64;
#pragma unroll
  for (int i = 0; i < 2; ++i) {
#pragma unroll
    for (int r = 0; r < 4; ++r) {
      int row = rbase + i * 16 + (l >> 4) * 4 + r;
#pragma unroll
      for (int j = 0; j < 4; ++j) {
        int col = cbase + j * 16 + lr;
        float v = acc[i][j][r] + bias[col];
        if (EPI == 0) {
          ((short*)Cout)[(size_t)row * N + col] = f2bf(v);
        } else if (EPI == 1) {
          v = 0.5f * v * (1.0f + erff(v * 0.70710678118654752f));
          ((short*)Cout)[(size_t)row * N + col] = f2bf(v);
        } else {
          ((float*)Cout)[(size_t)row * N + col] = v + resid[(size_t)row * N + col];
        }
      }
    }
  }
}

// ---------------- causal flash attention, LDS-free, L2-resident K/V ---------
// 4 independent waves per block (no barriers). Swapped QK^T, in-register
// softmax with defer-rescale, shfl-built P fragments.
// qkv: [ROWS][3*NE] bf16. vt: [48][HD][TT] bf16 (V transposed). y: [ROWS][NE].
__global__ __launch_bounds__(256) void attn_kernel(
    const short* __restrict__ qkv, const short* __restrict__ vt,
    short* __restrict__ y) {
  int t = threadIdx.x, w = t >> 6, l = t & 63;
  int lr = l & 15, g = l >> 4, lkb = g * 8;
  int bh = blockIdx.x;               // XCD = bh % 8 (gridDim.x = 48 ≡ 0 mod 8)
  int b = bh / NH, h = bh % NH;
  int qt = ((int)gridDim.y - 1) - blockIdx.y;   // longest blocks first
  int qbase = qt * 64;
  const int rstride = 3 * NE;

  // Q fragments (B-operand: col=qrow, k=hd): rows qbase + w*16 + lr
  const short* qrow = qkv + (size_t)(b * TT + qbase + w * 16 + lr) * rstride + h * HD + lkb;
  bf16x8 qf0 = *reinterpret_cast<const bf16x8*>(qrow);
  bf16x8 qf1 = *reinterpret_cast<const bf16x8*>(qrow + 32);

  f32x4 o[4];
#pragma unroll
  for (int j = 0; j < 4; ++j) o[j] = (f32x4){0.f, 0.f, 0.f, 0.f};
  float m_run = -3e38f, l_run = 0.f;   // per-lane q-row: qbase + w*16 + lr

  const short* kbase = qkv + (size_t)(b * TT) * rstride + NE + h * HD;
  const short* vbase = vt + (size_t)bh * HD * TT;

  int qmin = qbase + w * 16;
  int srcA = ((g & 1) * 2) * 16 + lr;   // shfl src lanes for P-frag build
  int srcB = srcA + 16;
  bool ghi = (g >= 2);

  for (int kt = 0; kt <= qt; ++kt) {
    int kvbase = kt * 64;

    // --- load K fragments (L2-hot, coalesced b128) ---
    bf16x8 kf[4][2];
#pragma unroll
    for (int nt = 0; nt < 4; ++nt) {
      const short* kp = kbase + (size_t)(kvbase + nt * 16 + lr) * rstride;
      kf[nt][0] = *reinterpret_cast<const bf16x8*>(kp + lkb);
      kf[nt][1] = *reinterpret_cast<const bf16x8*>(kp + 32 + lkb);
    }
    // --- load V^T fragments (independent of K path; issues early) ---
    bf16x8 vf[2][4];
#pragma unroll
    for (int c = 0; c < 2; ++c)
#pragma unroll
      for (int j = 0; j < 4; ++j)
        vf[c][j] = *reinterpret_cast<const bf16x8*>(
            vbase + (size_t)(j * 16 + lr) * TT + kvbase + c * 32 + lkb);

    // --- QK^T (swapped): s[nt][r] = S^T[kpos=kvbase+nt*16+g*4+r][qrow=lr]
    f32x4 s[4];
#pragma unroll
    for (int nt = 0; nt < 4; ++nt) {
      f32x4 st = (f32x4){0.f, 0.f, 0.f, 0.f};
      st = __builtin_amdgcn_mfma_f32_16x16x32_bf16(kf[nt][0], qf0, st, 0, 0, 0);
      st = __builtin_amdgcn_mfma_f32_16x16x32_bf16(kf[nt][1], qf1, st, 0, 0, 0);
      s[nt] = st;
    }

    // --- mask/scale ---
    if (kvbase + 63 > qmin) {   // diagonal tile
      int qabs = qmin + lr;
#pragma unroll
      for (int nt = 0; nt < 4; ++nt)
#pragma unroll
        for (int r = 0; r < 4; ++r) {
          int kp = kvbase + nt * 16 + g * 4 + r;
          s[nt][r] = (kp <= qabs) ? s[nt][r] * 0.125f : -3e38f;
        }
    } else {
#pragma unroll
      for (int nt = 0; nt < 4; ++nt)
#pragma unroll
        for (int r = 0; r < 4; ++r)
          s[nt][r] *= 0.125f;
    }

    // --- online softmax, in-register, defer-rescale (T13, THR=8) ---
    float mx = s[0][0];
#pragma unroll
    for (int nt = 0; nt < 4; ++nt)
#pragma unroll
      for (int r = 0; r < 4; ++r) mx = fmaxf(mx, s[nt][r]);
    mx = fmaxf(mx, __shfl_xor(mx, 16));
    mx = fmaxf(mx, __shfl_xor(mx, 32));
    if (__any(mx > m_run + 8.f)) {
      float mn = fmaxf(m_run, mx);
      float al = __expf(m_run - mn);
      m_run = mn;
      l_run *= al;
      float al0 = __shfl(al, g * 4 + 0);
      float al1 = __shfl(al, g * 4 + 1);
      float al2 = __shfl(al, g * 4 + 2);
      float al3 = __shfl(al, g * 4 + 3);
#pragma unroll
      for (int j = 0; j < 4; ++j) {
        o[j][0] *= al0; o[j][1] *= al1; o[j][2] *= al2; o[j][3] *= al3;
      }
    }
    float rs = 0.f;
#pragma unroll
    for (int nt = 0; nt < 4; ++nt)
#pragma unroll
      for (int r = 0; r < 4; ++r) {
        float p = __expf(s[nt][r] - m_run);
        s[nt][r] = p;
        rs += p;
      }
    rs += __shfl_xor(rs, 16);
    rs += __shfl_xor(rs, 32);
    l_run += rs;

    // --- pack P to bf16 pairs ---
    unsigned int pw[4][2];
#pragma unroll
    for (int nt = 0; nt < 4; ++nt)
#pragma unroll
      for (int pr = 0; pr < 2; ++pr)
        pw[nt][pr] = (unsigned int)(unsigned short)f2bf(s[nt][2 * pr]) |
                     ((unsigned int)(unsigned short)f2bf(s[nt][2 * pr + 1]) << 16);

    // --- PV: build P A-frag per 32-k chunk via shfl, then MFMA ---
#pragma unroll
    for (int c = 0; c < 2; ++c) {
      unsigned int a00 = __shfl(pw[c * 2 + 0][0], srcA);
      unsigned int a01 = __shfl(pw[c * 2 + 0][1], srcA);
      unsigned int a02 = __shfl(pw[c * 2 + 0][0], srcB);
      unsigned int a03 = __shfl(pw[c * 2 + 0][1], srcB);
      unsigned int a10 = __shfl(pw[c * 2 + 1][0], srcA);
      unsigned int a11 = __shfl(pw[c * 2 + 1][1], srcA);
      unsigned int a12 = __shfl(pw[c * 2 + 1][0], srcB);
      unsigned int a13 = __shfl(pw[c * 2 + 1][1], srcB);
      unsigned int u0 = ghi ? a10 : a00;
      unsigned int u1 = ghi ? a11 : a01;
      unsigned int u2 = ghi ? a12 : a02;
      unsigned int u3 = ghi ? a13 : a03;
      bf16x8 pa;
      pa[0] = (short)(u0 & 0xffffu); pa[1] = (short)(u0 >> 16);
      pa[2] = (short)(u1 & 0xffffu); pa[3] = (short)(u1 >> 16);
      pa[4] = (short)(u2 & 0xffffu); pa[5] = (short)(u2 >> 16);
      pa[6] = (short)(u3 & 0xffffu); pa[7] = (short)(u3 >> 16);
#pragma unroll
      for (int j = 0; j < 4; ++j)
        o[j] = __builtin_amdgcn_mfma_f32_16x16x32_bf16(pa, vf[c][j], o[j], 0, 0, 0);
    }
  }

  // --- epilogue: normalize (inv at lane (row); o rows are g*4+r) ---
  float inv = 1.0f / l_run;
  float i0 = __shfl(inv, g * 4 + 0);
  float i1 = __shfl(inv, g * 4 + 1);
  float i2 = __shfl(inv, g * 4 + 2);
  float i3 = __shfl(inv, g * 4 + 3);
#pragma unroll
  for (int r = 0; r < 4; ++r) {
    float ir = (r == 0) ? i0 : (r == 1) ? i1 : (r == 2) ? i2 : i3;
    size_t row = (size_t)(b * TT + qbase + w * 16 + g * 4 + r);
#pragma unroll
    for (int j = 0; j < 4; ++j)
      y[row * NE + h * HD + j * 16 + lr] = f2bf(o[j][r] * ir);
  }
}

extern "C" void kernel_launch(void* const* d_in, const int* in_sizes, int n_in,
                              void* d_out, int out_size, void* d_ws, size_t ws_size,
                              hipStream_t stream) {
  (void)in_sizes; (void)n_in; (void)out_size; (void)ws_size;
  const float* x       = (const float*)d_in[0];
  const float* ln1_g   = (const float*)d_in[1];
  const float* ln1_b   = (const float*)d_in[2];
  const float* w_attn  = (const float*)d_in[3];
  const float* b_attn  = (const float*)d_in[4];
  const float* w_aproj = (const float*)d_in[5];
  const float* b_aproj = (const float*)d_in[6];
  const float* ln2_g   = (const float*)d_in[7];
  const float* ln2_b   = (const float*)d_in[8];
  const float* w_fc    = (const float*)d_in[9];
  const float* b_fc    = (const float*)d_in[10];
  const float* w_mproj = (const float*)d_in[11];
  const float* b_mproj = (const float*)d_in[12];

  char* ws = (char*)d_ws;
  size_t off = 0;
  auto alloc = [&](size_t bytes) {
    char* p = ws + off;
    off += (bytes + 255) & ~(size_t)255;
    return p;
  };
  short* wt_attn  = (short*)alloc((size_t)2304 * 768 * 2);
  short* wt_aproj = (short*)alloc((size_t)768 * 768 * 2);
  short* wt_fc    = (short*)alloc((size_t)3072 * 768 * 2);
  short* wt_mproj = (short*)alloc((size_t)768 * 3072 * 2);
  short* lnb  = (short*)alloc((size_t)ROWS * 768 * 2);
  short* qkvb = (short*)alloc((size_t)ROWS * 3072 * 2);
  short* yb   = (short*)alloc((size_t)ROWS * 768 * 2);
  float* x2   = (float*)alloc((size_t)ROWS * 768 * 4);
  // vt aliases lnb: lnb (ln1 out) is dead after the qkv GEMM; ln2 rewrites it
  // after attention completes. Sizes match exactly (8192*768*2 B).
  short* vtg = lnb;

  wtrans_kernel<<<dim3(768 / 64, 2304 / 64), 256, 0, stream>>>(w_attn, wt_attn, 768, 2304);
  wtrans_kernel<<<dim3(768 / 64, 768 / 64), 256, 0, stream>>>(w_aproj, wt_aproj, 768, 768);
  wtrans_kernel<<<dim3(768 / 64, 3072 / 64), 256, 0, stream>>>(w_fc, wt_fc, 768, 3072);
  wtrans_kernel<<<dim3(3072 / 64, 768 / 64), 256, 0, stream>>>(w_mproj, wt_mproj, 3072, 768);

  ln_kernel<<<ROWS, 64, 0, stream>>>(x, ln1_g, ln1_b, lnb);
  gemm_kernel<0><<<dim3(2304 / 128, ROWS / 128), 256, 0, stream>>>(
      lnb, wt_attn, b_attn, nullptr, qkvb, ROWS, 2304, 768);
  vtrans_kernel<<<dim3(BB * NH, TT / 64), 256, 0, stream>>>(qkvb, vtg);
  attn_kernel<<<dim3(BB * NH, TT / 64), 256, 0, stream>>>(qkvb, vtg, yb);
  gemm64_kernel<2><<<dim3(768 / 64, ROWS / 128), 256, 0, stream>>>(
      yb, wt_aproj, b_aproj, x, x2, ROWS, 768, 768);
  ln_kernel<<<ROWS, 64, 0, stream>>>(x2, ln2_g, ln2_b, lnb);
  gemm_kernel<1><<<dim3(3072 / 128, ROWS / 128), 256, 0, stream>>>(
      lnb, wt_fc, b_fc, nullptr, qkvb, ROWS, 3072, 768);
  gemm64_kernel<2><<<dim3(768 / 64, ROWS / 128), 256, 0, stream>>>(
      qkvb, wt_mproj, b_mproj, x2, (float*)d_out, ROWS, 768, 3072);
}

// Round 7
// 343.075 us; speedup vs baseline: 1.2944x; 1.2944x over previous
//
#include <hip/hip_runtime.h>
#include <hip/hip_bf16.h>

#define NE 768
#define NH 12
#define HD 64
#define BB 4
#define TT 2048
#define ROWS (BB*TT)  // 8192

typedef __attribute__((ext_vector_type(8))) short bf16x8;
typedef __attribute__((ext_vector_type(4))) float f32x4;

__device__ __forceinline__ short f2bf(float f) {
  __hip_bfloat16 h = __float2bfloat16(f);
  union { __hip_bfloat16 h; short s; } u; u.h = h; return u.s;
}

__device__ __forceinline__ void gload16(const void* g, void* l) {
  __builtin_amdgcn_global_load_lds(
      (const __attribute__((address_space(1))) void*)g,
      (__attribute__((address_space(3))) void*)l,
      16, 0, 0);
}

// ---------------- weight convert + transpose: W[K][N] f32 -> Wt[N][K] bf16 ----
__global__ __launch_bounds__(256) void wtrans_kernel(
    const float* __restrict__ W, short* __restrict__ Wt, int K, int N) {
  __shared__ short tile[64 * 65];
  int k0 = blockIdx.x * 64, n0 = blockIdx.y * 64;
  int t = threadIdx.x;
#pragma unroll
  for (int p = 0; p < 16; ++p) {
    int idx = p * 256 + t;
    int r = idx >> 6, c = idx & 63;
    tile[r * 65 + c] = f2bf(W[(size_t)(k0 + r) * N + n0 + c]);
  }
  __syncthreads();
#pragma unroll
  for (int p = 0; p < 16; ++p) {
    int idx = p * 256 + t;
    int rr = idx >> 6, cc = idx & 63;
    Wt[(size_t)(n0 + rr) * K + k0 + cc] = tile[cc * 65 + rr];
  }
}

// ---------------- V transpose: qkv V-part -> Vt[bh][hd][tloc] bf16 ----------
__global__ __launch_bounds__(256) void vtrans_kernel(
    const short* __restrict__ qkv, short* __restrict__ vt) {
  __shared__ short tile[64 * 65];
  int bh = blockIdx.x;
  int b = bh / NH, h = bh % NH;
  int t0 = blockIdx.y * 64;
  int t = threadIdx.x;
#pragma unroll
  for (int p = 0; p < 16; ++p) {
    int idx = p * 256 + t;
    int r = idx >> 6, c = idx & 63;   // r = tloc, c = hd
    tile[r * 65 + c] =
        qkv[(size_t)(b * TT + t0 + r) * (3 * NE) + 2 * NE + h * HD + c];
  }
  __syncthreads();
#pragma unroll
  for (int p = 0; p < 16; ++p) {
    int idx = p * 256 + t;
    int rr = idx >> 6, cc = idx & 63; // rr = hd, cc = tloc
    vt[(size_t)bh * HD * TT + (size_t)rr * TT + t0 + cc] = tile[cc * 65 + rr];
  }
}

// ---------------- LayerNorm: fp32 in -> bf16 out, one wave per row ----------
__global__ __launch_bounds__(64) void ln_kernel(
    const float* __restrict__ x, const float* __restrict__ g,
    const float* __restrict__ b, short* __restrict__ out) {
  int row = blockIdx.x, l = threadIdx.x;
  const float* xr = x + (size_t)row * NE;
  float4 v[3];
  float s = 0.f, ss = 0.f;
#pragma unroll
  for (int i = 0; i < 3; ++i) {
    v[i] = *reinterpret_cast<const float4*>(xr + l * 4 + i * 256);
    s += v[i].x + v[i].y + v[i].z + v[i].w;
    ss += v[i].x * v[i].x + v[i].y * v[i].y + v[i].z * v[i].z + v[i].w * v[i].w;
  }
#pragma unroll
  for (int m = 1; m < 64; m <<= 1) {
    s += __shfl_xor(s, m);
    ss += __shfl_xor(ss, m);
  }
  float mu = s * (1.0f / NE);
  float var = ss * (1.0f / NE) - mu * mu;
  float rstd = rsqrtf(var + 1e-5f);
#pragma unroll
  for (int i = 0; i < 3; ++i) {
    float4 gv = *reinterpret_cast<const float4*>(g + l * 4 + i * 256);
    float4 bv = *reinterpret_cast<const float4*>(b + l * 4 + i * 256);
    short4 o;
    o.x = f2bf((v[i].x - mu) * rstd * gv.x + bv.x);
    o.y = f2bf((v[i].y - mu) * rstd * gv.y + bv.y);
    o.z = f2bf((v[i].z - mu) * rstd * gv.z + bv.z);
    o.w = f2bf((v[i].w - mu) * rstd * gv.w + bv.w);
    *reinterpret_cast<short4*>(out + (size_t)row * NE + l * 4 + i * 256) = o;
  }
}

// ---------------- GEMM 128x128, BK=64: C = A[M][K] * Bt[N][K]^T + epi -------
template <int EPI>
__global__ __launch_bounds__(256) void gemm_kernel(
    const short* __restrict__ A, const short* __restrict__ Bt,
    const float* __restrict__ bias, const float* __restrict__ resid,
    void* __restrict__ Cout, int M, int N, int K) {
  __shared__ short As[128 * 64];
  __shared__ short Bs[128 * 64];
  int t = threadIdx.x;
  int w = t >> 6, l = t & 63;
  int wr = w >> 1, wc = w & 1;
  int bn = blockIdx.x, bm = blockIdx.y;
  int lr = l & 15, lkb = (l >> 4) * 8;

  f32x4 acc[4][4];
#pragma unroll
  for (int i = 0; i < 4; ++i)
#pragma unroll
    for (int j = 0; j < 4; ++j) acc[i][j] = (f32x4){0.f, 0.f, 0.f, 0.f};

  const short* ga = A + (size_t)(bm * 128 + (t >> 3)) * K + (t & 7) * 8;
  const short* gb = Bt + (size_t)(bn * 128 + (t >> 3)) * K + (t & 7) * 8;
  short* lA = As + t * 8;
  short* lB = Bs + t * 8;
  int nk = K >> 6;
  for (int kt = 0; kt < nk; ++kt) {
    __syncthreads();
#pragma unroll
    for (int p = 0; p < 4; ++p) {
      gload16(ga + (size_t)(p * 32) * K, lA + p * 2048);
      gload16(gb + (size_t)(p * 32) * K, lB + p * 2048);
    }
    ga += 64; gb += 64;
    __syncthreads();
#pragma unroll
    for (int kc = 0; kc < 2; ++kc) {
      bf16x8 af[4], bfr[4];
#pragma unroll
      for (int i = 0; i < 4; ++i)
        af[i] = *reinterpret_cast<const bf16x8*>(
            As + (wr * 64 + i * 16 + lr) * 64 + kc * 32 + lkb);
#pragma unroll
      for (int j = 0; j < 4; ++j)
        bfr[j] = *reinterpret_cast<const bf16x8*>(
            Bs + (wc * 64 + j * 16 + lr) * 64 + kc * 32 + lkb);
#pragma unroll
      for (int i = 0; i < 4; ++i)
#pragma unroll
        for (int j = 0; j < 4; ++j)
          acc[i][j] = __builtin_amdgcn_mfma_f32_16x16x32_bf16(af[i], bfr[j], acc[i][j], 0, 0, 0);
    }
  }

  int rbase = bm * 128 + wr * 64;
  int cbase = bn * 128 + wc * 64;
#pragma unroll
  for (int i = 0; i < 4; ++i) {
#pragma unroll
    for (int r = 0; r < 4; ++r) {
      int row = rbase + i * 16 + (l >> 4) * 4 + r;
#pragma unroll
      for (int j = 0; j < 4; ++j) {
        int col = cbase + j * 16 + lr;
        float v = acc[i][j][r] + bias[col];
        if (EPI == 0) {
          ((short*)Cout)[(size_t)row * N + col] = f2bf(v);
        } else if (EPI == 1) {
          v = 0.5f * v * (1.0f + erff(v * 0.70710678118654752f));
          ((short*)Cout)[(size_t)row * N + col] = f2bf(v);
        } else {
          ((float*)Cout)[(size_t)row * N + col] = v + resid[(size_t)row * N + col];
        }
      }
    }
  }
}

// ---------------- GEMM 128x64, BK=64 (thin-N): 4 waves x (32 x 64) ----------
template <int EPI>
__global__ __launch_bounds__(256) void gemm64_kernel(
    const short* __restrict__ A, const short* __restrict__ Bt,
    const float* __restrict__ bias, const float* __restrict__ resid,
    void* __restrict__ Cout, int M, int N, int K) {
  __shared__ short As[128 * 64];
  __shared__ short Bs[64 * 64];
  int t = threadIdx.x;
  int w = t >> 6, l = t & 63;
  int bn = blockIdx.x, bm = blockIdx.y;
  int lr = l & 15, lkb = (l >> 4) * 8;

  f32x4 acc[2][4];
#pragma unroll
  for (int i = 0; i < 2; ++i)
#pragma unroll
    for (int j = 0; j < 4; ++j) acc[i][j] = (f32x4){0.f, 0.f, 0.f, 0.f};

  const short* ga = A + (size_t)(bm * 128 + (t >> 3)) * K + (t & 7) * 8;
  const short* gb = Bt + (size_t)(bn * 64 + (t >> 3)) * K + (t & 7) * 8;
  short* lA = As + t * 8;
  short* lB = Bs + t * 8;
  int nk = K >> 6;
  for (int kt = 0; kt < nk; ++kt) {
    __syncthreads();
#pragma unroll
    for (int p = 0; p < 4; ++p)
      gload16(ga + (size_t)(p * 32) * K, lA + p * 2048);
#pragma unroll
    for (int p = 0; p < 2; ++p)
      gload16(gb + (size_t)(p * 32) * K, lB + p * 2048);
    ga += 64; gb += 64;
    __syncthreads();
#pragma unroll
    for (int kc = 0; kc < 2; ++kc) {
      bf16x8 af[2], bfr[4];
#pragma unroll
      for (int i = 0; i < 2; ++i)
        af[i] = *reinterpret_cast<const bf16x8*>(
            As + (w * 32 + i * 16 + lr) * 64 + kc * 32 + lkb);
#pragma unroll
      for (int j = 0; j < 4; ++j)
        bfr[j] = *reinterpret_cast<const bf16x8*>(
            Bs + (j * 16 + lr) * 64 + kc * 32 + lkb);
#pragma unroll
      for (int i = 0; i < 2; ++i)
#pragma unroll
        for (int j = 0; j < 4; ++j)
          acc[i][j] = __builtin_amdgcn_mfma_f32_16x16x32_bf16(af[i], bfr[j], acc[i][j], 0, 0, 0);
    }
  }

  int rbase = bm * 128 + w * 32;
  int cbase = bn * 64;
#pragma unroll
  for (int i = 0; i < 2; ++i) {
#pragma unroll
    for (int r = 0; r < 4; ++r) {
      int row = rbase + i * 16 + (l >> 4) * 4 + r;
#pragma unroll
      for (int j = 0; j < 4; ++j) {
        int col = cbase + j * 16 + lr;
        float v = acc[i][j][r] + bias[col];
        if (EPI == 0) {
          ((short*)Cout)[(size_t)row * N + col] = f2bf(v);
        } else if (EPI == 1) {
          v = 0.5f * v * (1.0f + erff(v * 0.70710678118654752f));
          ((short*)Cout)[(size_t)row * N + col] = f2bf(v);
        } else {
          ((float*)Cout)[(size_t)row * N + col] = v + resid[(size_t)row * N + col];
        }
      }
    }
  }
}

// ---------------- causal flash attention, QBLK=64, KVBLK=64, dbuf -----------
// K and pre-transposed V^T both staged via global_load_lds (swizzled source).
// Swapped QK^T + in-register softmax (defer-rescale) + shfl-built P frags.
// qkv: [ROWS][3*NE] bf16. vt: [48][HD][TT] bf16. y: [ROWS][NE] bf16.
__global__ __launch_bounds__(256, 4) void attn_kernel(
    const short* __restrict__ qkv, const short* __restrict__ vt,
    short* __restrict__ y) {
  __shared__ short Ks[2][64 * 64];   // [kpos][hd], XOR-swizzled
  __shared__ short Vs[2][64 * 64];   // [hd][kpos], XOR-swizzled
  int t = threadIdx.x, w = t >> 6, l = t & 63;
  int lr = l & 15, g = l >> 4, lkb = g * 8;
  int bh = blockIdx.x;               // XCD = bh % 8 (48 % 8 == 0)
  int b = bh / NH, h = bh % NH;
  int qt = ((int)gridDim.y - 1) - blockIdx.y;   // longest blocks first
  int qbase = qt * 64;
  const int rstride = 3 * NE;

  // Q fragments (B-operand: col=qrow, k=hd): rows qbase + w*16 + lr
  const short* qrow = qkv + (size_t)(b * TT + qbase + w * 16 + lr) * rstride + h * HD + lkb;
  bf16x8 qf0 = *reinterpret_cast<const bf16x8*>(qrow);
  bf16x8 qf1 = *reinterpret_cast<const bf16x8*>(qrow + 32);

  f32x4 o[4];
#pragma unroll
  for (int j = 0; j < 4; ++j) o[j] = (f32x4){0.f, 0.f, 0.f, 0.f};
  float m_run = -3e38f, l_run = 0.f;   // per-lane q-row: qbase + w*16 + lr

  // staging geometry: 16B chunk ids; row = id>>3, col pre-swizzled
  int ci0 = t, ci1 = t + 256;
  int row0 = ci0 >> 3, c0 = ((ci0 & 7) ^ (row0 & 7)) * 8;
  int row1 = ci1 >> 3, c1 = ((ci1 & 7) ^ (row1 & 7)) * 8;

  const short* kbase = qkv + (size_t)(b * TT) * rstride + NE + h * HD;
  const short* vtb = vt + (size_t)bh * HD * TT;

  // --- prologue: stage tile 0 into buffer 0 ---
  gload16(kbase + (size_t)row0 * rstride + c0, &Ks[0][ci0 * 8]);
  gload16(kbase + (size_t)row1 * rstride + c1, &Ks[0][ci1 * 8]);
  gload16(vtb + (size_t)row0 * TT + c0, &Vs[0][ci0 * 8]);
  gload16(vtb + (size_t)row1 * TT + c1, &Vs[0][ci1 * 8]);

  int qmin = qbase + w * 16;
  int srcA = ((g & 1) * 2) * 16 + lr;   // shfl src lanes for P-frag build
  int srcB = srcA + 16;
  bool ghi = (g >= 2);

  int nkv = qt + 1;
  for (int kt = 0; kt < nkv; ++kt) {
    int bi = kt & 1;
    int kvbase = kt * 64;
    bool pre = (kt + 1 < nkv);
    __syncthreads();   // buf bi ready (vmcnt drained by barrier)

    if (pre) {   // issue next tile's DMA (hides under this tile's compute)
      int nb = kvbase + 64;
      gload16(kbase + (size_t)(nb + row0) * rstride + c0, &Ks[bi ^ 1][ci0 * 8]);
      gload16(kbase + (size_t)(nb + row1) * rstride + c1, &Ks[bi ^ 1][ci1 * 8]);
      gload16(vtb + (size_t)row0 * TT + nb + c0, &Vs[bi ^ 1][ci0 * 8]);
      gload16(vtb + (size_t)row1 * TT + nb + c1, &Vs[bi ^ 1][ci1 * 8]);
    }

    // --- QK^T (swapped): s[nt][r] = S^T[kpos=kvbase+nt*16+g*4+r][qrow=lr]
    f32x4 s[4];
#pragma unroll
    for (int nt = 0; nt < 4; ++nt) {
      int row = nt * 16 + lr;
      bf16x8 kf0 = *reinterpret_cast<const bf16x8*>(
          (char*)Ks[bi] + ((row * 128 + lkb * 2) ^ ((lr & 7) << 4)));
      bf16x8 kf1 = *reinterpret_cast<const bf16x8*>(
          (char*)Ks[bi] + ((row * 128 + 64 + lkb * 2) ^ ((lr & 7) << 4)));
      f32x4 st = (f32x4){0.f, 0.f, 0.f, 0.f};
      st = __builtin_amdgcn_mfma_f32_16x16x32_bf16(kf0, qf0, st, 0, 0, 0);
      st = __builtin_amdgcn_mfma_f32_16x16x32_bf16(kf1, qf1, st, 0, 0, 0);
      s[nt] = st;
    }

    // --- mask/scale ---
    if (kvbase + 63 > qmin) {   // diagonal tile
      int qabs = qmin + lr;
#pragma unroll
      for (int nt = 0; nt < 4; ++nt)
#pragma unroll
        for (int r = 0; r < 4; ++r) {
          int kp = kvbase + nt * 16 + g * 4 + r;
          s[nt][r] = (kp <= qabs) ? s[nt][r] * 0.125f : -3e38f;
        }
    } else {
#pragma unroll
      for (int nt = 0; nt < 4; ++nt)
#pragma unroll
        for (int r = 0; r < 4; ++r)
          s[nt][r] *= 0.125f;
    }

    // --- online softmax, in-register, defer-rescale (T13, THR=8) ---
    float mx = s[0][0];
#pragma unroll
    for (int nt = 0; nt < 4; ++nt)
#pragma unroll
      for (int r = 0; r < 4; ++r) mx = fmaxf(mx, s[nt][r]);
    mx = fmaxf(mx, __shfl_xor(mx, 16));
    mx = fmaxf(mx, __shfl_xor(mx, 32));
    if (__any(mx > m_run + 8.f)) {
      float mn = fmaxf(m_run, mx);
      float al = __expf(m_run - mn);
      m_run = mn;
      l_run *= al;
      float al0 = __shfl(al, g * 4 + 0);
      float al1 = __shfl(al, g * 4 + 1);
      float al2 = __shfl(al, g * 4 + 2);
      float al3 = __shfl(al, g * 4 + 3);
#pragma unroll
      for (int j = 0; j < 4; ++j) {
        o[j][0] *= al0; o[j][1] *= al1; o[j][2] *= al2; o[j][3] *= al3;
      }
    }
    float rs = 0.f;
#pragma unroll
    for (int nt = 0; nt < 4; ++nt)
#pragma unroll
      for (int r = 0; r < 4; ++r) {
        float p = __expf(s[nt][r] - m_run);
        s[nt][r] = p;
        rs += p;
      }
    rs += __shfl_xor(rs, 16);
    rs += __shfl_xor(rs, 32);
    l_run += rs;

    // --- pack P to bf16 pairs ---
    unsigned int pw[4][2];
#pragma unroll
    for (int nt = 0; nt < 4; ++nt)
#pragma unroll
      for (int pr = 0; pr < 2; ++pr)
        pw[nt][pr] = (unsigned int)(unsigned short)f2bf(s[nt][2 * pr]) |
                     ((unsigned int)(unsigned short)f2bf(s[nt][2 * pr + 1]) << 16);

    // --- PV: build P A-frag per 32-k chunk via shfl, then MFMA ---
#pragma unroll
    for (int c = 0; c < 2; ++c) {
      unsigned int a00 = __shfl(pw[c * 2 + 0][0], srcA);
      unsigned int a01 = __shfl(pw[c * 2 + 0][1], srcA);
      unsigned int a02 = __shfl(pw[c * 2 + 0][0], srcB);
      unsigned int a03 = __shfl(pw[c * 2 + 0][1], srcB);
      unsigned int a10 = __shfl(pw[c * 2 + 1][0], srcA);
      unsigned int a11 = __shfl(pw[c * 2 + 1][1], srcA);
      unsigned int a12 = __shfl(pw[c * 2 + 1][0], srcB);
      unsigned int a13 = __shfl(pw[c * 2 + 1][1], srcB);
      unsigned int u0 = ghi ? a10 : a00;
      unsigned int u1 = ghi ? a11 : a01;
      unsigned int u2 = ghi ? a12 : a02;
      unsigned int u3 = ghi ? a13 : a03;
      bf16x8 pa;
      pa[0] = (short)(u0 & 0xffffu); pa[1] = (short)(u0 >> 16);
      pa[2] = (short)(u1 & 0xffffu); pa[3] = (short)(u1 >> 16);
      pa[4] = (short)(u2 & 0xffffu); pa[5] = (short)(u2 >> 16);
      pa[6] = (short)(u3 & 0xffffu); pa[7] = (short)(u3 >> 16);
#pragma unroll
      for (int j = 0; j < 4; ++j) {
        int vrow = j * 16 + lr;
        bf16x8 vf = *reinterpret_cast<const bf16x8*>(
            (char*)Vs[bi] + ((vrow * 128 + c * 64 + lkb * 2) ^ ((lr & 7) << 4)));
        o[j] = __builtin_amdgcn_mfma_f32_16x16x32_bf16(pa, vf, o[j], 0, 0, 0);
      }
    }
  }

  // --- epilogue: normalize (inv at lane (row); o rows are g*4+r) ---
  float inv = 1.0f / l_run;
  float i0 = __shfl(inv, g * 4 + 0);
  float i1 = __shfl(inv, g * 4 + 1);
  float i2 = __shfl(inv, g * 4 + 2);
  float i3 = __shfl(inv, g * 4 + 3);
#pragma unroll
  for (int r = 0; r < 4; ++r) {
    float ir = (r == 0) ? i0 : (r == 1) ? i1 : (r == 2) ? i2 : i3;
    size_t row = (size_t)(b * TT + qbase + w * 16 + g * 4 + r);
#pragma unroll
    for (int j = 0; j < 4; ++j)
      y[row * NE + h * HD + j * 16 + lr] = f2bf(o[j][r] * ir);
  }
}

extern "C" void kernel_launch(void* const* d_in, const int* in_sizes, int n_in,
                              void* d_out, int out_size, void* d_ws, size_t ws_size,
                              hipStream_t stream) {
  (void)in_sizes; (void)n_in; (void)out_size; (void)ws_size;
  const float* x       = (const float*)d_in[0];
  const float* ln1_g   = (const float*)d_in[1];
  const float* ln1_b   = (const float*)d_in[2];
  const float* w_attn  = (const float*)d_in[3];
  const float* b_attn  = (const float*)d_in[4];
  const float* w_aproj = (const float*)d_in[5];
  const float* b_aproj = (const float*)d_in[6];
  const float* ln2_g   = (const float*)d_in[7];
  const float* ln2_b   = (const float*)d_in[8];
  const float* w_fc    = (const float*)d_in[9];
  const float* b_fc    = (const float*)d_in[10];
  const float* w_mproj = (const float*)d_in[11];
  const float* b_mproj = (const float*)d_in[12];

  char* ws = (char*)d_ws;
  size_t off = 0;
  auto alloc = [&](size_t bytes) {
    char* p = ws + off;
    off += (bytes + 255) & ~(size_t)255;
    return p;
  };
  short* wt_attn  = (short*)alloc((size_t)2304 * 768 * 2);
  short* wt_aproj = (short*)alloc((size_t)768 * 768 * 2);
  short* wt_fc    = (short*)alloc((size_t)3072 * 768 * 2);
  short* wt_mproj = (short*)alloc((size_t)768 * 3072 * 2);
  short* lnb  = (short*)alloc((size_t)ROWS * 768 * 2);
  short* qkvb = (short*)alloc((size_t)ROWS * 3072 * 2);
  short* yb   = (short*)alloc((size_t)ROWS * 768 * 2);
  float* x2   = (float*)alloc((size_t)ROWS * 768 * 4);
  // vt aliases lnb: lnb (ln1 out) is dead after the qkv GEMM; ln2 rewrites it
  // after attention completes. Sizes match exactly (8192*768*2 B).
  short* vtg = lnb;

  wtrans_kernel<<<dim3(768 / 64, 2304 / 64), 256, 0, stream>>>(w_attn, wt_attn, 768, 2304);
  wtrans_kernel<<<dim3(768 / 64, 768 / 64), 256, 0, stream>>>(w_aproj, wt_aproj, 768, 768);
  wtrans_kernel<<<dim3(768 / 64, 3072 / 64), 256, 0, stream>>>(w_fc, wt_fc, 768, 3072);
  wtrans_kernel<<<dim3(3072 / 64, 768 / 64), 256, 0, stream>>>(w_mproj, wt_mproj, 3072, 768);

  ln_kernel<<<ROWS, 64, 0, stream>>>(x, ln1_g, ln1_b, lnb);
  gemm_kernel<0><<<dim3(2304 / 128, ROWS / 128), 256, 0, stream>>>(
      lnb, wt_attn, b_attn, nullptr, qkvb, ROWS, 2304, 768);
  vtrans_kernel<<<dim3(BB * NH, TT / 64), 256, 0, stream>>>(qkvb, vtg);
  attn_kernel<<<dim3(BB * NH, TT / 64), 256, 0, stream>>>(qkvb, vtg, yb);
  gemm64_kernel<2><<<dim3(768 / 64, ROWS / 128), 256, 0, stream>>>(
      yb, wt_aproj, b_aproj, x, x2, ROWS, 768, 768);
  ln_kernel<<<ROWS, 64, 0, stream>>>(x2, ln2_g, ln2_b, lnb);
  gemm_kernel<1><<<dim3(3072 / 128, ROWS / 128), 256, 0, stream>>>(
      lnb, wt_fc, b_fc, nullptr, qkvb, ROWS, 3072, 768);
  gemm64_kernel<2><<<dim3(768 / 64, ROWS / 128), 256, 0, stream>>>(
      qkvb, wt_mproj, b_mproj, x2, (float*)d_out, ROWS, 768, 3072);
}

// Round 8
// 318.613 us; speedup vs baseline: 1.3938x; 1.0768x over previous
//
#include <hip/hip_runtime.h>
#include <hip/hip_bf16.h>

#define NE 768
#define NH 12
#define HD 64
#define BB 4
#define TT 2048
#define ROWS (BB*TT)  // 8192

typedef __attribute__((ext_vector_type(8))) short bf16x8;
typedef __attribute__((ext_vector_type(4))) float f32x4;

__device__ __forceinline__ short f2bf(float f) {
  __hip_bfloat16 h = __float2bfloat16(f);
  union { __hip_bfloat16 h; short s; } u; u.h = h; return u.s;
}

__device__ __forceinline__ void gload16(const void* g, void* l) {
  __builtin_amdgcn_global_load_lds(
      (const __attribute__((address_space(1))) void*)g,
      (__attribute__((address_space(3))) void*)l,
      16, 0, 0);
}

// ---------------- weight convert + transpose: W[K][N] f32 -> Wt[N][K] bf16 ----
__global__ __launch_bounds__(256) void wtrans_kernel(
    const float* __restrict__ W, short* __restrict__ Wt, int K, int N) {
  __shared__ short tile[64 * 65];
  int k0 = blockIdx.x * 64, n0 = blockIdx.y * 64;
  int t = threadIdx.x;
#pragma unroll
  for (int p = 0; p < 16; ++p) {
    int idx = p * 256 + t;
    int r = idx >> 6, c = idx & 63;
    tile[r * 65 + c] = f2bf(W[(size_t)(k0 + r) * N + n0 + c]);
  }
  __syncthreads();
#pragma unroll
  for (int p = 0; p < 16; ++p) {
    int idx = p * 256 + t;
    int rr = idx >> 6, cc = idx & 63;
    Wt[(size_t)(n0 + rr) * K + k0 + cc] = tile[cc * 65 + rr];
  }
}

// ---------------- V transpose: qkv V-part -> Vt[bh][hd][tloc] bf16 ----------
__global__ __launch_bounds__(256) void vtrans_kernel(
    const short* __restrict__ qkv, short* __restrict__ vt) {
  __shared__ short tile[64 * 65];
  int bh = blockIdx.x;
  int b = bh / NH, h = bh % NH;
  int t0 = blockIdx.y * 64;
  int t = threadIdx.x;
#pragma unroll
  for (int p = 0; p < 16; ++p) {
    int idx = p * 256 + t;
    int r = idx >> 6, c = idx & 63;   // r = tloc, c = hd
    tile[r * 65 + c] =
        qkv[(size_t)(b * TT + t0 + r) * (3 * NE) + 2 * NE + h * HD + c];
  }
  __syncthreads();
#pragma unroll
  for (int p = 0; p < 16; ++p) {
    int idx = p * 256 + t;
    int rr = idx >> 6, cc = idx & 63; // rr = hd, cc = tloc
    vt[(size_t)bh * HD * TT + (size_t)rr * TT + t0 + cc] = tile[cc * 65 + rr];
  }
}

// ---------------- LayerNorm: fp32 in -> bf16 out, one wave per row ----------
__global__ __launch_bounds__(64) void ln_kernel(
    const float* __restrict__ x, const float* __restrict__ g,
    const float* __restrict__ b, short* __restrict__ out) {
  int row = blockIdx.x, l = threadIdx.x;
  const float* xr = x + (size_t)row * NE;
  float4 v[3];
  float s = 0.f, ss = 0.f;
#pragma unroll
  for (int i = 0; i < 3; ++i) {
    v[i] = *reinterpret_cast<const float4*>(xr + l * 4 + i * 256);
    s += v[i].x + v[i].y + v[i].z + v[i].w;
    ss += v[i].x * v[i].x + v[i].y * v[i].y + v[i].z * v[i].z + v[i].w * v[i].w;
  }
#pragma unroll
  for (int m = 1; m < 64; m <<= 1) {
    s += __shfl_xor(s, m);
    ss += __shfl_xor(ss, m);
  }
  float mu = s * (1.0f / NE);
  float var = ss * (1.0f / NE) - mu * mu;
  float rstd = rsqrtf(var + 1e-5f);
#pragma unroll
  for (int i = 0; i < 3; ++i) {
    float4 gv = *reinterpret_cast<const float4*>(g + l * 4 + i * 256);
    float4 bv = *reinterpret_cast<const float4*>(b + l * 4 + i * 256);
    short4 o;
    o.x = f2bf((v[i].x - mu) * rstd * gv.x + bv.x);
    o.y = f2bf((v[i].y - mu) * rstd * gv.y + bv.y);
    o.z = f2bf((v[i].z - mu) * rstd * gv.z + bv.z);
    o.w = f2bf((v[i].w - mu) * rstd * gv.w + bv.w);
    *reinterpret_cast<short4*>(out + (size_t)row * NE + l * 4 + i * 256) = o;
  }
}

// ---------------- GEMM 128x128, BK=32, double-buffered single-barrier -------
// LDS XOR-swizzled (pre-swizzled gload source + XOR'd read, involution).
template <int EPI>
__global__ __launch_bounds__(256) void gemm_kernel(
    const short* __restrict__ A, const short* __restrict__ Bt,
    const float* __restrict__ bias, const float* __restrict__ resid,
    void* __restrict__ Cout, int M, int N, int K) {
  __shared__ short As[2][128 * 32];
  __shared__ short Bs[2][128 * 32];
  int t = threadIdx.x;
  int w = t >> 6, l = t & 63;
  int wr = w >> 1, wc = w & 1;
  int bn = blockIdx.x, bm = blockIdx.y;
  int lr = l & 15, g4 = l >> 4;

  f32x4 acc[4][4];
#pragma unroll
  for (int i = 0; i < 4; ++i)
#pragma unroll
    for (int j = 0; j < 4; ++j) acc[i][j] = (f32x4){0.f, 0.f, 0.f, 0.f};

  // staging: chunk t -> row t>>2 (0..63), chunk t+256 -> row 64 + (t>>2)
  // swizzled source col (shorts): ((t&3) ^ ((t>>2)&3)) * 8  (same for both)
  int r0 = t >> 2;
  int cs = ((t & 3) ^ (r0 & 3)) * 8;
  const short* ga = A + (size_t)(bm * 128) * K;
  const short* gb = Bt + (size_t)(bn * 128) * K;

  // prologue: stage tile 0 into buffer 0
  gload16(ga + (size_t)r0 * K + cs, &As[0][t * 8]);
  gload16(ga + (size_t)(r0 + 64) * K + cs, &As[0][(t + 256) * 8]);
  gload16(gb + (size_t)r0 * K + cs, &Bs[0][t * 8]);
  gload16(gb + (size_t)(r0 + 64) * K + cs, &Bs[0][(t + 256) * 8]);

  int xorA = (lr & 3) << 4;   // read-side swizzle (row&3 == lr&3 for frag rows)
  int nk = K >> 5;
  for (int kt = 0; kt < nk; ++kt) {
    int bi = kt & 1;
    __syncthreads();   // buf bi ready (barrier drains vmcnt)
    if (kt + 1 < nk) { // issue next tile's DMA; lands during this compute
      int ko = (kt + 1) * 32;
      gload16(ga + (size_t)r0 * K + ko + cs, &As[bi ^ 1][t * 8]);
      gload16(ga + (size_t)(r0 + 64) * K + ko + cs, &As[bi ^ 1][(t + 256) * 8]);
      gload16(gb + (size_t)r0 * K + ko + cs, &Bs[bi ^ 1][t * 8]);
      gload16(gb + (size_t)(r0 + 64) * K + ko + cs, &Bs[bi ^ 1][(t + 256) * 8]);
    }
    const char* Ab = (const char*)As[bi];
    const char* Bb = (const char*)Bs[bi];
    bf16x8 af[4], bfr[4];
#pragma unroll
    for (int i = 0; i < 4; ++i)
      af[i] = *reinterpret_cast<const bf16x8*>(
          Ab + (((wr * 64 + i * 16 + lr) * 64 + g4 * 16) ^ xorA));
#pragma unroll
    for (int j = 0; j < 4; ++j)
      bfr[j] = *reinterpret_cast<const bf16x8*>(
          Bb + (((wc * 64 + j * 16 + lr) * 64 + g4 * 16) ^ xorA));
#pragma unroll
    for (int i = 0; i < 4; ++i)
#pragma unroll
      for (int j = 0; j < 4; ++j)
        acc[i][j] = __builtin_amdgcn_mfma_f32_16x16x32_bf16(af[i], bfr[j], acc[i][j], 0, 0, 0);
  }

  int rbase = bm * 128 + wr * 64;
  int cbase = bn * 128 + wc * 64;
#pragma unroll
  for (int i = 0; i < 4; ++i) {
#pragma unroll
    for (int r = 0; r < 4; ++r) {
      int row = rbase + i * 16 + g4 * 4 + r;
#pragma unroll
      for (int j = 0; j < 4; ++j) {
        int col = cbase + j * 16 + lr;
        float v = acc[i][j][r] + bias[col];
        if (EPI == 0) {
          ((short*)Cout)[(size_t)row * N + col] = f2bf(v);
        } else if (EPI == 1) {
          v = 0.5f * v * (1.0f + erff(v * 0.70710678118654752f));
          ((short*)Cout)[(size_t)row * N + col] = f2bf(v);
        } else {
          ((float*)Cout)[(size_t)row * N + col] = v + resid[(size_t)row * N + col];
        }
      }
    }
  }
}

// ---------------- GEMM 128x64, BK=32, dbuf (thin-N): 4 waves x (32 x 64) ----
template <int EPI>
__global__ __launch_bounds__(256) void gemm64_kernel(
    const short* __restrict__ A, const short* __restrict__ Bt,
    const float* __restrict__ bias, const float* __restrict__ resid,
    void* __restrict__ Cout, int M, int N, int K) {
  __shared__ short As[2][128 * 32];
  __shared__ short Bs[2][64 * 32];
  int t = threadIdx.x;
  int w = t >> 6, l = t & 63;
  int bn = blockIdx.x, bm = blockIdx.y;
  int lr = l & 15, g4 = l >> 4;

  f32x4 acc[2][4];
#pragma unroll
  for (int i = 0; i < 2; ++i)
#pragma unroll
    for (int j = 0; j < 4; ++j) acc[i][j] = (f32x4){0.f, 0.f, 0.f, 0.f};

  int r0 = t >> 2;
  int cs = ((t & 3) ^ (r0 & 3)) * 8;
  const short* ga = A + (size_t)(bm * 128) * K;
  const short* gb = Bt + (size_t)(bn * 64) * K;

  gload16(ga + (size_t)r0 * K + cs, &As[0][t * 8]);
  gload16(ga + (size_t)(r0 + 64) * K + cs, &As[0][(t + 256) * 8]);
  gload16(gb + (size_t)r0 * K + cs, &Bs[0][t * 8]);

  int xorA = (lr & 3) << 4;
  int nk = K >> 5;
  for (int kt = 0; kt < nk; ++kt) {
    int bi = kt & 1;
    __syncthreads();
    if (kt + 1 < nk) {
      int ko = (kt + 1) * 32;
      gload16(ga + (size_t)r0 * K + ko + cs, &As[bi ^ 1][t * 8]);
      gload16(ga + (size_t)(r0 + 64) * K + ko + cs, &As[bi ^ 1][(t + 256) * 8]);
      gload16(gb + (size_t)r0 * K + ko + cs, &Bs[bi ^ 1][t * 8]);
    }
    const char* Ab = (const char*)As[bi];
    const char* Bb = (const char*)Bs[bi];
    bf16x8 af[2], bfr[4];
#pragma unroll
    for (int i = 0; i < 2; ++i)
      af[i] = *reinterpret_cast<const bf16x8*>(
          Ab + (((w * 32 + i * 16 + lr) * 64 + g4 * 16) ^ xorA));
#pragma unroll
    for (int j = 0; j < 4; ++j)
      bfr[j] = *reinterpret_cast<const bf16x8*>(
          Bb + (((j * 16 + lr) * 64 + g4 * 16) ^ xorA));
#pragma unroll
    for (int i = 0; i < 2; ++i)
#pragma unroll
      for (int j = 0; j < 4; ++j)
        acc[i][j] = __builtin_amdgcn_mfma_f32_16x16x32_bf16(af[i], bfr[j], acc[i][j], 0, 0, 0);
  }

  int rbase = bm * 128 + w * 32;
  int cbase = bn * 64;
#pragma unroll
  for (int i = 0; i < 2; ++i) {
#pragma unroll
    for (int r = 0; r < 4; ++r) {
      int row = rbase + i * 16 + g4 * 4 + r;
#pragma unroll
      for (int j = 0; j < 4; ++j) {
        int col = cbase + j * 16 + lr;
        float v = acc[i][j][r] + bias[col];
        if (EPI == 0) {
          ((short*)Cout)[(size_t)row * N + col] = f2bf(v);
        } else if (EPI == 1) {
          v = 0.5f * v * (1.0f + erff(v * 0.70710678118654752f));
          ((short*)Cout)[(size_t)row * N + col] = f2bf(v);
        } else {
          ((float*)Cout)[(size_t)row * N + col] = v + resid[(size_t)row * N + col];
        }
      }
    }
  }
}

// ---------------- causal flash attention, QBLK=64, KVBLK=64, dbuf -----------
// K and pre-transposed V^T both staged via global_load_lds (swizzled source).
// Swapped QK^T + in-register softmax (defer-rescale) + shfl-built P frags.
// qkv: [ROWS][3*NE] bf16. vt: [48][HD][TT] bf16. y: [ROWS][NE] bf16.
__global__ __launch_bounds__(256, 4) void attn_kernel(
    const short* __restrict__ qkv, const short* __restrict__ vt,
    short* __restrict__ y) {
  __shared__ short Ks[2][64 * 64];   // [kpos][hd], XOR-swizzled
  __shared__ short Vs[2][64 * 64];   // [hd][kpos], XOR-swizzled
  int t = threadIdx.x, w = t >> 6, l = t & 63;
  int lr = l & 15, g = l >> 4, lkb = g * 8;
  int bh = blockIdx.x;               // XCD = bh % 8 (48 % 8 == 0)
  int b = bh / NH, h = bh % NH;
  int qt = ((int)gridDim.y - 1) - blockIdx.y;   // longest blocks first
  int qbase = qt * 64;
  const int rstride = 3 * NE;

  // Q fragments (B-operand: col=qrow, k=hd): rows qbase + w*16 + lr
  const short* qrow = qkv + (size_t)(b * TT + qbase + w * 16 + lr) * rstride + h * HD + lkb;
  bf16x8 qf0 = *reinterpret_cast<const bf16x8*>(qrow);
  bf16x8 qf1 = *reinterpret_cast<const bf16x8*>(qrow + 32);

  f32x4 o[4];
#pragma unroll
  for (int j = 0; j < 4; ++j) o[j] = (f32x4){0.f, 0.f, 0.f, 0.f};
  float m_run = -3e38f, l_run = 0.f;   // per-lane q-row: qbase + w*16 + lr

  // staging geometry: 16B chunk ids; row = id>>3, col pre-swizzled
  int ci0 = t, ci1 = t + 256;
  int row0 = ci0 >> 3, c0 = ((ci0 & 7) ^ (row0 & 7)) * 8;
  int row1 = ci1 >> 3, c1 = ((ci1 & 7) ^ (row1 & 7)) * 8;

  const short* kbase = qkv + (size_t)(b * TT) * rstride + NE + h * HD;
  const short* vtb = vt + (size_t)bh * HD * TT;

  // --- prologue: stage tile 0 into buffer 0 ---
  gload16(kbase + (size_t)row0 * rstride + c0, &Ks[0][ci0 * 8]);
  gload16(kbase + (size_t)row1 * rstride + c1, &Ks[0][ci1 * 8]);
  gload16(vtb + (size_t)row0 * TT + c0, &Vs[0][ci0 * 8]);
  gload16(vtb + (size_t)row1 * TT + c1, &Vs[0][ci1 * 8]);

  int qmin = qbase + w * 16;
  int srcA = ((g & 1) * 2) * 16 + lr;   // shfl src lanes for P-frag build
  int srcB = srcA + 16;
  bool ghi = (g >= 2);

  int nkv = qt + 1;
  for (int kt = 0; kt < nkv; ++kt) {
    int bi = kt & 1;
    int kvbase = kt * 64;
    bool pre = (kt + 1 < nkv);
    __syncthreads();   // buf bi ready (vmcnt drained by barrier)

    if (pre) {   // issue next tile's DMA (hides under this tile's compute)
      int nb = kvbase + 64;
      gload16(kbase + (size_t)(nb + row0) * rstride + c0, &Ks[bi ^ 1][ci0 * 8]);
      gload16(kbase + (size_t)(nb + row1) * rstride + c1, &Ks[bi ^ 1][ci1 * 8]);
      gload16(vtb + (size_t)row0 * TT + nb + c0, &Vs[bi ^ 1][ci0 * 8]);
      gload16(vtb + (size_t)row1 * TT + nb + c1, &Vs[bi ^ 1][ci1 * 8]);
    }

    // --- QK^T (swapped): s[nt][r] = S^T[kpos=kvbase+nt*16+g*4+r][qrow=lr]
    f32x4 s[4];
#pragma unroll
    for (int nt = 0; nt < 4; ++nt) {
      int row = nt * 16 + lr;
      bf16x8 kf0 = *reinterpret_cast<const bf16x8*>(
          (char*)Ks[bi] + ((row * 128 + lkb * 2) ^ ((lr & 7) << 4)));
      bf16x8 kf1 = *reinterpret_cast<const bf16x8*>(
          (char*)Ks[bi] + ((row * 128 + 64 + lkb * 2) ^ ((lr & 7) << 4)));
      f32x4 st = (f32x4){0.f, 0.f, 0.f, 0.f};
      st = __builtin_amdgcn_mfma_f32_16x16x32_bf16(kf0, qf0, st, 0, 0, 0);
      st = __builtin_amdgcn_mfma_f32_16x16x32_bf16(kf1, qf1, st, 0, 0, 0);
      s[nt] = st;
    }

    // --- mask/scale ---
    if (kvbase + 63 > qmin) {   // diagonal tile
      int qabs = qmin + lr;
#pragma unroll
      for (int nt = 0; nt < 4; ++nt)
#pragma unroll
        for (int r = 0; r < 4; ++r) {
          int kp = kvbase + nt * 16 + g * 4 + r;
          s[nt][r] = (kp <= qabs) ? s[nt][r] * 0.125f : -3e38f;
        }
    } else {
#pragma unroll
      for (int nt = 0; nt < 4; ++nt)
#pragma unroll
        for (int r = 0; r < 4; ++r)
          s[nt][r] *= 0.125f;
    }

    // --- online softmax, in-register, defer-rescale (T13, THR=8) ---
    float mx = s[0][0];
#pragma unroll
    for (int nt = 0; nt < 4; ++nt)
#pragma unroll
      for (int r = 0; r < 4; ++r) mx = fmaxf(mx, s[nt][r]);
    mx = fmaxf(mx, __shfl_xor(mx, 16));
    mx = fmaxf(mx, __shfl_xor(mx, 32));
    if (__any(mx > m_run + 8.f)) {
      float mn = fmaxf(m_run, mx);
      float al = __expf(m_run - mn);
      m_run = mn;
      l_run *= al;
      float al0 = __shfl(al, g * 4 + 0);
      float al1 = __shfl(al, g * 4 + 1);
      float al2 = __shfl(al, g * 4 + 2);
      float al3 = __shfl(al, g * 4 + 3);
#pragma unroll
      for (int j = 0; j < 4; ++j) {
        o[j][0] *= al0; o[j][1] *= al1; o[j][2] *= al2; o[j][3] *= al3;
      }
    }
    float rs = 0.f;
#pragma unroll
    for (int nt = 0; nt < 4; ++nt)
#pragma unroll
      for (int r = 0; r < 4; ++r) {
        float p = __expf(s[nt][r] - m_run);
        s[nt][r] = p;
        rs += p;
      }
    rs += __shfl_xor(rs, 16);
    rs += __shfl_xor(rs, 32);
    l_run += rs;

    // --- pack P to bf16 pairs ---
    unsigned int pw[4][2];
#pragma unroll
    for (int nt = 0; nt < 4; ++nt)
#pragma unroll
      for (int pr = 0; pr < 2; ++pr)
        pw[nt][pr] = (unsigned int)(unsigned short)f2bf(s[nt][2 * pr]) |
                     ((unsigned int)(unsigned short)f2bf(s[nt][2 * pr + 1]) << 16);

    // --- PV: build P A-frag per 32-k chunk via shfl, then MFMA ---
#pragma unroll
    for (int c = 0; c < 2; ++c) {
      unsigned int a00 = __shfl(pw[c * 2 + 0][0], srcA);
      unsigned int a01 = __shfl(pw[c * 2 + 0][1], srcA);
      unsigned int a02 = __shfl(pw[c * 2 + 0][0], srcB);
      unsigned int a03 = __shfl(pw[c * 2 + 0][1], srcB);
      unsigned int a10 = __shfl(pw[c * 2 + 1][0], srcA);
      unsigned int a11 = __shfl(pw[c * 2 + 1][1], srcA);
      unsigned int a12 = __shfl(pw[c * 2 + 1][0], srcB);
      unsigned int a13 = __shfl(pw[c * 2 + 1][1], srcB);
      unsigned int u0 = ghi ? a10 : a00;
      unsigned int u1 = ghi ? a11 : a01;
      unsigned int u2 = ghi ? a12 : a02;
      unsigned int u3 = ghi ? a13 : a03;
      bf16x8 pa;
      pa[0] = (short)(u0 & 0xffffu); pa[1] = (short)(u0 >> 16);
      pa[2] = (short)(u1 & 0xffffu); pa[3] = (short)(u1 >> 16);
      pa[4] = (short)(u2 & 0xffffu); pa[5] = (short)(u2 >> 16);
      pa[6] = (short)(u3 & 0xffffu); pa[7] = (short)(u3 >> 16);
#pragma unroll
      for (int j = 0; j < 4; ++j) {
        int vrow = j * 16 + lr;
        bf16x8 vf = *reinterpret_cast<const bf16x8*>(
            (char*)Vs[bi] + ((vrow * 128 + c * 64 + lkb * 2) ^ ((lr & 7) << 4)));
        o[j] = __builtin_amdgcn_mfma_f32_16x16x32_bf16(pa, vf, o[j], 0, 0, 0);
      }
    }
  }

  // --- epilogue: normalize (inv at lane (row); o rows are g*4+r) ---
  float inv = 1.0f / l_run;
  float i0 = __shfl(inv, g * 4 + 0);
  float i1 = __shfl(inv, g * 4 + 1);
  float i2 = __shfl(inv, g * 4 + 2);
  float i3 = __shfl(inv, g * 4 + 3);
#pragma unroll
  for (int r = 0; r < 4; ++r) {
    float ir = (r == 0) ? i0 : (r == 1) ? i1 : (r == 2) ? i2 : i3;
    size_t row = (size_t)(b * TT + qbase + w * 16 + g * 4 + r);
#pragma unroll
    for (int j = 0; j < 4; ++j)
      y[row * NE + h * HD + j * 16 + lr] = f2bf(o[j][r] * ir);
  }
}

extern "C" void kernel_launch(void* const* d_in, const int* in_sizes, int n_in,
                              void* d_out, int out_size, void* d_ws, size_t ws_size,
                              hipStream_t stream) {
  (void)in_sizes; (void)n_in; (void)out_size; (void)ws_size;
  const float* x       = (const float*)d_in[0];
  const float* ln1_g   = (const float*)d_in[1];
  const float* ln1_b   = (const float*)d_in[2];
  const float* w_attn  = (const float*)d_in[3];
  const float* b_attn  = (const float*)d_in[4];
  const float* w_aproj = (const float*)d_in[5];
  const float* b_aproj = (const float*)d_in[6];
  const float* ln2_g   = (const float*)d_in[7];
  const float* ln2_b   = (const float*)d_in[8];
  const float* w_fc    = (const float*)d_in[9];
  const float* b_fc    = (const float*)d_in[10];
  const float* w_mproj = (const float*)d_in[11];
  const float* b_mproj = (const float*)d_in[12];

  char* ws = (char*)d_ws;
  size_t off = 0;
  auto alloc = [&](size_t bytes) {
    char* p = ws + off;
    off += (bytes + 255) & ~(size_t)255;
    return p;
  };
  short* wt_attn  = (short*)alloc((size_t)2304 * 768 * 2);
  short* wt_aproj = (short*)alloc((size_t)768 * 768 * 2);
  short* wt_fc    = (short*)alloc((size_t)3072 * 768 * 2);
  short* wt_mproj = (short*)alloc((size_t)768 * 3072 * 2);
  short* lnb  = (short*)alloc((size_t)ROWS * 768 * 2);
  short* qkvb = (short*)alloc((size_t)ROWS * 3072 * 2);
  short* yb   = (short*)alloc((size_t)ROWS * 768 * 2);
  float* x2   = (float*)alloc((size_t)ROWS * 768 * 4);
  // vt aliases lnb: lnb (ln1 out) is dead after the qkv GEMM; ln2 rewrites it
  // after attention completes. Sizes match exactly (8192*768*2 B).
  short* vtg = lnb;

  wtrans_kernel<<<dim3(768 / 64, 2304 / 64), 256, 0, stream>>>(w_attn, wt_attn, 768, 2304);
  wtrans_kernel<<<dim3(768 / 64, 768 / 64), 256, 0, stream>>>(w_aproj, wt_aproj, 768, 768);
  wtrans_kernel<<<dim3(768 / 64, 3072 / 64), 256, 0, stream>>>(w_fc, wt_fc, 768, 3072);
  wtrans_kernel<<<dim3(3072 / 64, 768 / 64), 256, 0, stream>>>(w_mproj, wt_mproj, 3072, 768);

  ln_kernel<<<ROWS, 64, 0, stream>>>(x, ln1_g, ln1_b, lnb);
  gemm_kernel<0><<<dim3(2304 / 128, ROWS / 128), 256, 0, stream>>>(
      lnb, wt_attn, b_attn, nullptr, qkvb, ROWS, 2304, 768);
  vtrans_kernel<<<dim3(BB * NH, TT / 64), 256, 0, stream>>>(qkvb, vtg);
  attn_kernel<<<dim3(BB * NH, TT / 64), 256, 0, stream>>>(qkvb, vtg, yb);
  gemm64_kernel<2><<<dim3(768 / 64, ROWS / 128), 256, 0, stream>>>(
      yb, wt_aproj, b_aproj, x, x2, ROWS, 768, 768);
  ln_kernel<<<ROWS, 64, 0, stream>>>(x2, ln2_g, ln2_b, lnb);
  gemm_kernel<1><<<dim3(3072 / 128, ROWS / 128), 256, 0, stream>>>(
      lnb, wt_fc, b_fc, nullptr, qkvb, ROWS, 3072, 768);
  gemm64_kernel<2><<<dim3(768 / 64, ROWS / 128), 256, 0, stream>>>(
      qkvb, wt_mproj, b_mproj, x2, (float*)d_out, ROWS, 768, 3072);
}

// Round 9
// 306.894 us; speedup vs baseline: 1.4470x; 1.0382x over previous
//
#include <hip/hip_runtime.h>
#include <hip/hip_bf16.h>

#define NE 768
#define NH 12
#define HD 64
#define BB 4
#define TT 2048
#define ROWS (BB*TT)  // 8192

typedef __attribute__((ext_vector_type(8))) short bf16x8;
typedef __attribute__((ext_vector_type(4))) float f32x4;

__device__ __forceinline__ short f2bf(float f) {
  __hip_bfloat16 h = __float2bfloat16(f);
  union { __hip_bfloat16 h; short s; } u; u.h = h; return u.s;
}

__device__ __forceinline__ void gload16(const void* g, void* l) {
  __builtin_amdgcn_global_load_lds(
      (const __attribute__((address_space(1))) void*)g,
      (__attribute__((address_space(3))) void*)l,
      16, 0, 0);
}

// XCD-aware remap: 64 bm panels = 8 XCDs x 8. Same-bm blocks co-locate on one
// XCD (id%8) and are dispatched adjacently -> A-panel fetched once per chip.
__device__ __forceinline__ void xcd_remap(int id, int nbn, int& bm, int& bn) {
  int x = id & 7;
  int j = id >> 3;
  bm = x * 8 + j / nbn;
  bn = j % nbn;
}

// ---------------- weight convert + transpose: W[K][N] f32 -> Wt[N][K] bf16 ----
__global__ __launch_bounds__(256) void wtrans_kernel(
    const float* __restrict__ W, short* __restrict__ Wt, int K, int N) {
  __shared__ short tile[64 * 65];
  int k0 = blockIdx.x * 64, n0 = blockIdx.y * 64;
  int t = threadIdx.x;
#pragma unroll
  for (int p = 0; p < 16; ++p) {
    int idx = p * 256 + t;
    int r = idx >> 6, c = idx & 63;
    tile[r * 65 + c] = f2bf(W[(size_t)(k0 + r) * N + n0 + c]);
  }
  __syncthreads();
#pragma unroll
  for (int p = 0; p < 16; ++p) {
    int idx = p * 256 + t;
    int rr = idx >> 6, cc = idx & 63;
    Wt[(size_t)(n0 + rr) * K + k0 + cc] = tile[cc * 65 + rr];
  }
}

// ---------------- V transpose: qkv V-part -> Vt[bh][hd][tloc] bf16 ----------
__global__ __launch_bounds__(256) void vtrans_kernel(
    const short* __restrict__ qkv, short* __restrict__ vt) {
  __shared__ short tile[64 * 65];
  int bh = blockIdx.x;
  int b = bh / NH, h = bh % NH;
  int t0 = blockIdx.y * 64;
  int t = threadIdx.x;
#pragma unroll
  for (int p = 0; p < 16; ++p) {
    int idx = p * 256 + t;
    int r = idx >> 6, c = idx & 63;   // r = tloc, c = hd
    tile[r * 65 + c] =
        qkv[(size_t)(b * TT + t0 + r) * (3 * NE) + 2 * NE + h * HD + c];
  }
  __syncthreads();
#pragma unroll
  for (int p = 0; p < 16; ++p) {
    int idx = p * 256 + t;
    int rr = idx >> 6, cc = idx & 63; // rr = hd, cc = tloc
    vt[(size_t)bh * HD * TT + (size_t)rr * TT + t0 + cc] = tile[cc * 65 + rr];
  }
}

// ---------------- LayerNorm: fp32 in -> bf16 out, one wave per row ----------
__global__ __launch_bounds__(64) void ln_kernel(
    const float* __restrict__ x, const float* __restrict__ g,
    const float* __restrict__ b, short* __restrict__ out) {
  int row = blockIdx.x, l = threadIdx.x;
  const float* xr = x + (size_t)row * NE;
  float4 v[3];
  float s = 0.f, ss = 0.f;
#pragma unroll
  for (int i = 0; i < 3; ++i) {
    v[i] = *reinterpret_cast<const float4*>(xr + l * 4 + i * 256);
    s += v[i].x + v[i].y + v[i].z + v[i].w;
    ss += v[i].x * v[i].x + v[i].y * v[i].y + v[i].z * v[i].z + v[i].w * v[i].w;
  }
#pragma unroll
  for (int m = 1; m < 64; m <<= 1) {
    s += __shfl_xor(s, m);
    ss += __shfl_xor(ss, m);
  }
  float mu = s * (1.0f / NE);
  float var = ss * (1.0f / NE) - mu * mu;
  float rstd = rsqrtf(var + 1e-5f);
#pragma unroll
  for (int i = 0; i < 3; ++i) {
    float4 gv = *reinterpret_cast<const float4*>(g + l * 4 + i * 256);
    float4 bv = *reinterpret_cast<const float4*>(b + l * 4 + i * 256);
    short4 o;
    o.x = f2bf((v[i].x - mu) * rstd * gv.x + bv.x);
    o.y = f2bf((v[i].y - mu) * rstd * gv.y + bv.y);
    o.z = f2bf((v[i].z - mu) * rstd * gv.z + bv.z);
    o.w = f2bf((v[i].w - mu) * rstd * gv.w + bv.w);
    *reinterpret_cast<short4*>(out + (size_t)row * NE + l * 4 + i * 256) = o;
  }
}

// ---------------- GEMM 128x128, BK=32, dbuf, XCD-remapped 1-D grid ----------
template <int EPI>
__global__ __launch_bounds__(256) void gemm_kernel(
    const short* __restrict__ A, const short* __restrict__ Bt,
    const float* __restrict__ bias, const float* __restrict__ resid,
    void* __restrict__ Cout, int M, int N, int K, int nbn) {
  __shared__ short As[2][128 * 32];
  __shared__ short Bs[2][128 * 32];
  int t = threadIdx.x;
  int w = t >> 6, l = t & 63;
  int wr = w >> 1, wc = w & 1;
  int bm, bn;
  xcd_remap(blockIdx.x, nbn, bm, bn);
  int lr = l & 15, g4 = l >> 4;

  f32x4 acc[4][4];
#pragma unroll
  for (int i = 0; i < 4; ++i)
#pragma unroll
    for (int j = 0; j < 4; ++j) acc[i][j] = (f32x4){0.f, 0.f, 0.f, 0.f};

  int r0 = t >> 2;
  int cs = ((t & 3) ^ (r0 & 3)) * 8;
  const short* ga = A + (size_t)(bm * 128) * K;
  const short* gb = Bt + (size_t)(bn * 128) * K;

  gload16(ga + (size_t)r0 * K + cs, &As[0][t * 8]);
  gload16(ga + (size_t)(r0 + 64) * K + cs, &As[0][(t + 256) * 8]);
  gload16(gb + (size_t)r0 * K + cs, &Bs[0][t * 8]);
  gload16(gb + (size_t)(r0 + 64) * K + cs, &Bs[0][(t + 256) * 8]);

  int xorA = (lr & 3) << 4;
  int nk = K >> 5;
  for (int kt = 0; kt < nk; ++kt) {
    int bi = kt & 1;
    __syncthreads();
    if (kt + 1 < nk) {
      int ko = (kt + 1) * 32;
      gload16(ga + (size_t)r0 * K + ko + cs, &As[bi ^ 1][t * 8]);
      gload16(ga + (size_t)(r0 + 64) * K + ko + cs, &As[bi ^ 1][(t + 256) * 8]);
      gload16(gb + (size_t)r0 * K + ko + cs, &Bs[bi ^ 1][t * 8]);
      gload16(gb + (size_t)(r0 + 64) * K + ko + cs, &Bs[bi ^ 1][(t + 256) * 8]);
    }
    const char* Ab = (const char*)As[bi];
    const char* Bb = (const char*)Bs[bi];
    bf16x8 af[4], bfr[4];
#pragma unroll
    for (int i = 0; i < 4; ++i)
      af[i] = *reinterpret_cast<const bf16x8*>(
          Ab + (((wr * 64 + i * 16 + lr) * 64 + g4 * 16) ^ xorA));
#pragma unroll
    for (int j = 0; j < 4; ++j)
      bfr[j] = *reinterpret_cast<const bf16x8*>(
          Bb + (((wc * 64 + j * 16 + lr) * 64 + g4 * 16) ^ xorA));
#pragma unroll
    for (int i = 0; i < 4; ++i)
#pragma unroll
      for (int j = 0; j < 4; ++j)
        acc[i][j] = __builtin_amdgcn_mfma_f32_16x16x32_bf16(af[i], bfr[j], acc[i][j], 0, 0, 0);
  }

  int rbase = bm * 128 + wr * 64;
  int cbase = bn * 128 + wc * 64;
#pragma unroll
  for (int i = 0; i < 4; ++i) {
#pragma unroll
    for (int r = 0; r < 4; ++r) {
      int row = rbase + i * 16 + g4 * 4 + r;
#pragma unroll
      for (int j = 0; j < 4; ++j) {
        int col = cbase + j * 16 + lr;
        float v = acc[i][j][r] + bias[col];
        if (EPI == 0) {
          ((short*)Cout)[(size_t)row * N + col] = f2bf(v);
        } else if (EPI == 1) {
          v = 0.5f * v * (1.0f + erff(v * 0.70710678118654752f));
          ((short*)Cout)[(size_t)row * N + col] = f2bf(v);
        } else {
          ((float*)Cout)[(size_t)row * N + col] = v + resid[(size_t)row * N + col];
        }
      }
    }
  }
}

// ---------------- GEMM 128x64, BK=32, dbuf, XCD-remapped 1-D grid -----------
template <int EPI>
__global__ __launch_bounds__(256) void gemm64_kernel(
    const short* __restrict__ A, const short* __restrict__ Bt,
    const float* __restrict__ bias, const float* __restrict__ resid,
    void* __restrict__ Cout, int M, int N, int K, int nbn) {
  __shared__ short As[2][128 * 32];
  __shared__ short Bs[2][64 * 32];
  int t = threadIdx.x;
  int w = t >> 6, l = t & 63;
  int bm, bn;
  xcd_remap(blockIdx.x, nbn, bm, bn);
  int lr = l & 15, g4 = l >> 4;

  f32x4 acc[2][4];
#pragma unroll
  for (int i = 0; i < 2; ++i)
#pragma unroll
    for (int j = 0; j < 4; ++j) acc[i][j] = (f32x4){0.f, 0.f, 0.f, 0.f};

  int r0 = t >> 2;
  int cs = ((t & 3) ^ (r0 & 3)) * 8;
  const short* ga = A + (size_t)(bm * 128) * K;
  const short* gb = Bt + (size_t)(bn * 64) * K;

  gload16(ga + (size_t)r0 * K + cs, &As[0][t * 8]);
  gload16(ga + (size_t)(r0 + 64) * K + cs, &As[0][(t + 256) * 8]);
  gload16(gb + (size_t)r0 * K + cs, &Bs[0][t * 8]);

  int xorA = (lr & 3) << 4;
  int nk = K >> 5;
  for (int kt = 0; kt < nk; ++kt) {
    int bi = kt & 1;
    __syncthreads();
    if (kt + 1 < nk) {
      int ko = (kt + 1) * 32;
      gload16(ga + (size_t)r0 * K + ko + cs, &As[bi ^ 1][t * 8]);
      gload16(ga + (size_t)(r0 + 64) * K + ko + cs, &As[bi ^ 1][(t + 256) * 8]);
      gload16(gb + (size_t)r0 * K + ko + cs, &Bs[bi ^ 1][t * 8]);
    }
    const char* Ab = (const char*)As[bi];
    const char* Bb = (const char*)Bs[bi];
    bf16x8 af[2], bfr[4];
#pragma unroll
    for (int i = 0; i < 2; ++i)
      af[i] = *reinterpret_cast<const bf16x8*>(
          Ab + (((w * 32 + i * 16 + lr) * 64 + g4 * 16) ^ xorA));
#pragma unroll
    for (int j = 0; j < 4; ++j)
      bfr[j] = *reinterpret_cast<const bf16x8*>(
          Bb + (((j * 16 + lr) * 64 + g4 * 16) ^ xorA));
#pragma unroll
    for (int i = 0; i < 2; ++i)
#pragma unroll
      for (int j = 0; j < 4; ++j)
        acc[i][j] = __builtin_amdgcn_mfma_f32_16x16x32_bf16(af[i], bfr[j], acc[i][j], 0, 0, 0);
  }

  int rbase = bm * 128 + w * 32;
  int cbase = bn * 64;
#pragma unroll
  for (int i = 0; i < 2; ++i) {
#pragma unroll
    for (int r = 0; r < 4; ++r) {
      int row = rbase + i * 16 + g4 * 4 + r;
#pragma unroll
      for (int j = 0; j < 4; ++j) {
        int col = cbase + j * 16 + lr;
        float v = acc[i][j][r] + bias[col];
        if (EPI == 0) {
          ((short*)Cout)[(size_t)row * N + col] = f2bf(v);
        } else if (EPI == 1) {
          v = 0.5f * v * (1.0f + erff(v * 0.70710678118654752f));
          ((short*)Cout)[(size_t)row * N + col] = f2bf(v);
        } else {
          ((float*)Cout)[(size_t)row * N + col] = v + resid[(size_t)row * N + col];
        }
      }
    }
  }
}

// ---------------- causal flash attention, QBLK=64, KVBLK=64, dbuf -----------
// K and pre-transposed V^T both staged via global_load_lds (swizzled source).
// Swapped QK^T + in-register softmax (defer-rescale) + shfl-built P frags.
// qkv: [ROWS][3*NE] bf16. vt: [48][HD][TT] bf16. y: [ROWS][NE] bf16.
__global__ __launch_bounds__(256, 4) void attn_kernel(
    const short* __restrict__ qkv, const short* __restrict__ vt,
    short* __restrict__ y) {
  __shared__ short Ks[2][64 * 64];   // [kpos][hd], XOR-swizzled
  __shared__ short Vs[2][64 * 64];   // [hd][kpos], XOR-swizzled
  int t = threadIdx.x, w = t >> 6, l = t & 63;
  int lr = l & 15, g = l >> 4, lkb = g * 8;
  int bh = blockIdx.x;               // XCD = bh % 8 (48 % 8 == 0)
  int b = bh / NH, h = bh % NH;
  int qt = ((int)gridDim.y - 1) - blockIdx.y;   // longest blocks first
  int qbase = qt * 64;
  const int rstride = 3 * NE;

  // Q fragments (B-operand: col=qrow, k=hd): rows qbase + w*16 + lr
  const short* qrow = qkv + (size_t)(b * TT + qbase + w * 16 + lr) * rstride + h * HD + lkb;
  bf16x8 qf0 = *reinterpret_cast<const bf16x8*>(qrow);
  bf16x8 qf1 = *reinterpret_cast<const bf16x8*>(qrow + 32);

  f32x4 o[4];
#pragma unroll
  for (int j = 0; j < 4; ++j) o[j] = (f32x4){0.f, 0.f, 0.f, 0.f};
  float m_run = -3e38f, l_run = 0.f;   // per-lane q-row: qbase + w*16 + lr

  // staging geometry: 16B chunk ids; row = id>>3, col pre-swizzled
  int ci0 = t, ci1 = t + 256;
  int row0 = ci0 >> 3, c0 = ((ci0 & 7) ^ (row0 & 7)) * 8;
  int row1 = ci1 >> 3, c1 = ((ci1 & 7) ^ (row1 & 7)) * 8;

  const short* kbase = qkv + (size_t)(b * TT) * rstride + NE + h * HD;
  const short* vtb = vt + (size_t)bh * HD * TT;

  // --- prologue: stage tile 0 into buffer 0 ---
  gload16(kbase + (size_t)row0 * rstride + c0, &Ks[0][ci0 * 8]);
  gload16(kbase + (size_t)row1 * rstride + c1, &Ks[0][ci1 * 8]);
  gload16(vtb + (size_t)row0 * TT + c0, &Vs[0][ci0 * 8]);
  gload16(vtb + (size_t)row1 * TT + c1, &Vs[0][ci1 * 8]);

  int qmin = qbase + w * 16;
  int srcA = ((g & 1) * 2) * 16 + lr;   // shfl src lanes for P-frag build
  int srcB = srcA + 16;
  bool ghi = (g >= 2);

  int nkv = qt + 1;
  for (int kt = 0; kt < nkv; ++kt) {
    int bi = kt & 1;
    int kvbase = kt * 64;
    bool pre = (kt + 1 < nkv);
    __syncthreads();   // buf bi ready (vmcnt drained by barrier)

    if (pre) {   // issue next tile's DMA (hides under this tile's compute)
      int nb = kvbase + 64;
      gload16(kbase + (size_t)(nb + row0) * rstride + c0, &Ks[bi ^ 1][ci0 * 8]);
      gload16(kbase + (size_t)(nb + row1) * rstride + c1, &Ks[bi ^ 1][ci1 * 8]);
      gload16(vtb + (size_t)row0 * TT + nb + c0, &Vs[bi ^ 1][ci0 * 8]);
      gload16(vtb + (size_t)row1 * TT + nb + c1, &Vs[bi ^ 1][ci1 * 8]);
    }

    // --- QK^T (swapped): s[nt][r] = S^T[kpos=kvbase+nt*16+g*4+r][qrow=lr]
    f32x4 s[4];
#pragma unroll
    for (int nt = 0; nt < 4; ++nt) {
      int row = nt * 16 + lr;
      bf16x8 kf0 = *reinterpret_cast<const bf16x8*>(
          (char*)Ks[bi] + ((row * 128 + lkb * 2) ^ ((lr & 7) << 4)));
      bf16x8 kf1 = *reinterpret_cast<const bf16x8*>(
          (char*)Ks[bi] + ((row * 128 + 64 + lkb * 2) ^ ((lr & 7) << 4)));
      f32x4 st = (f32x4){0.f, 0.f, 0.f, 0.f};
      st = __builtin_amdgcn_mfma_f32_16x16x32_bf16(kf0, qf0, st, 0, 0, 0);
      st = __builtin_amdgcn_mfma_f32_16x16x32_bf16(kf1, qf1, st, 0, 0, 0);
      s[nt] = st;
    }

    // --- mask/scale ---
    if (kvbase + 63 > qmin) {   // diagonal tile
      int qabs = qmin + lr;
#pragma unroll
      for (int nt = 0; nt < 4; ++nt)
#pragma unroll
        for (int r = 0; r < 4; ++r) {
          int kp = kvbase + nt * 16 + g * 4 + r;
          s[nt][r] = (kp <= qabs) ? s[nt][r] * 0.125f : -3e38f;
        }
    } else {
#pragma unroll
      for (int nt = 0; nt < 4; ++nt)
#pragma unroll
        for (int r = 0; r < 4; ++r)
          s[nt][r] *= 0.125f;
    }

    // --- online softmax, in-register, defer-rescale (T13, THR=8) ---
    float mx = s[0][0];
#pragma unroll
    for (int nt = 0; nt < 4; ++nt)
#pragma unroll
      for (int r = 0; r < 4; ++r) mx = fmaxf(mx, s[nt][r]);
    mx = fmaxf(mx, __shfl_xor(mx, 16));
    mx = fmaxf(mx, __shfl_xor(mx, 32));
    if (__any(mx > m_run + 8.f)) {
      float mn = fmaxf(m_run, mx);
      float al = __expf(m_run - mn);
      m_run = mn;
      l_run *= al;
      float al0 = __shfl(al, g * 4 + 0);
      float al1 = __shfl(al, g * 4 + 1);
      float al2 = __shfl(al, g * 4 + 2);
      float al3 = __shfl(al, g * 4 + 3);
#pragma unroll
      for (int j = 0; j < 4; ++j) {
        o[j][0] *= al0; o[j][1] *= al1; o[j][2] *= al2; o[j][3] *= al3;
      }
    }
    float rs = 0.f;
#pragma unroll
    for (int nt = 0; nt < 4; ++nt)
#pragma unroll
      for (int r = 0; r < 4; ++r) {
        float p = __expf(s[nt][r] - m_run);
        s[nt][r] = p;
        rs += p;
      }
    rs += __shfl_xor(rs, 16);
    rs += __shfl_xor(rs, 32);
    l_run += rs;

    // --- pack P to bf16 pairs ---
    unsigned int pw[4][2];
#pragma unroll
    for (int nt = 0; nt < 4; ++nt)
#pragma unroll
      for (int pr = 0; pr < 2; ++pr)
        pw[nt][pr] = (unsigned int)(unsigned short)f2bf(s[nt][2 * pr]) |
                     ((unsigned int)(unsigned short)f2bf(s[nt][2 * pr + 1]) << 16);

    // --- PV: build P A-frag per 32-k chunk via shfl, then MFMA ---
#pragma unroll
    for (int c = 0; c < 2; ++c) {
      unsigned int a00 = __shfl(pw[c * 2 + 0][0], srcA);
      unsigned int a01 = __shfl(pw[c * 2 + 0][1], srcA);
      unsigned int a02 = __shfl(pw[c * 2 + 0][0], srcB);
      unsigned int a03 = __shfl(pw[c * 2 + 0][1], srcB);
      unsigned int a10 = __shfl(pw[c * 2 + 1][0], srcA);
      unsigned int a11 = __shfl(pw[c * 2 + 1][1], srcA);
      unsigned int a12 = __shfl(pw[c * 2 + 1][0], srcB);
      unsigned int a13 = __shfl(pw[c * 2 + 1][1], srcB);
      unsigned int u0 = ghi ? a10 : a00;
      unsigned int u1 = ghi ? a11 : a01;
      unsigned int u2 = ghi ? a12 : a02;
      unsigned int u3 = ghi ? a13 : a03;
      bf16x8 pa;
      pa[0] = (short)(u0 & 0xffffu); pa[1] = (short)(u0 >> 16);
      pa[2] = (short)(u1 & 0xffffu); pa[3] = (short)(u1 >> 16);
      pa[4] = (short)(u2 & 0xffffu); pa[5] = (short)(u2 >> 16);
      pa[6] = (short)(u3 & 0xffffu); pa[7] = (short)(u3 >> 16);
#pragma unroll
      for (int j = 0; j < 4; ++j) {
        int vrow = j * 16 + lr;
        bf16x8 vf = *reinterpret_cast<const bf16x8*>(
            (char*)Vs[bi] + ((vrow * 128 + c * 64 + lkb * 2) ^ ((lr & 7) << 4)));
        o[j] = __builtin_amdgcn_mfma_f32_16x16x32_bf16(pa, vf, o[j], 0, 0, 0);
      }
    }
  }

  // --- epilogue: normalize (inv at lane (row); o rows are g*4+r) ---
  float inv = 1.0f / l_run;
  float i0 = __shfl(inv, g * 4 + 0);
  float i1 = __shfl(inv, g * 4 + 1);
  float i2 = __shfl(inv, g * 4 + 2);
  float i3 = __shfl(inv, g * 4 + 3);
#pragma unroll
  for (int r = 0; r < 4; ++r) {
    float ir = (r == 0) ? i0 : (r == 1) ? i1 : (r == 2) ? i2 : i3;
    size_t row = (size_t)(b * TT + qbase + w * 16 + g * 4 + r);
#pragma unroll
    for (int j = 0; j < 4; ++j)
      y[row * NE + h * HD + j * 16 + lr] = f2bf(o[j][r] * ir);
  }
}

extern "C" void kernel_launch(void* const* d_in, const int* in_sizes, int n_in,
                              void* d_out, int out_size, void* d_ws, size_t ws_size,
                              hipStream_t stream) {
  (void)in_sizes; (void)n_in; (void)out_size; (void)ws_size;
  const float* x       = (const float*)d_in[0];
  const float* ln1_g   = (const float*)d_in[1];
  const float* ln1_b   = (const float*)d_in[2];
  const float* w_attn  = (const float*)d_in[3];
  const float* b_attn  = (const float*)d_in[4];
  const float* w_aproj = (const float*)d_in[5];
  const float* b_aproj = (const float*)d_in[6];
  const float* ln2_g   = (const float*)d_in[7];
  const float* ln2_b   = (const float*)d_in[8];
  const float* w_fc    = (const float*)d_in[9];
  const float* b_fc    = (const float*)d_in[10];
  const float* w_mproj = (const float*)d_in[11];
  const float* b_mproj = (const float*)d_in[12];

  char* ws = (char*)d_ws;
  size_t off = 0;
  auto alloc = [&](size_t bytes) {
    char* p = ws + off;
    off += (bytes + 255) & ~(size_t)255;
    return p;
  };
  short* wt_attn  = (short*)alloc((size_t)2304 * 768 * 2);
  short* wt_aproj = (short*)alloc((size_t)768 * 768 * 2);
  short* wt_fc    = (short*)alloc((size_t)3072 * 768 * 2);
  short* wt_mproj = (short*)alloc((size_t)768 * 3072 * 2);
  short* lnb  = (short*)alloc((size_t)ROWS * 768 * 2);
  short* qkvb = (short*)alloc((size_t)ROWS * 3072 * 2);
  short* yb   = (short*)alloc((size_t)ROWS * 768 * 2);
  float* x2   = (float*)alloc((size_t)ROWS * 768 * 4);
  // vt aliases lnb: lnb (ln1 out) is dead after the qkv GEMM; ln2 rewrites it
  // after attention completes. Sizes match exactly (8192*768*2 B).
  short* vtg = lnb;

  wtrans_kernel<<<dim3(768 / 64, 2304 / 64), 256, 0, stream>>>(w_attn, wt_attn, 768, 2304);
  wtrans_kernel<<<dim3(768 / 64, 768 / 64), 256, 0, stream>>>(w_aproj, wt_aproj, 768, 768);
  wtrans_kernel<<<dim3(768 / 64, 3072 / 64), 256, 0, stream>>>(w_fc, wt_fc, 768, 3072);
  wtrans_kernel<<<dim3(3072 / 64, 768 / 64), 256, 0, stream>>>(w_mproj, wt_mproj, 3072, 768);

  ln_kernel<<<ROWS, 64, 0, stream>>>(x, ln1_g, ln1_b, lnb);
  gemm_kernel<0><<<64 * 18, 256, 0, stream>>>(
      lnb, wt_attn, b_attn, nullptr, qkvb, ROWS, 2304, 768, 18);
  vtrans_kernel<<<dim3(BB * NH, TT / 64), 256, 0, stream>>>(qkvb, vtg);
  attn_kernel<<<dim3(BB * NH, TT / 64), 256, 0, stream>>>(qkvb, vtg, yb);
  gemm64_kernel<2><<<64 * 12, 256, 0, stream>>>(
      yb, wt_aproj, b_aproj, x, x2, ROWS, 768, 768, 12);
  ln_kernel<<<ROWS, 64, 0, stream>>>(x2, ln2_g, ln2_b, lnb);
  gemm_kernel<1><<<64 * 24, 256, 0, stream>>>(
      lnb, wt_fc, b_fc, nullptr, qkvb, ROWS, 3072, 768, 24);
  gemm64_kernel<2><<<64 * 12, 256, 0, stream>>>(
      qkvb, wt_mproj, b_mproj, x2, (float*)d_out, ROWS, 768, 3072, 12);
}

// Round 10
// 303.932 us; speedup vs baseline: 1.4611x; 1.0097x over previous
//
#include <hip/hip_runtime.h>
#include <hip/hip_bf16.h>

#define NE 768
#define NH 12
#define HD 64
#define BB 4
#define TT 2048
#define ROWS (BB*TT)  // 8192

typedef __attribute__((ext_vector_type(8))) short bf16x8;
typedef __attribute__((ext_vector_type(4))) float f32x4;

// counted-vmcnt pipeline fences (m201 pattern): wait only the oldest tile's
// loads, raw barrier, sched fences to pin ordering at source level.
#define WAITV(N) asm volatile("s_waitcnt vmcnt(" #N ")" ::: "memory")
#define BARSYNC()                                   \
  do {                                              \
    __builtin_amdgcn_sched_barrier(0);              \
    __builtin_amdgcn_s_barrier();                   \
    __builtin_amdgcn_sched_barrier(0);              \
  } while (0)

__device__ __forceinline__ short f2bf(float f) {
  __hip_bfloat16 h = __float2bfloat16(f);
  union { __hip_bfloat16 h; short s; } u; u.h = h; return u.s;
}

__device__ __forceinline__ void gload16(const void* g, void* l) {
  __builtin_amdgcn_global_load_lds(
      (const __attribute__((address_space(1))) void*)g,
      (__attribute__((address_space(3))) void*)l,
      16, 0, 0);
}

// XCD-aware remap: 64 bm panels = 8 XCDs x 8. Same-bm blocks co-locate on one
// XCD (id%8) and are dispatched adjacently -> A-panel fetched once per chip.
__device__ __forceinline__ void xcd_remap(int id, int nbn, int& bm, int& bn) {
  int x = id & 7;
  int j = id >> 3;
  bm = x * 8 + j / nbn;
  bn = j % nbn;
}

// ---------------- weight convert + transpose: W[K][N] f32 -> Wt[N][K] bf16 ----
__global__ __launch_bounds__(256) void wtrans_kernel(
    const float* __restrict__ W, short* __restrict__ Wt, int K, int N) {
  __shared__ short tile[64 * 65];
  int k0 = blockIdx.x * 64, n0 = blockIdx.y * 64;
  int t = threadIdx.x;
#pragma unroll
  for (int p = 0; p < 16; ++p) {
    int idx = p * 256 + t;
    int r = idx >> 6, c = idx & 63;
    tile[r * 65 + c] = f2bf(W[(size_t)(k0 + r) * N + n0 + c]);
  }
  __syncthreads();
#pragma unroll
  for (int p = 0; p < 16; ++p) {
    int idx = p * 256 + t;
    int rr = idx >> 6, cc = idx & 63;
    Wt[(size_t)(n0 + rr) * K + k0 + cc] = tile[cc * 65 + rr];
  }
}

// ---------------- V transpose: qkv V-part -> Vt[bh][hd][tloc] bf16 ----------
__global__ __launch_bounds__(256) void vtrans_kernel(
    const short* __restrict__ qkv, short* __restrict__ vt) {
  __shared__ short tile[64 * 65];
  int bh = blockIdx.x;
  int b = bh / NH, h = bh % NH;
  int t0 = blockIdx.y * 64;
  int t = threadIdx.x;
#pragma unroll
  for (int p = 0; p < 16; ++p) {
    int idx = p * 256 + t;
    int r = idx >> 6, c = idx & 63;   // r = tloc, c = hd
    tile[r * 65 + c] =
        qkv[(size_t)(b * TT + t0 + r) * (3 * NE) + 2 * NE + h * HD + c];
  }
  __syncthreads();
#pragma unroll
  for (int p = 0; p < 16; ++p) {
    int idx = p * 256 + t;
    int rr = idx >> 6, cc = idx & 63; // rr = hd, cc = tloc
    vt[(size_t)bh * HD * TT + (size_t)rr * TT + t0 + cc] = tile[cc * 65 + rr];
  }
}

// ---------------- LayerNorm: fp32 in -> bf16 out, one wave per row ----------
__global__ __launch_bounds__(64) void ln_kernel(
    const float* __restrict__ x, const float* __restrict__ g,
    const float* __restrict__ b, short* __restrict__ out) {
  int row = blockIdx.x, l = threadIdx.x;
  const float* xr = x + (size_t)row * NE;
  float4 v[3];
  float s = 0.f, ss = 0.f;
#pragma unroll
  for (int i = 0; i < 3; ++i) {
    v[i] = *reinterpret_cast<const float4*>(xr + l * 4 + i * 256);
    s += v[i].x + v[i].y + v[i].z + v[i].w;
    ss += v[i].x * v[i].x + v[i].y * v[i].y + v[i].z * v[i].z + v[i].w * v[i].w;
  }
#pragma unroll
  for (int m = 1; m < 64; m <<= 1) {
    s += __shfl_xor(s, m);
    ss += __shfl_xor(ss, m);
  }
  float mu = s * (1.0f / NE);
  float var = ss * (1.0f / NE) - mu * mu;
  float rstd = rsqrtf(var + 1e-5f);
#pragma unroll
  for (int i = 0; i < 3; ++i) {
    float4 gv = *reinterpret_cast<const float4*>(g + l * 4 + i * 256);
    float4 bv = *reinterpret_cast<const float4*>(b + l * 4 + i * 256);
    short4 o;
    o.x = f2bf((v[i].x - mu) * rstd * gv.x + bv.x);
    o.y = f2bf((v[i].y - mu) * rstd * gv.y + bv.y);
    o.z = f2bf((v[i].z - mu) * rstd * gv.z + bv.z);
    o.w = f2bf((v[i].w - mu) * rstd * gv.w + bv.w);
    *reinterpret_cast<short4*>(out + (size_t)row * NE + l * 4 + i * 256) = o;
  }
}

// ---------------- GEMM 128x128, BK=32, 3-buf depth-2 pipeline, XCD remap ----
template <int EPI>
__global__ __launch_bounds__(256) void gemm_kernel(
    const short* __restrict__ A, const short* __restrict__ Bt,
    const float* __restrict__ bias, const float* __restrict__ resid,
    void* __restrict__ Cout, int M, int N, int K, int nbn) {
  __shared__ short As[3][128 * 32];
  __shared__ short Bs[3][128 * 32];
  int t = threadIdx.x;
  int w = t >> 6, l = t & 63;
  int wr = w >> 1, wc = w & 1;
  int bm, bn;
  xcd_remap(blockIdx.x, nbn, bm, bn);
  int lr = l & 15, g4 = l >> 4;

  f32x4 acc[4][4];
#pragma unroll
  for (int i = 0; i < 4; ++i)
#pragma unroll
    for (int j = 0; j < 4; ++j) acc[i][j] = (f32x4){0.f, 0.f, 0.f, 0.f};

  int r0 = t >> 2;
  int cs = ((t & 3) ^ (r0 & 3)) * 8;
  const short* ga = A + (size_t)(bm * 128) * K;
  const short* gb = Bt + (size_t)(bn * 128) * K;

  // prologue: stage tiles 0,1 into buffers 0,1
#pragma unroll
  for (int p = 0; p < 2; ++p) {
    int ko = p * 32;
    gload16(ga + (size_t)r0 * K + ko + cs, &As[p][t * 8]);
    gload16(ga + (size_t)(r0 + 64) * K + ko + cs, &As[p][(t + 256) * 8]);
    gload16(gb + (size_t)r0 * K + ko + cs, &Bs[p][t * 8]);
    gload16(gb + (size_t)(r0 + 64) * K + ko + cs, &Bs[p][(t + 256) * 8]);
  }

  int xorA = (lr & 3) << 4;
  int nk = K >> 5;
  int cur = 0, prv = 2;
  for (int kt = 0; kt < nk; ++kt) {
    if (kt < nk - 1) WAITV(4); else WAITV(0);  // oldest tile landed (this wave)
    BARSYNC();                                  // all waves' quarters landed
    if (kt + 2 < nk) {                          // issue t+2 into freed buffer
      int ko = (kt + 2) * 32;
      gload16(ga + (size_t)r0 * K + ko + cs, &As[prv][t * 8]);
      gload16(ga + (size_t)(r0 + 64) * K + ko + cs, &As[prv][(t + 256) * 8]);
      gload16(gb + (size_t)r0 * K + ko + cs, &Bs[prv][t * 8]);
      gload16(gb + (size_t)(r0 + 64) * K + ko + cs, &Bs[prv][(t + 256) * 8]);
    }
    __builtin_amdgcn_sched_barrier(0);          // pin issue before compute
    const char* Ab = (const char*)As[cur];
    const char* Bb = (const char*)Bs[cur];
    bf16x8 af[4], bfr[4];
#pragma unroll
    for (int i = 0; i < 4; ++i)
      af[i] = *reinterpret_cast<const bf16x8*>(
          Ab + (((wr * 64 + i * 16 + lr) * 64 + g4 * 16) ^ xorA));
#pragma unroll
    for (int j = 0; j < 4; ++j)
      bfr[j] = *reinterpret_cast<const bf16x8*>(
          Bb + (((wc * 64 + j * 16 + lr) * 64 + g4 * 16) ^ xorA));
#pragma unroll
    for (int i = 0; i < 4; ++i)
#pragma unroll
      for (int j = 0; j < 4; ++j)
        acc[i][j] = __builtin_amdgcn_mfma_f32_16x16x32_bf16(af[i], bfr[j], acc[i][j], 0, 0, 0);
    prv = cur;
    cur = (cur == 2) ? 0 : cur + 1;
  }

  int rbase = bm * 128 + wr * 64;
  int cbase = bn * 128 + wc * 64;
#pragma unroll
  for (int i = 0; i < 4; ++i) {
#pragma unroll
    for (int r = 0; r < 4; ++r) {
      int row = rbase + i * 16 + g4 * 4 + r;
#pragma unroll
      for (int j = 0; j < 4; ++j) {
        int col = cbase + j * 16 + lr;
        float v = acc[i][j][r] + bias[col];
        if (EPI == 0) {
          ((short*)Cout)[(size_t)row * N + col] = f2bf(v);
        } else if (EPI == 1) {
          v = 0.5f * v * (1.0f + erff(v * 0.70710678118654752f));
          ((short*)Cout)[(size_t)row * N + col] = f2bf(v);
        } else {
          ((float*)Cout)[(size_t)row * N + col] = v + resid[(size_t)row * N + col];
        }
      }
    }
  }
}

// ---------------- GEMM 128x64, BK=32, 4-buf depth-3 pipeline, XCD remap -----
template <int EPI>
__global__ __launch_bounds__(256) void gemm64_kernel(
    const short* __restrict__ A, const short* __restrict__ Bt,
    const float* __restrict__ bias, const float* __restrict__ resid,
    void* __restrict__ Cout, int M, int N, int K, int nbn) {
  __shared__ short As[4][128 * 32];
  __shared__ short Bs[4][64 * 32];
  int t = threadIdx.x;
  int w = t >> 6, l = t & 63;
  int bm, bn;
  xcd_remap(blockIdx.x, nbn, bm, bn);
  int lr = l & 15, g4 = l >> 4;

  f32x4 acc[2][4];
#pragma unroll
  for (int i = 0; i < 2; ++i)
#pragma unroll
    for (int j = 0; j < 4; ++j) acc[i][j] = (f32x4){0.f, 0.f, 0.f, 0.f};

  int r0 = t >> 2;
  int cs = ((t & 3) ^ (r0 & 3)) * 8;
  const short* ga = A + (size_t)(bm * 128) * K;
  const short* gb = Bt + (size_t)(bn * 64) * K;

  // prologue: stage tiles 0,1,2 into buffers 0,1,2
#pragma unroll
  for (int p = 0; p < 3; ++p) {
    int ko = p * 32;
    gload16(ga + (size_t)r0 * K + ko + cs, &As[p][t * 8]);
    gload16(ga + (size_t)(r0 + 64) * K + ko + cs, &As[p][(t + 256) * 8]);
    gload16(gb + (size_t)r0 * K + ko + cs, &Bs[p][t * 8]);
  }

  int xorA = (lr & 3) << 4;
  int nk = K >> 5;
  for (int kt = 0; kt < nk; ++kt) {
    int bi = kt & 3;
    int rem = nk - 1 - kt;
    if (rem >= 2) WAITV(6);
    else if (rem == 1) WAITV(3);
    else WAITV(0);
    BARSYNC();
    if (kt + 3 < nk) {   // issue t+3 into buf (t-1)&3 (freed by this barrier)
      int ko = (kt + 3) * 32;
      int nb = (kt + 3) & 3;
      gload16(ga + (size_t)r0 * K + ko + cs, &As[nb][t * 8]);
      gload16(ga + (size_t)(r0 + 64) * K + ko + cs, &As[nb][(t + 256) * 8]);
      gload16(gb + (size_t)r0 * K + ko + cs, &Bs[nb][t * 8]);
    }
    __builtin_amdgcn_sched_barrier(0);
    const char* Ab = (const char*)As[bi];
    const char* Bb = (const char*)Bs[bi];
    bf16x8 af[2], bfr[4];
#pragma unroll
    for (int i = 0; i < 2; ++i)
      af[i] = *reinterpret_cast<const bf16x8*>(
          Ab + (((w * 32 + i * 16 + lr) * 64 + g4 * 16) ^ xorA));
#pragma unroll
    for (int j = 0; j < 4; ++j)
      bfr[j] = *reinterpret_cast<const bf16x8*>(
          Bb + (((j * 16 + lr) * 64 + g4 * 16) ^ xorA));
#pragma unroll
    for (int i = 0; i < 2; ++i)
#pragma unroll
      for (int j = 0; j < 4; ++j)
        acc[i][j] = __builtin_amdgcn_mfma_f32_16x16x32_bf16(af[i], bfr[j], acc[i][j], 0, 0, 0);
  }

  int rbase = bm * 128 + w * 32;
  int cbase = bn * 64;
#pragma unroll
  for (int i = 0; i < 2; ++i) {
#pragma unroll
    for (int r = 0; r < 4; ++r) {
      int row = rbase + i * 16 + g4 * 4 + r;
#pragma unroll
      for (int j = 0; j < 4; ++j) {
        int col = cbase + j * 16 + lr;
        float v = acc[i][j][r] + bias[col];
        if (EPI == 0) {
          ((short*)Cout)[(size_t)row * N + col] = f2bf(v);
        } else if (EPI == 1) {
          v = 0.5f * v * (1.0f + erff(v * 0.70710678118654752f));
          ((short*)Cout)[(size_t)row * N + col] = f2bf(v);
        } else {
          ((float*)Cout)[(size_t)row * N + col] = v + resid[(size_t)row * N + col];
        }
      }
    }
  }
}

// ---------------- causal flash attention, QBLK=64, KVBLK=64, dbuf -----------
// K and pre-transposed V^T both staged via global_load_lds (swizzled source).
// Swapped QK^T + in-register softmax (defer-rescale) + shfl-built P frags.
// qkv: [ROWS][3*NE] bf16. vt: [48][HD][TT] bf16. y: [ROWS][NE] bf16.
__global__ __launch_bounds__(256, 4) void attn_kernel(
    const short* __restrict__ qkv, const short* __restrict__ vt,
    short* __restrict__ y) {
  __shared__ short Ks[2][64 * 64];   // [kpos][hd], XOR-swizzled
  __shared__ short Vs[2][64 * 64];   // [hd][kpos], XOR-swizzled
  int t = threadIdx.x, w = t >> 6, l = t & 63;
  int lr = l & 15, g = l >> 4, lkb = g * 8;
  int bh = blockIdx.x;               // XCD = bh % 8 (48 % 8 == 0)
  int b = bh / NH, h = bh % NH;
  int qt = ((int)gridDim.y - 1) - blockIdx.y;   // longest blocks first
  int qbase = qt * 64;
  const int rstride = 3 * NE;

  // Q fragments (B-operand: col=qrow, k=hd): rows qbase + w*16 + lr
  const short* qrow = qkv + (size_t)(b * TT + qbase + w * 16 + lr) * rstride + h * HD + lkb;
  bf16x8 qf0 = *reinterpret_cast<const bf16x8*>(qrow);
  bf16x8 qf1 = *reinterpret_cast<const bf16x8*>(qrow + 32);

  f32x4 o[4];
#pragma unroll
  for (int j = 0; j < 4; ++j) o[j] = (f32x4){0.f, 0.f, 0.f, 0.f};
  float m_run = -3e38f, l_run = 0.f;   // per-lane q-row: qbase + w*16 + lr

  // staging geometry: 16B chunk ids; row = id>>3, col pre-swizzled
  int ci0 = t, ci1 = t + 256;
  int row0 = ci0 >> 3, c0 = ((ci0 & 7) ^ (row0 & 7)) * 8;
  int row1 = ci1 >> 3, c1 = ((ci1 & 7) ^ (row1 & 7)) * 8;

  const short* kbase = qkv + (size_t)(b * TT) * rstride + NE + h * HD;
  const short* vtb = vt + (size_t)bh * HD * TT;

  // --- prologue: stage tile 0 into buffer 0 ---
  gload16(kbase + (size_t)row0 * rstride + c0, &Ks[0][ci0 * 8]);
  gload16(kbase + (size_t)row1 * rstride + c1, &Ks[0][ci1 * 8]);
  gload16(vtb + (size_t)row0 * TT + c0, &Vs[0][ci0 * 8]);
  gload16(vtb + (size_t)row1 * TT + c1, &Vs[0][ci1 * 8]);

  int qmin = qbase + w * 16;
  int srcA = ((g & 1) * 2) * 16 + lr;   // shfl src lanes for P-frag build
  int srcB = srcA + 16;
  bool ghi = (g >= 2);

  int nkv = qt + 1;
  for (int kt = 0; kt < nkv; ++kt) {
    int bi = kt & 1;
    int kvbase = kt * 64;
    bool pre = (kt + 1 < nkv);
    __syncthreads();   // buf bi ready (vmcnt drained by barrier)

    if (pre) {   // issue next tile's DMA (hides under this tile's compute)
      int nb = kvbase + 64;
      gload16(kbase + (size_t)(nb + row0) * rstride + c0, &Ks[bi ^ 1][ci0 * 8]);
      gload16(kbase + (size_t)(nb + row1) * rstride + c1, &Ks[bi ^ 1][ci1 * 8]);
      gload16(vtb + (size_t)row0 * TT + nb + c0, &Vs[bi ^ 1][ci0 * 8]);
      gload16(vtb + (size_t)row1 * TT + nb + c1, &Vs[bi ^ 1][ci1 * 8]);
    }

    // --- QK^T (swapped): s[nt][r] = S^T[kpos=kvbase+nt*16+g*4+r][qrow=lr]
    f32x4 s[4];
#pragma unroll
    for (int nt = 0; nt < 4; ++nt) {
      int row = nt * 16 + lr;
      bf16x8 kf0 = *reinterpret_cast<const bf16x8*>(
          (char*)Ks[bi] + ((row * 128 + lkb * 2) ^ ((lr & 7) << 4)));
      bf16x8 kf1 = *reinterpret_cast<const bf16x8*>(
          (char*)Ks[bi] + ((row * 128 + 64 + lkb * 2) ^ ((lr & 7) << 4)));
      f32x4 st = (f32x4){0.f, 0.f, 0.f, 0.f};
      st = __builtin_amdgcn_mfma_f32_16x16x32_bf16(kf0, qf0, st, 0, 0, 0);
      st = __builtin_amdgcn_mfma_f32_16x16x32_bf16(kf1, qf1, st, 0, 0, 0);
      s[nt] = st;
    }

    // --- mask/scale ---
    if (kvbase + 63 > qmin) {   // diagonal tile
      int qabs = qmin + lr;
#pragma unroll
      for (int nt = 0; nt < 4; ++nt)
#pragma unroll
        for (int r = 0; r < 4; ++r) {
          int kp = kvbase + nt * 16 + g * 4 + r;
          s[nt][r] = (kp <= qabs) ? s[nt][r] * 0.125f : -3e38f;
        }
    } else {
#pragma unroll
      for (int nt = 0; nt < 4; ++nt)
#pragma unroll
        for (int r = 0; r < 4; ++r)
          s[nt][r] *= 0.125f;
    }

    // --- online softmax, in-register, defer-rescale (T13, THR=8) ---
    float mx = s[0][0];
#pragma unroll
    for (int nt = 0; nt < 4; ++nt)
#pragma unroll
      for (int r = 0; r < 4; ++r) mx = fmaxf(mx, s[nt][r]);
    mx = fmaxf(mx, __shfl_xor(mx, 16));
    mx = fmaxf(mx, __shfl_xor(mx, 32));
    if (__any(mx > m_run + 8.f)) {
      float mn = fmaxf(m_run, mx);
      float al = __expf(m_run - mn);
      m_run = mn;
      l_run *= al;
      float al0 = __shfl(al, g * 4 + 0);
      float al1 = __shfl(al, g * 4 + 1);
      float al2 = __shfl(al, g * 4 + 2);
      float al3 = __shfl(al, g * 4 + 3);
#pragma unroll
      for (int j = 0; j < 4; ++j) {
        o[j][0] *= al0; o[j][1] *= al1; o[j][2] *= al2; o[j][3] *= al3;
      }
    }
    float rs = 0.f;
#pragma unroll
    for (int nt = 0; nt < 4; ++nt)
#pragma unroll
      for (int r = 0; r < 4; ++r) {
        float p = __expf(s[nt][r] - m_run);
        s[nt][r] = p;
        rs += p;
      }
    rs += __shfl_xor(rs, 16);
    rs += __shfl_xor(rs, 32);
    l_run += rs;

    // --- pack P to bf16 pairs ---
    unsigned int pw[4][2];
#pragma unroll
    for (int nt = 0; nt < 4; ++nt)
#pragma unroll
      for (int pr = 0; pr < 2; ++pr)
        pw[nt][pr] = (unsigned int)(unsigned short)f2bf(s[nt][2 * pr]) |
                     ((unsigned int)(unsigned short)f2bf(s[nt][2 * pr + 1]) << 16);

    // --- PV: build P A-frag per 32-k chunk via shfl, then MFMA ---
#pragma unroll
    for (int c = 0; c < 2; ++c) {
      unsigned int a00 = __shfl(pw[c * 2 + 0][0], srcA);
      unsigned int a01 = __shfl(pw[c * 2 + 0][1], srcA);
      unsigned int a02 = __shfl(pw[c * 2 + 0][0], srcB);
      unsigned int a03 = __shfl(pw[c * 2 + 0][1], srcB);
      unsigned int a10 = __shfl(pw[c * 2 + 1][0], srcA);
      unsigned int a11 = __shfl(pw[c * 2 + 1][1], srcA);
      unsigned int a12 = __shfl(pw[c * 2 + 1][0], srcB);
      unsigned int a13 = __shfl(pw[c * 2 + 1][1], srcB);
      unsigned int u0 = ghi ? a10 : a00;
      unsigned int u1 = ghi ? a11 : a01;
      unsigned int u2 = ghi ? a12 : a02;
      unsigned int u3 = ghi ? a13 : a03;
      bf16x8 pa;
      pa[0] = (short)(u0 & 0xffffu); pa[1] = (short)(u0 >> 16);
      pa[2] = (short)(u1 & 0xffffu); pa[3] = (short)(u1 >> 16);
      pa[4] = (short)(u2 & 0xffffu); pa[5] = (short)(u2 >> 16);
      pa[6] = (short)(u3 & 0xffffu); pa[7] = (short)(u3 >> 16);
#pragma unroll
      for (int j = 0; j < 4; ++j) {
        int vrow = j * 16 + lr;
        bf16x8 vf = *reinterpret_cast<const bf16x8*>(
            (char*)Vs[bi] + ((vrow * 128 + c * 64 + lkb * 2) ^ ((lr & 7) << 4)));
        o[j] = __builtin_amdgcn_mfma_f32_16x16x32_bf16(pa, vf, o[j], 0, 0, 0);
      }
    }
  }

  // --- epilogue: normalize (inv at lane (row); o rows are g*4+r) ---
  float inv = 1.0f / l_run;
  float i0 = __shfl(inv, g * 4 + 0);
  float i1 = __shfl(inv, g * 4 + 1);
  float i2 = __shfl(inv, g * 4 + 2);
  float i3 = __shfl(inv, g * 4 + 3);
#pragma unroll
  for (int r = 0; r < 4; ++r) {
    float ir = (r == 0) ? i0 : (r == 1) ? i1 : (r == 2) ? i2 : i3;
    size_t row = (size_t)(b * TT + qbase + w * 16 + g * 4 + r);
#pragma unroll
    for (int j = 0; j < 4; ++j)
      y[row * NE + h * HD + j * 16 + lr] = f2bf(o[j][r] * ir);
  }
}

extern "C" void kernel_launch(void* const* d_in, const int* in_sizes, int n_in,
                              void* d_out, int out_size, void* d_ws, size_t ws_size,
                              hipStream_t stream) {
  (void)in_sizes; (void)n_in; (void)out_size; (void)ws_size;
  const float* x       = (const float*)d_in[0];
  const float* ln1_g   = (const float*)d_in[1];
  const float* ln1_b   = (const float*)d_in[2];
  const float* w_attn  = (const float*)d_in[3];
  const float* b_attn  = (const float*)d_in[4];
  const float* w_aproj = (const float*)d_in[5];
  const float* b_aproj = (const float*)d_in[6];
  const float* ln2_g   = (const float*)d_in[7];
  const float* ln2_b   = (const float*)d_in[8];
  const float* w_fc    = (const float*)d_in[9];
  const float* b_fc    = (const float*)d_in[10];
  const float* w_mproj = (const float*)d_in[11];
  const float* b_mproj = (const float*)d_in[12];

  char* ws = (char*)d_ws;
  size_t off = 0;
  auto alloc = [&](size_t bytes) {
    char* p = ws + off;
    off += (bytes + 255) & ~(size_t)255;
    return p;
  };
  short* wt_attn  = (short*)alloc((size_t)2304 * 768 * 2);
  short* wt_aproj = (short*)alloc((size_t)768 * 768 * 2);
  short* wt_fc    = (short*)alloc((size_t)3072 * 768 * 2);
  short* wt_mproj = (short*)alloc((size_t)768 * 3072 * 2);
  short* lnb  = (short*)alloc((size_t)ROWS * 768 * 2);
  short* qkvb = (short*)alloc((size_t)ROWS * 3072 * 2);
  short* yb   = (short*)alloc((size_t)ROWS * 768 * 2);
  float* x2   = (float*)alloc((size_t)ROWS * 768 * 4);
  // vt aliases lnb: lnb (ln1 out) is dead after the qkv GEMM; ln2 rewrites it
  // after attention completes. Sizes match exactly (8192*768*2 B).
  short* vtg = lnb;

  wtrans_kernel<<<dim3(768 / 64, 2304 / 64), 256, 0, stream>>>(w_attn, wt_attn, 768, 2304);
  wtrans_kernel<<<dim3(768 / 64, 768 / 64), 256, 0, stream>>>(w_aproj, wt_aproj, 768, 768);
  wtrans_kernel<<<dim3(768 / 64, 3072 / 64), 256, 0, stream>>>(w_fc, wt_fc, 768, 3072);
  wtrans_kernel<<<dim3(3072 / 64, 768 / 64), 256, 0, stream>>>(w_mproj, wt_mproj, 3072, 768);

  ln_kernel<<<ROWS, 64, 0, stream>>>(x, ln1_g, ln1_b, lnb);
  gemm_kernel<0><<<64 * 18, 256, 0, stream>>>(
      lnb, wt_attn, b_attn, nullptr, qkvb, ROWS, 2304, 768, 18);
  vtrans_kernel<<<dim3(BB * NH, TT / 64), 256, 0, stream>>>(qkvb, vtg);
  attn_kernel<<<dim3(BB * NH, TT / 64), 256, 0, stream>>>(qkvb, vtg, yb);
  gemm64_kernel<2><<<64 * 12, 256, 0, stream>>>(
      yb, wt_aproj, b_aproj, x, x2, ROWS, 768, 768, 12);
  ln_kernel<<<ROWS, 64, 0, stream>>>(x2, ln2_g, ln2_b, lnb);
  gemm_kernel<1><<<64 * 24, 256, 0, stream>>>(
      lnb, wt_fc, b_fc, nullptr, qkvb, ROWS, 3072, 768, 24);
  gemm64_kernel<2><<<64 * 12, 256, 0, stream>>>(
      qkvb, wt_mproj, b_mproj, x2, (float*)d_out, ROWS, 768, 3072, 12);
}

// Round 11
// 290.278 us; speedup vs baseline: 1.5298x; 1.0470x over previous
//
#include <hip/hip_runtime.h>
#include <hip/hip_bf16.h>

#define NE 768
#define NH 12
#define HD 64
#define BB 4
#define TT 2048
#define ROWS (BB*TT)  // 8192
#define QSCALE 0.18033688011112042f  // 0.125 * log2(e): softmax in exp2 domain

typedef __attribute__((ext_vector_type(8))) short bf16x8;
typedef __attribute__((ext_vector_type(4))) float f32x4;

#define WAITV(N) asm volatile("s_waitcnt vmcnt(" #N ")" ::: "memory")
#define BARSYNC()                                   \
  do {                                              \
    __builtin_amdgcn_sched_barrier(0);              \
    __builtin_amdgcn_s_barrier();                   \
    __builtin_amdgcn_sched_barrier(0);              \
  } while (0)

__device__ __forceinline__ short f2bf(float f) {
  __hip_bfloat16 h = __float2bfloat16(f);
  union { __hip_bfloat16 h; short s; } u; u.h = h; return u.s;
}

__device__ __forceinline__ float exp2fast(float x) {
  float r;
  asm("v_exp_f32 %0, %1" : "=v"(r) : "v"(x));
  return r;
}

__device__ __forceinline__ unsigned int cvtpk(float lo, float hi) {
  unsigned int r;
  asm("v_cvt_pk_bf16_f32 %0, %1, %2" : "=v"(r) : "v"(lo), "v"(hi));
  return r;
}

__device__ __forceinline__ void gload16(const void* g, void* l) {
  __builtin_amdgcn_global_load_lds(
      (const __attribute__((address_space(1))) void*)g,
      (__attribute__((address_space(3))) void*)l,
      16, 0, 0);
}

__device__ __forceinline__ void xcd_remap(int id, int nbn, int& bm, int& bn) {
  int x = id & 7;
  int j = id >> 3;
  bm = x * 8 + j / nbn;
  bn = j % nbn;
}

// ---------------- merged weight transpose: all 4 weights in one launch ------
__global__ __launch_bounds__(256) void wtrans_all_kernel(
    const float* __restrict__ w_attn, const float* __restrict__ w_aproj,
    const float* __restrict__ w_fc, const float* __restrict__ w_mproj,
    short* __restrict__ o_attn, short* __restrict__ o_aproj,
    short* __restrict__ o_fc, short* __restrict__ o_mproj) {
  __shared__ short tile[64 * 65];
  int id = blockIdx.x;
  const float* W; short* Wt; int K, N, bx, by;
  if (id < 432)       { W = w_attn;  Wt = o_attn;  K = 768;  N = 2304; bx = id % 12;  by = id / 12; }
  else if (id < 576)  { id -= 432;  W = w_aproj; Wt = o_aproj; K = 768;  N = 768;  bx = id % 12;  by = id / 12; }
  else if (id < 1152) { id -= 576;  W = w_fc;    Wt = o_fc;    K = 768;  N = 3072; bx = id % 12;  by = id / 12; }
  else                { id -= 1152; W = w_mproj; Wt = o_mproj; K = 3072; N = 768;  bx = id % 48;  by = id / 48; }
  int k0 = bx * 64, n0 = by * 64;
  int t = threadIdx.x;
#pragma unroll
  for (int p = 0; p < 16; ++p) {
    int idx = p * 256 + t;
    int r = idx >> 6, c = idx & 63;
    tile[r * 65 + c] = f2bf(W[(size_t)(k0 + r) * N + n0 + c]);
  }
  __syncthreads();
#pragma unroll
  for (int p = 0; p < 16; ++p) {
    int idx = p * 256 + t;
    int rr = idx >> 6, cc = idx & 63;
    Wt[(size_t)(n0 + rr) * K + k0 + cc] = tile[cc * 65 + rr];
  }
}

// ---------------- V transpose: qkv V-part -> Vt[bh][hd][tloc] bf16 ----------
__global__ __launch_bounds__(256) void vtrans_kernel(
    const short* __restrict__ qkv, short* __restrict__ vt) {
  __shared__ short tile[64 * 65];
  int bh = blockIdx.x;
  int b = bh / NH, h = bh % NH;
  int t0 = blockIdx.y * 64;
  int t = threadIdx.x;
#pragma unroll
  for (int p = 0; p < 16; ++p) {
    int idx = p * 256 + t;
    int r = idx >> 6, c = idx & 63;   // r = tloc, c = hd
    tile[r * 65 + c] =
        qkv[(size_t)(b * TT + t0 + r) * (3 * NE) + 2 * NE + h * HD + c];
  }
  __syncthreads();
#pragma unroll
  for (int p = 0; p < 16; ++p) {
    int idx = p * 256 + t;
    int rr = idx >> 6, cc = idx & 63; // rr = hd, cc = tloc
    vt[(size_t)bh * HD * TT + (size_t)rr * TT + t0 + cc] = tile[cc * 65 + rr];
  }
}

// ---------------- LayerNorm: fp32 in -> bf16 out, one wave per row ----------
__global__ __launch_bounds__(64) void ln_kernel(
    const float* __restrict__ x, const float* __restrict__ g,
    const float* __restrict__ b, short* __restrict__ out) {
  int row = blockIdx.x, l = threadIdx.x;
  const float* xr = x + (size_t)row * NE;
  float4 v[3];
  float s = 0.f, ss = 0.f;
#pragma unroll
  for (int i = 0; i < 3; ++i) {
    v[i] = *reinterpret_cast<const float4*>(xr + l * 4 + i * 256);
    s += v[i].x + v[i].y + v[i].z + v[i].w;
    ss += v[i].x * v[i].x + v[i].y * v[i].y + v[i].z * v[i].z + v[i].w * v[i].w;
  }
#pragma unroll
  for (int m = 1; m < 64; m <<= 1) {
    s += __shfl_xor(s, m);
    ss += __shfl_xor(ss, m);
  }
  float mu = s * (1.0f / NE);
  float var = ss * (1.0f / NE) - mu * mu;
  float rstd = rsqrtf(var + 1e-5f);
#pragma unroll
  for (int i = 0; i < 3; ++i) {
    float4 gv = *reinterpret_cast<const float4*>(g + l * 4 + i * 256);
    float4 bv = *reinterpret_cast<const float4*>(b + l * 4 + i * 256);
    short4 o;
    o.x = f2bf((v[i].x - mu) * rstd * gv.x + bv.x);
    o.y = f2bf((v[i].y - mu) * rstd * gv.y + bv.y);
    o.z = f2bf((v[i].z - mu) * rstd * gv.z + bv.z);
    o.w = f2bf((v[i].w - mu) * rstd * gv.w + bv.w);
    *reinterpret_cast<short4*>(out + (size_t)row * NE + l * 4 + i * 256) = o;
  }
}

// ---------------- GEMM 128x128, BK=32, 3-buf depth-2 pipeline, XCD remap ----
// EPI 0: qkv out (Q cols pre-scaled by QSCALE for exp2-domain softmax)
template <int EPI>
__global__ __launch_bounds__(256) void gemm_kernel(
    const short* __restrict__ A, const short* __restrict__ Bt,
    const float* __restrict__ bias, const float* __restrict__ resid,
    void* __restrict__ Cout, int M, int N, int K, int nbn) {
  __shared__ short As[3][128 * 32];
  __shared__ short Bs[3][128 * 32];
  int t = threadIdx.x;
  int w = t >> 6, l = t & 63;
  int wr = w >> 1, wc = w & 1;
  int bm, bn;
  xcd_remap(blockIdx.x, nbn, bm, bn);
  int lr = l & 15, g4 = l >> 4;

  f32x4 acc[4][4];
#pragma unroll
  for (int i = 0; i < 4; ++i)
#pragma unroll
    for (int j = 0; j < 4; ++j) acc[i][j] = (f32x4){0.f, 0.f, 0.f, 0.f};

  int r0 = t >> 2;
  int cs = ((t & 3) ^ (r0 & 3)) * 8;
  const short* ga = A + (size_t)(bm * 128) * K;
  const short* gb = Bt + (size_t)(bn * 128) * K;

#pragma unroll
  for (int p = 0; p < 2; ++p) {
    int ko = p * 32;
    gload16(ga + (size_t)r0 * K + ko + cs, &As[p][t * 8]);
    gload16(ga + (size_t)(r0 + 64) * K + ko + cs, &As[p][(t + 256) * 8]);
    gload16(gb + (size_t)r0 * K + ko + cs, &Bs[p][t * 8]);
    gload16(gb + (size_t)(r0 + 64) * K + ko + cs, &Bs[p][(t + 256) * 8]);
  }

  int xorA = (lr & 3) << 4;
  int nk = K >> 5;
  int cur = 0, prv = 2;
  for (int kt = 0; kt < nk; ++kt) {
    if (kt < nk - 1) WAITV(4); else WAITV(0);
    BARSYNC();
    if (kt + 2 < nk) {
      int ko = (kt + 2) * 32;
      gload16(ga + (size_t)r0 * K + ko + cs, &As[prv][t * 8]);
      gload16(ga + (size_t)(r0 + 64) * K + ko + cs, &As[prv][(t + 256) * 8]);
      gload16(gb + (size_t)r0 * K + ko + cs, &Bs[prv][t * 8]);
      gload16(gb + (size_t)(r0 + 64) * K + ko + cs, &Bs[prv][(t + 256) * 8]);
    }
    __builtin_amdgcn_sched_barrier(0);
    const char* Ab = (const char*)As[cur];
    const char* Bb = (const char*)Bs[cur];
    bf16x8 af[4], bfr[4];
#pragma unroll
    for (int i = 0; i < 4; ++i)
      af[i] = *reinterpret_cast<const bf16x8*>(
          Ab + (((wr * 64 + i * 16 + lr) * 64 + g4 * 16) ^ xorA));
#pragma unroll
    for (int j = 0; j < 4; ++j)
      bfr[j] = *reinterpret_cast<const bf16x8*>(
          Bb + (((wc * 64 + j * 16 + lr) * 64 + g4 * 16) ^ xorA));
#pragma unroll
    for (int i = 0; i < 4; ++i)
#pragma unroll
      for (int j = 0; j < 4; ++j)
        acc[i][j] = __builtin_amdgcn_mfma_f32_16x16x32_bf16(af[i], bfr[j], acc[i][j], 0, 0, 0);
    prv = cur;
    cur = (cur == 2) ? 0 : cur + 1;
  }

  int rbase = bm * 128 + wr * 64;
  int cbase = bn * 128 + wc * 64;
#pragma unroll
  for (int i = 0; i < 4; ++i) {
#pragma unroll
    for (int r = 0; r < 4; ++r) {
      int row = rbase + i * 16 + g4 * 4 + r;
#pragma unroll
      for (int j = 0; j < 4; ++j) {
        int col = cbase + j * 16 + lr;
        float v = acc[i][j][r] + bias[col];
        if (EPI == 0) {
          // Q columns pre-scaled so attn softmax runs in exp2 domain
          if (col < NE) v *= QSCALE;
          ((short*)Cout)[(size_t)row * N + col] = f2bf(v);
        } else if (EPI == 1) {
          v = 0.5f * v * (1.0f + erff(v * 0.70710678118654752f));
          ((short*)Cout)[(size_t)row * N + col] = f2bf(v);
        } else {
          ((float*)Cout)[(size_t)row * N + col] = v + resid[(size_t)row * N + col];
        }
      }
    }
  }
}

// ---------------- GEMM 128x64, BK=32, 4-buf depth-3 pipeline, XCD remap -----
template <int EPI>
__global__ __launch_bounds__(256) void gemm64_kernel(
    const short* __restrict__ A, const short* __restrict__ Bt,
    const float* __restrict__ bias, const float* __restrict__ resid,
    void* __restrict__ Cout, int M, int N, int K, int nbn) {
  __shared__ short As[4][128 * 32];
  __shared__ short Bs[4][64 * 32];
  int t = threadIdx.x;
  int w = t >> 6, l = t & 63;
  int bm, bn;
  xcd_remap(blockIdx.x, nbn, bm, bn);
  int lr = l & 15, g4 = l >> 4;

  f32x4 acc[2][4];
#pragma unroll
  for (int i = 0; i < 2; ++i)
#pragma unroll
    for (int j = 0; j < 4; ++j) acc[i][j] = (f32x4){0.f, 0.f, 0.f, 0.f};

  int r0 = t >> 2;
  int cs = ((t & 3) ^ (r0 & 3)) * 8;
  const short* ga = A + (size_t)(bm * 128) * K;
  const short* gb = Bt + (size_t)(bn * 64) * K;

#pragma unroll
  for (int p = 0; p < 3; ++p) {
    int ko = p * 32;
    gload16(ga + (size_t)r0 * K + ko + cs, &As[p][t * 8]);
    gload16(ga + (size_t)(r0 + 64) * K + ko + cs, &As[p][(t + 256) * 8]);
    gload16(gb + (size_t)r0 * K + ko + cs, &Bs[p][t * 8]);
  }

  int xorA = (lr & 3) << 4;
  int nk = K >> 5;
  for (int kt = 0; kt < nk; ++kt) {
    int bi = kt & 3;
    int rem = nk - 1 - kt;
    if (rem >= 2) WAITV(6);
    else if (rem == 1) WAITV(3);
    else WAITV(0);
    BARSYNC();
    if (kt + 3 < nk) {
      int ko = (kt + 3) * 32;
      int nb = (kt + 3) & 3;
      gload16(ga + (size_t)r0 * K + ko + cs, &As[nb][t * 8]);
      gload16(ga + (size_t)(r0 + 64) * K + ko + cs, &As[nb][(t + 256) * 8]);
      gload16(gb + (size_t)r0 * K + ko + cs, &Bs[nb][t * 8]);
    }
    __builtin_amdgcn_sched_barrier(0);
    const char* Ab = (const char*)As[bi];
    const char* Bb = (const char*)Bs[bi];
    bf16x8 af[2], bfr[4];
#pragma unroll
    for (int i = 0; i < 2; ++i)
      af[i] = *reinterpret_cast<const bf16x8*>(
          Ab + (((w * 32 + i * 16 + lr) * 64 + g4 * 16) ^ xorA));
#pragma unroll
    for (int j = 0; j < 4; ++j)
      bfr[j] = *reinterpret_cast<const bf16x8*>(
          Bb + (((j * 16 + lr) * 64 + g4 * 16) ^ xorA));
#pragma unroll
    for (int i = 0; i < 2; ++i)
#pragma unroll
      for (int j = 0; j < 4; ++j)
        acc[i][j] = __builtin_amdgcn_mfma_f32_16x16x32_bf16(af[i], bfr[j], acc[i][j], 0, 0, 0);
  }

  int rbase = bm * 128 + w * 32;
  int cbase = bn * 64;
#pragma unroll
  for (int i = 0; i < 2; ++i) {
#pragma unroll
    for (int r = 0; r < 4; ++r) {
      int row = rbase + i * 16 + g4 * 4 + r;
#pragma unroll
      for (int j = 0; j < 4; ++j) {
        int col = cbase + j * 16 + lr;
        float v = acc[i][j][r] + bias[col];
        if (EPI == 0) {
          ((short*)Cout)[(size_t)row * N + col] = f2bf(v);
        } else if (EPI == 1) {
          v = 0.5f * v * (1.0f + erff(v * 0.70710678118654752f));
          ((short*)Cout)[(size_t)row * N + col] = f2bf(v);
        } else {
          ((float*)Cout)[(size_t)row * N + col] = v + resid[(size_t)row * N + col];
        }
      }
    }
  }
}

// ---------------- causal flash attention, QBLK=64, KVBLK=64, dbuf -----------
// Q pre-scaled by 0.125*log2e -> softmax in exp2 domain (bare v_exp_f32).
// cvt_pk bf16 pack; P-frag via shfl + dword union. Defer-rescale THR=11.54.
__global__ __launch_bounds__(256, 4) void attn_kernel(
    const short* __restrict__ qkv, const short* __restrict__ vt,
    short* __restrict__ y) {
  __shared__ short Ks[2][64 * 64];   // [kpos][hd], XOR-swizzled
  __shared__ short Vs[2][64 * 64];   // [hd][kpos], XOR-swizzled
  int t = threadIdx.x, w = t >> 6, l = t & 63;
  int lr = l & 15, g = l >> 4, lkb = g * 8;
  int bh = blockIdx.x;               // XCD = bh % 8 (48 % 8 == 0)
  int b = bh / NH, h = bh % NH;
  int qt = ((int)gridDim.y - 1) - blockIdx.y;   // longest blocks first
  int qbase = qt * 64;
  const int rstride = 3 * NE;

  const short* qrow = qkv + (size_t)(b * TT + qbase + w * 16 + lr) * rstride + h * HD + lkb;
  bf16x8 qf0 = *reinterpret_cast<const bf16x8*>(qrow);
  bf16x8 qf1 = *reinterpret_cast<const bf16x8*>(qrow + 32);

  f32x4 o[4];
#pragma unroll
  for (int j = 0; j < 4; ++j) o[j] = (f32x4){0.f, 0.f, 0.f, 0.f};
  float m_run = -3e38f, l_run = 0.f;   // exp2-domain running max / linear sum

  int ci0 = t, ci1 = t + 256;
  int row0 = ci0 >> 3, c0 = ((ci0 & 7) ^ (row0 & 7)) * 8;
  int row1 = ci1 >> 3, c1 = ((ci1 & 7) ^ (row1 & 7)) * 8;

  const short* kbase = qkv + (size_t)(b * TT) * rstride + NE + h * HD;
  const short* vtb = vt + (size_t)bh * HD * TT;

  gload16(kbase + (size_t)row0 * rstride + c0, &Ks[0][ci0 * 8]);
  gload16(kbase + (size_t)row1 * rstride + c1, &Ks[0][ci1 * 8]);
  gload16(vtb + (size_t)row0 * TT + c0, &Vs[0][ci0 * 8]);
  gload16(vtb + (size_t)row1 * TT + c1, &Vs[0][ci1 * 8]);

  int qmin = qbase + w * 16;
  int srcA = ((g & 1) * 2) * 16 + lr;
  int srcB = srcA + 16;
  bool ghi = (g >= 2);

  int nkv = qt + 1;
  for (int kt = 0; kt < nkv; ++kt) {
    int bi = kt & 1;
    int kvbase = kt * 64;
    bool pre = (kt + 1 < nkv);
    __syncthreads();

    if (pre) {
      int nb = kvbase + 64;
      gload16(kbase + (size_t)(nb + row0) * rstride + c0, &Ks[bi ^ 1][ci0 * 8]);
      gload16(kbase + (size_t)(nb + row1) * rstride + c1, &Ks[bi ^ 1][ci1 * 8]);
      gload16(vtb + (size_t)row0 * TT + nb + c0, &Vs[bi ^ 1][ci0 * 8]);
      gload16(vtb + (size_t)row1 * TT + nb + c1, &Vs[bi ^ 1][ci1 * 8]);
    }

    // --- QK^T (swapped; values already exp2-domain scaled via Q) ---
    f32x4 s[4];
#pragma unroll
    for (int nt = 0; nt < 4; ++nt) {
      int row = nt * 16 + lr;
      bf16x8 kf0 = *reinterpret_cast<const bf16x8*>(
          (char*)Ks[bi] + ((row * 128 + lkb * 2) ^ ((lr & 7) << 4)));
      bf16x8 kf1 = *reinterpret_cast<const bf16x8*>(
          (char*)Ks[bi] + ((row * 128 + 64 + lkb * 2) ^ ((lr & 7) << 4)));
      f32x4 st = (f32x4){0.f, 0.f, 0.f, 0.f};
      st = __builtin_amdgcn_mfma_f32_16x16x32_bf16(kf0, qf0, st, 0, 0, 0);
      st = __builtin_amdgcn_mfma_f32_16x16x32_bf16(kf1, qf1, st, 0, 0, 0);
      s[nt] = st;
    }

    // --- causal mask (diagonal tile only; no scaling needed) ---
    if (kvbase + 63 > qmin) {
      int qabs = qmin + lr;
#pragma unroll
      for (int nt = 0; nt < 4; ++nt)
#pragma unroll
        for (int r = 0; r < 4; ++r) {
          int kp = kvbase + nt * 16 + g * 4 + r;
          s[nt][r] = (kp <= qabs) ? s[nt][r] : -3e38f;
        }
    }

    // --- online softmax (exp2 domain), defer-rescale THR=11.54 ---
    float mx = s[0][0];
#pragma unroll
    for (int nt = 0; nt < 4; ++nt)
#pragma unroll
      for (int r = 0; r < 4; ++r) mx = fmaxf(mx, s[nt][r]);
    mx = fmaxf(mx, __shfl_xor(mx, 16));
    mx = fmaxf(mx, __shfl_xor(mx, 32));
    if (__any(mx > m_run + 11.54f)) {
      float mn = fmaxf(m_run, mx);
      float al = exp2fast(m_run - mn);
      m_run = mn;
      l_run *= al;
      float al0 = __shfl(al, g * 4 + 0);
      float al1 = __shfl(al, g * 4 + 1);
      float al2 = __shfl(al, g * 4 + 2);
      float al3 = __shfl(al, g * 4 + 3);
#pragma unroll
      for (int j = 0; j < 4; ++j) {
        o[j][0] *= al0; o[j][1] *= al1; o[j][2] *= al2; o[j][3] *= al3;
      }
    }
    float rs = 0.f;
#pragma unroll
    for (int nt = 0; nt < 4; ++nt)
#pragma unroll
      for (int r = 0; r < 4; ++r) {
        float p = exp2fast(s[nt][r] - m_run);
        s[nt][r] = p;
        rs += p;
      }
    rs += __shfl_xor(rs, 16);
    rs += __shfl_xor(rs, 32);
    l_run += rs;

    // --- pack P to bf16 pairs: single-instruction cvt_pk ---
    unsigned int pw[4][2];
#pragma unroll
    for (int nt = 0; nt < 4; ++nt)
#pragma unroll
      for (int pr = 0; pr < 2; ++pr)
        pw[nt][pr] = cvtpk(s[nt][2 * pr], s[nt][2 * pr + 1]);

    // --- PV: build P A-frag per 32-k chunk via shfl; dword-union assembly ---
#pragma unroll
    for (int c = 0; c < 2; ++c) {
      unsigned int a00 = __shfl(pw[c * 2 + 0][0], srcA);
      unsigned int a01 = __shfl(pw[c * 2 + 0][1], srcA);
      unsigned int a02 = __shfl(pw[c * 2 + 0][0], srcB);
      unsigned int a03 = __shfl(pw[c * 2 + 0][1], srcB);
      unsigned int a10 = __shfl(pw[c * 2 + 1][0], srcA);
      unsigned int a11 = __shfl(pw[c * 2 + 1][1], srcA);
      unsigned int a12 = __shfl(pw[c * 2 + 1][0], srcB);
      unsigned int a13 = __shfl(pw[c * 2 + 1][1], srcB);
      union { unsigned int u[4]; bf16x8 v; } pau;
      pau.u[0] = ghi ? a10 : a00;
      pau.u[1] = ghi ? a11 : a01;
      pau.u[2] = ghi ? a12 : a02;
      pau.u[3] = ghi ? a13 : a03;
#pragma unroll
      for (int j = 0; j < 4; ++j) {
        int vrow = j * 16 + lr;
        bf16x8 vf = *reinterpret_cast<const bf16x8*>(
            (char*)Vs[bi] + ((vrow * 128 + c * 64 + lkb * 2) ^ ((lr & 7) << 4)));
        o[j] = __builtin_amdgcn_mfma_f32_16x16x32_bf16(pau.v, vf, o[j], 0, 0, 0);
      }
    }
  }

  // --- epilogue ---
  float inv = 1.0f / l_run;
  float i0 = __shfl(inv, g * 4 + 0);
  float i1 = __shfl(inv, g * 4 + 1);
  float i2 = __shfl(inv, g * 4 + 2);
  float i3 = __shfl(inv, g * 4 + 3);
#pragma unroll
  for (int r = 0; r < 4; ++r) {
    float ir = (r == 0) ? i0 : (r == 1) ? i1 : (r == 2) ? i2 : i3;
    size_t row = (size_t)(b * TT + qbase + w * 16 + g * 4 + r);
#pragma unroll
    for (int j = 0; j < 4; ++j)
      y[row * NE + h * HD + j * 16 + lr] = f2bf(o[j][r] * ir);
  }
}

extern "C" void kernel_launch(void* const* d_in, const int* in_sizes, int n_in,
                              void* d_out, int out_size, void* d_ws, size_t ws_size,
                              hipStream_t stream) {
  (void)in_sizes; (void)n_in; (void)out_size; (void)ws_size;
  const float* x       = (const float*)d_in[0];
  const float* ln1_g   = (const float*)d_in[1];
  const float* ln1_b   = (const float*)d_in[2];
  const float* w_attn  = (const float*)d_in[3];
  const float* b_attn  = (const float*)d_in[4];
  const float* w_aproj = (const float*)d_in[5];
  const float* b_aproj = (const float*)d_in[6];
  const float* ln2_g   = (const float*)d_in[7];
  const float* ln2_b   = (const float*)d_in[8];
  const float* w_fc    = (const float*)d_in[9];
  const float* b_fc    = (const float*)d_in[10];
  const float* w_mproj = (const float*)d_in[11];
  const float* b_mproj = (const float*)d_in[12];

  char* ws = (char*)d_ws;
  size_t off = 0;
  auto alloc = [&](size_t bytes) {
    char* p = ws + off;
    off += (bytes + 255) & ~(size_t)255;
    return p;
  };
  short* wt_attn  = (short*)alloc((size_t)2304 * 768 * 2);
  short* wt_aproj = (short*)alloc((size_t)768 * 768 * 2);
  short* wt_fc    = (short*)alloc((size_t)3072 * 768 * 2);
  short* wt_mproj = (short*)alloc((size_t)768 * 3072 * 2);
  short* lnb  = (short*)alloc((size_t)ROWS * 768 * 2);
  short* qkvb = (short*)alloc((size_t)ROWS * 3072 * 2);
  short* yb   = (short*)alloc((size_t)ROWS * 768 * 2);
  float* x2   = (float*)alloc((size_t)ROWS * 768 * 4);
  short* vtg = lnb;  // aliases dead lnb between qkv-GEMM and ln2

  wtrans_all_kernel<<<1728, 256, 0, stream>>>(
      w_attn, w_aproj, w_fc, w_mproj, wt_attn, wt_aproj, wt_fc, wt_mproj);

  ln_kernel<<<ROWS, 64, 0, stream>>>(x, ln1_g, ln1_b, lnb);
  gemm_kernel<0><<<64 * 18, 256, 0, stream>>>(
      lnb, wt_attn, b_attn, nullptr, qkvb, ROWS, 2304, 768, 18);
  vtrans_kernel<<<dim3(BB * NH, TT / 64), 256, 0, stream>>>(qkvb, vtg);
  attn_kernel<<<dim3(BB * NH, TT / 64), 256, 0, stream>>>(qkvb, vtg, yb);
  gemm64_kernel<2><<<64 * 12, 256, 0, stream>>>(
      yb, wt_aproj, b_aproj, x, x2, ROWS, 768, 768, 12);
  ln_kernel<<<ROWS, 64, 0, stream>>>(x2, ln2_g, ln2_b, lnb);
  gemm_kernel<1><<<64 * 24, 256, 0, stream>>>(
      lnb, wt_fc, b_fc, nullptr, qkvb, ROWS, 3072, 768, 24);
  gemm64_kernel<2><<<64 * 12, 256, 0, stream>>>(
      qkvb, wt_mproj, b_mproj, x2, (float*)d_out, ROWS, 768, 3072, 12);
}

// Round 12
// 283.029 us; speedup vs baseline: 1.5690x; 1.0256x over previous
//
#include <hip/hip_runtime.h>
#include <hip/hip_bf16.h>

#define NE 768
#define NH 12
#define HD 64
#define BB 4
#define TT 2048
#define ROWS (BB*TT)  // 8192
#define QSCALE 0.18033688011112042f  // 0.125 * log2(e): softmax in exp2 domain

typedef __attribute__((ext_vector_type(8))) short bf16x8;
typedef __attribute__((ext_vector_type(4))) float f32x4;

#define WAITV(N) asm volatile("s_waitcnt vmcnt(" #N ")" ::: "memory")
#define BARSYNC()                                   \
  do {                                              \
    __builtin_amdgcn_sched_barrier(0);              \
    __builtin_amdgcn_s_barrier();                   \
    __builtin_amdgcn_sched_barrier(0);              \
  } while (0)

__device__ __forceinline__ short f2bf(float f) {
  __hip_bfloat16 h = __float2bfloat16(f);
  union { __hip_bfloat16 h; short s; } u; u.h = h; return u.s;
}

__device__ __forceinline__ float exp2fast(float x) {
  float r;
  asm("v_exp_f32 %0, %1" : "=v"(r) : "v"(x));
  return r;
}

__device__ __forceinline__ float rcpfast(float x) {
  float r;
  asm("v_rcp_f32 %0, %1" : "=v"(r) : "v"(x));
  return r;
}

__device__ __forceinline__ unsigned int cvtpk(float lo, float hi) {
  unsigned int r;
  asm("v_cvt_pk_bf16_f32 %0, %1, %2" : "=v"(r) : "v"(lo), "v"(hi));
  return r;
}

// tanh-form GELU in exp2 domain: ~7 VALU ops vs ~25 for erff.
__device__ __forceinline__ float gelu_fast(float v) {
  float u = fmaf(0.044715f * v, v, 1.0f);
  float e = exp2fast(fminf(v * u * 2.3022079f, 80.f));
  return v * e * rcpfast(e + 1.f);
}

__device__ __forceinline__ void gload16(const void* g, void* l) {
  __builtin_amdgcn_global_load_lds(
      (const __attribute__((address_space(1))) void*)g,
      (__attribute__((address_space(3))) void*)l,
      16, 0, 0);
}

__device__ __forceinline__ void xcd_remap(int id, int nbn, int& bm, int& bn) {
  int x = id & 7;
  int j = id >> 3;
  bm = x * 8 + j / nbn;
  bn = j % nbn;
}

// ---------------- merged weight transpose: all 4 weights in one launch ------
__global__ __launch_bounds__(256) void wtrans_all_kernel(
    const float* __restrict__ w_attn, const float* __restrict__ w_aproj,
    const float* __restrict__ w_fc, const float* __restrict__ w_mproj,
    short* __restrict__ o_attn, short* __restrict__ o_aproj,
    short* __restrict__ o_fc, short* __restrict__ o_mproj) {
  __shared__ short tile[64 * 65];
  int id = blockIdx.x;
  const float* W; short* Wt; int K, N, bx, by;
  if (id < 432)       { W = w_attn;  Wt = o_attn;  K = 768;  N = 2304; bx = id % 12;  by = id / 12; }
  else if (id < 576)  { id -= 432;  W = w_aproj; Wt = o_aproj; K = 768;  N = 768;  bx = id % 12;  by = id / 12; }
  else if (id < 1152) { id -= 576;  W = w_fc;    Wt = o_fc;    K = 768;  N = 3072; bx = id % 12;  by = id / 12; }
  else                { id -= 1152; W = w_mproj; Wt = o_mproj; K = 3072; N = 768;  bx = id % 48;  by = id / 48; }
  int k0 = bx * 64, n0 = by * 64;
  int t = threadIdx.x;
#pragma unroll
  for (int p = 0; p < 16; ++p) {
    int idx = p * 256 + t;
    int r = idx >> 6, c = idx & 63;
    tile[r * 65 + c] = f2bf(W[(size_t)(k0 + r) * N + n0 + c]);
  }
  __syncthreads();
#pragma unroll
  for (int p = 0; p < 16; ++p) {
    int idx = p * 256 + t;
    int rr = idx >> 6, cc = idx & 63;
    Wt[(size_t)(n0 + rr) * K + k0 + cc] = tile[cc * 65 + rr];
  }
}

// ---------------- V transpose: qkv V-part -> Vt[bh][hd][tloc] bf16 ----------
__global__ __launch_bounds__(256) void vtrans_kernel(
    const short* __restrict__ qkv, short* __restrict__ vt) {
  __shared__ short tile[64 * 65];
  int bh = blockIdx.x;
  int b = bh / NH, h = bh % NH;
  int t0 = blockIdx.y * 64;
  int t = threadIdx.x;
#pragma unroll
  for (int p = 0; p < 16; ++p) {
    int idx = p * 256 + t;
    int r = idx >> 6, c = idx & 63;   // r = tloc, c = hd
    tile[r * 65 + c] =
        qkv[(size_t)(b * TT + t0 + r) * (3 * NE) + 2 * NE + h * HD + c];
  }
  __syncthreads();
#pragma unroll
  for (int p = 0; p < 16; ++p) {
    int idx = p * 256 + t;
    int rr = idx >> 6, cc = idx & 63; // rr = hd, cc = tloc
    vt[(size_t)bh * HD * TT + (size_t)rr * TT + t0 + cc] = tile[cc * 65 + rr];
  }
}

// ---------------- LayerNorm: fp32 in -> bf16 out, one wave per row ----------
__global__ __launch_bounds__(64) void ln_kernel(
    const float* __restrict__ x, const float* __restrict__ g,
    const float* __restrict__ b, short* __restrict__ out) {
  int row = blockIdx.x, l = threadIdx.x;
  const float* xr = x + (size_t)row * NE;
  float4 v[3];
  float s = 0.f, ss = 0.f;
#pragma unroll
  for (int i = 0; i < 3; ++i) {
    v[i] = *reinterpret_cast<const float4*>(xr + l * 4 + i * 256);
    s += v[i].x + v[i].y + v[i].z + v[i].w;
    ss += v[i].x * v[i].x + v[i].y * v[i].y + v[i].z * v[i].z + v[i].w * v[i].w;
  }
#pragma unroll
  for (int m = 1; m < 64; m <<= 1) {
    s += __shfl_xor(s, m);
    ss += __shfl_xor(ss, m);
  }
  float mu = s * (1.0f / NE);
  float var = ss * (1.0f / NE) - mu * mu;
  float rstd = rsqrtf(var + 1e-5f);
#pragma unroll
  for (int i = 0; i < 3; ++i) {
    float4 gv = *reinterpret_cast<const float4*>(g + l * 4 + i * 256);
    float4 bv = *reinterpret_cast<const float4*>(b + l * 4 + i * 256);
    short4 o;
    o.x = f2bf((v[i].x - mu) * rstd * gv.x + bv.x);
    o.y = f2bf((v[i].y - mu) * rstd * gv.y + bv.y);
    o.z = f2bf((v[i].z - mu) * rstd * gv.z + bv.z);
    o.w = f2bf((v[i].w - mu) * rstd * gv.w + bv.w);
    *reinterpret_cast<short4*>(out + (size_t)row * NE + l * 4 + i * 256) = o;
  }
}

// 4-bit LDS swizzle: slot_lds = gslot ^ (row&3) ^ ((row>>2)&3). Involution on
// both sides; fragment reads land 2 lanes/bank-window (free floor).

// ---------------- GEMM 128x128, BK=32, 3-buf depth-2 pipeline, XCD remap ----
template <int EPI>
__global__ __launch_bounds__(256) void gemm_kernel(
    const short* __restrict__ A, const short* __restrict__ Bt,
    const float* __restrict__ bias, const float* __restrict__ resid,
    void* __restrict__ Cout, int M, int N, int K, int nbn) {
  __shared__ short As[3][128 * 32];
  __shared__ short Bs[3][128 * 32];
  int t = threadIdx.x;
  int w = t >> 6, l = t & 63;
  int wr = w >> 1, wc = w & 1;
  int bm, bn;
  xcd_remap(blockIdx.x, nbn, bm, bn);
  int lr = l & 15, g4 = l >> 4;

  f32x4 acc[4][4];
#pragma unroll
  for (int i = 0; i < 4; ++i)
#pragma unroll
    for (int j = 0; j < 4; ++j) acc[i][j] = (f32x4){0.f, 0.f, 0.f, 0.f};

  int r0 = t >> 2;
  int cs = ((t & 3) ^ (r0 & 3) ^ ((r0 >> 2) & 3)) * 8;  // pre-swizzled src col
  const short* ga = A + (size_t)(bm * 128) * K;
  const short* gb = Bt + (size_t)(bn * 128) * K;

#pragma unroll
  for (int p = 0; p < 2; ++p) {
    int ko = p * 32;
    gload16(ga + (size_t)r0 * K + ko + cs, &As[p][t * 8]);
    gload16(ga + (size_t)(r0 + 64) * K + ko + cs, &As[p][(t + 256) * 8]);
    gload16(gb + (size_t)r0 * K + ko + cs, &Bs[p][t * 8]);
    gload16(gb + (size_t)(r0 + 64) * K + ko + cs, &Bs[p][(t + 256) * 8]);
  }

  int xorR = ((lr & 3) ^ ((lr >> 2) & 3)) << 4;   // read-side swizzle
  int nk = K >> 5;
  int cur = 0, prv = 2;
  for (int kt = 0; kt < nk; ++kt) {
    if (kt < nk - 1) WAITV(4); else WAITV(0);
    BARSYNC();
    if (kt + 2 < nk) {
      int ko = (kt + 2) * 32;
      gload16(ga + (size_t)r0 * K + ko + cs, &As[prv][t * 8]);
      gload16(ga + (size_t)(r0 + 64) * K + ko + cs, &As[prv][(t + 256) * 8]);
      gload16(gb + (size_t)r0 * K + ko + cs, &Bs[prv][t * 8]);
      gload16(gb + (size_t)(r0 + 64) * K + ko + cs, &Bs[prv][(t + 256) * 8]);
    }
    __builtin_amdgcn_sched_barrier(0);
    const char* Ab = (const char*)As[cur];
    const char* Bb = (const char*)Bs[cur];
    bf16x8 af[4], bfr[4];
#pragma unroll
    for (int i = 0; i < 4; ++i)
      af[i] = *reinterpret_cast<const bf16x8*>(
          Ab + (((wr * 64 + i * 16 + lr) * 64 + g4 * 16) ^ xorR));
#pragma unroll
    for (int j = 0; j < 4; ++j)
      bfr[j] = *reinterpret_cast<const bf16x8*>(
          Bb + (((wc * 64 + j * 16 + lr) * 64 + g4 * 16) ^ xorR));
#pragma unroll
    for (int i = 0; i < 4; ++i)
#pragma unroll
      for (int j = 0; j < 4; ++j)
        acc[i][j] = __builtin_amdgcn_mfma_f32_16x16x32_bf16(af[i], bfr[j], acc[i][j], 0, 0, 0);
    prv = cur;
    cur = (cur == 2) ? 0 : cur + 1;
  }

  int rbase = bm * 128 + wr * 64;
  int cbase = bn * 128 + wc * 64;
#pragma unroll
  for (int i = 0; i < 4; ++i) {
#pragma unroll
    for (int r = 0; r < 4; ++r) {
      int row = rbase + i * 16 + g4 * 4 + r;
#pragma unroll
      for (int j = 0; j < 4; ++j) {
        int col = cbase + j * 16 + lr;
        float v = acc[i][j][r] + bias[col];
        if (EPI == 0) {
          if (col < NE) v *= QSCALE;   // Q pre-scale for exp2-domain softmax
          ((short*)Cout)[(size_t)row * N + col] = f2bf(v);
        } else if (EPI == 1) {
          ((short*)Cout)[(size_t)row * N + col] = f2bf(gelu_fast(v));
        } else {
          ((float*)Cout)[(size_t)row * N + col] = v + resid[(size_t)row * N + col];
        }
      }
    }
  }
}

// ---------------- GEMM 128x64, BK=32, 4-buf depth-3 pipeline, XCD remap -----
template <int EPI>
__global__ __launch_bounds__(256) void gemm64_kernel(
    const short* __restrict__ A, const short* __restrict__ Bt,
    const float* __restrict__ bias, const float* __restrict__ resid,
    void* __restrict__ Cout, int M, int N, int K, int nbn) {
  __shared__ short As[4][128 * 32];
  __shared__ short Bs[4][64 * 32];
  int t = threadIdx.x;
  int w = t >> 6, l = t & 63;
  int bm, bn;
  xcd_remap(blockIdx.x, nbn, bm, bn);
  int lr = l & 15, g4 = l >> 4;

  f32x4 acc[2][4];
#pragma unroll
  for (int i = 0; i < 2; ++i)
#pragma unroll
    for (int j = 0; j < 4; ++j) acc[i][j] = (f32x4){0.f, 0.f, 0.f, 0.f};

  int r0 = t >> 2;
  int cs = ((t & 3) ^ (r0 & 3) ^ ((r0 >> 2) & 3)) * 8;
  const short* ga = A + (size_t)(bm * 128) * K;
  const short* gb = Bt + (size_t)(bn * 64) * K;

#pragma unroll
  for (int p = 0; p < 3; ++p) {
    int ko = p * 32;
    gload16(ga + (size_t)r0 * K + ko + cs, &As[p][t * 8]);
    gload16(ga + (size_t)(r0 + 64) * K + ko + cs, &As[p][(t + 256) * 8]);
    gload16(gb + (size_t)r0 * K + ko + cs, &Bs[p][t * 8]);
  }

  int xorR = ((lr & 3) ^ ((lr >> 2) & 3)) << 4;
  int nk = K >> 5;
  for (int kt = 0; kt < nk; ++kt) {
    int bi = kt & 3;
    int rem = nk - 1 - kt;
    if (rem >= 2) WAITV(6);
    else if (rem == 1) WAITV(3);
    else WAITV(0);
    BARSYNC();
    if (kt + 3 < nk) {
      int ko = (kt + 3) * 32;
      int nb = (kt + 3) & 3;
      gload16(ga + (size_t)r0 * K + ko + cs, &As[nb][t * 8]);
      gload16(ga + (size_t)(r0 + 64) * K + ko + cs, &As[nb][(t + 256) * 8]);
      gload16(gb + (size_t)r0 * K + ko + cs, &Bs[nb][t * 8]);
    }
    __builtin_amdgcn_sched_barrier(0);
    const char* Ab = (const char*)As[bi];
    const char* Bb = (const char*)Bs[bi];
    bf16x8 af[2], bfr[4];
#pragma unroll
    for (int i = 0; i < 2; ++i)
      af[i] = *reinterpret_cast<const bf16x8*>(
          Ab + (((w * 32 + i * 16 + lr) * 64 + g4 * 16) ^ xorR));
#pragma unroll
    for (int j = 0; j < 4; ++j)
      bfr[j] = *reinterpret_cast<const bf16x8*>(
          Bb + (((j * 16 + lr) * 64 + g4 * 16) ^ xorR));
#pragma unroll
    for (int i = 0; i < 2; ++i)
#pragma unroll
      for (int j = 0; j < 4; ++j)
        acc[i][j] = __builtin_amdgcn_mfma_f32_16x16x32_bf16(af[i], bfr[j], acc[i][j], 0, 0, 0);
  }

  int rbase = bm * 128 + w * 32;
  int cbase = bn * 64;
#pragma unroll
  for (int i = 0; i < 2; ++i) {
#pragma unroll
    for (int r = 0; r < 4; ++r) {
      int row = rbase + i * 16 + g4 * 4 + r;
#pragma unroll
      for (int j = 0; j < 4; ++j) {
        int col = cbase + j * 16 + lr;
        float v = acc[i][j][r] + bias[col];
        if (EPI == 0) {
          ((short*)Cout)[(size_t)row * N + col] = f2bf(v);
        } else if (EPI == 1) {
          ((short*)Cout)[(size_t)row * N + col] = f2bf(gelu_fast(v));
        } else {
          ((float*)Cout)[(size_t)row * N + col] = v + resid[(size_t)row * N + col];
        }
      }
    }
  }
}

// ---------------- causal flash attention, QBLK=64, KVBLK=64, dbuf -----------
__global__ __launch_bounds__(256, 4) void attn_kernel(
    const short* __restrict__ qkv, const short* __restrict__ vt,
    short* __restrict__ y) {
  __shared__ short Ks[2][64 * 64];   // [kpos][hd], XOR-swizzled
  __shared__ short Vs[2][64 * 64];   // [hd][kpos], XOR-swizzled
  int t = threadIdx.x, w = t >> 6, l = t & 63;
  int lr = l & 15, g = l >> 4, lkb = g * 8;
  int bh = blockIdx.x;               // XCD = bh % 8 (48 % 8 == 0)
  int b = bh / NH, h = bh % NH;
  int qt = ((int)gridDim.y - 1) - blockIdx.y;   // longest blocks first
  int qbase = qt * 64;
  const int rstride = 3 * NE;

  const short* qrow = qkv + (size_t)(b * TT + qbase + w * 16 + lr) * rstride + h * HD + lkb;
  bf16x8 qf0 = *reinterpret_cast<const bf16x8*>(qrow);
  bf16x8 qf1 = *reinterpret_cast<const bf16x8*>(qrow + 32);

  f32x4 o[4];
#pragma unroll
  for (int j = 0; j < 4; ++j) o[j] = (f32x4){0.f, 0.f, 0.f, 0.f};
  float m_run = -3e38f, l_run = 0.f;

  int ci0 = t, ci1 = t + 256;
  int row0 = ci0 >> 3, c0 = ((ci0 & 7) ^ (row0 & 7)) * 8;
  int row1 = ci1 >> 3, c1 = ((ci1 & 7) ^ (row1 & 7)) * 8;

  const short* kbase = qkv + (size_t)(b * TT) * rstride + NE + h * HD;
  const short* vtb = vt + (size_t)bh * HD * TT;

  gload16(kbase + (size_t)row0 * rstride + c0, &Ks[0][ci0 * 8]);
  gload16(kbase + (size_t)row1 * rstride + c1, &Ks[0][ci1 * 8]);
  gload16(vtb + (size_t)row0 * TT + c0, &Vs[0][ci0 * 8]);
  gload16(vtb + (size_t)row1 * TT + c1, &Vs[0][ci1 * 8]);

  int qmin = qbase + w * 16;
  int srcA = ((g & 1) * 2) * 16 + lr;
  int srcB = srcA + 16;
  bool ghi = (g >= 2);

  int nkv = qt + 1;
  for (int kt = 0; kt < nkv; ++kt) {
    int bi = kt & 1;
    int kvbase = kt * 64;
    bool pre = (kt + 1 < nkv);
    __syncthreads();

    if (pre) {
      int nb = kvbase + 64;
      gload16(kbase + (size_t)(nb + row0) * rstride + c0, &Ks[bi ^ 1][ci0 * 8]);
      gload16(kbase + (size_t)(nb + row1) * rstride + c1, &Ks[bi ^ 1][ci1 * 8]);
      gload16(vtb + (size_t)row0 * TT + nb + c0, &Vs[bi ^ 1][ci0 * 8]);
      gload16(vtb + (size_t)row1 * TT + nb + c1, &Vs[bi ^ 1][ci1 * 8]);
    }

    f32x4 s[4];
#pragma unroll
    for (int nt = 0; nt < 4; ++nt) {
      int row = nt * 16 + lr;
      bf16x8 kf0 = *reinterpret_cast<const bf16x8*>(
          (char*)Ks[bi] + ((row * 128 + lkb * 2) ^ ((lr & 7) << 4)));
      bf16x8 kf1 = *reinterpret_cast<const bf16x8*>(
          (char*)Ks[bi] + ((row * 128 + 64 + lkb * 2) ^ ((lr & 7) << 4)));
      f32x4 st = (f32x4){0.f, 0.f, 0.f, 0.f};
      st = __builtin_amdgcn_mfma_f32_16x16x32_bf16(kf0, qf0, st, 0, 0, 0);
      st = __builtin_amdgcn_mfma_f32_16x16x32_bf16(kf1, qf1, st, 0, 0, 0);
      s[nt] = st;
    }

    if (kvbase + 63 > qmin) {
      int qabs = qmin + lr;
#pragma unroll
      for (int nt = 0; nt < 4; ++nt)
#pragma unroll
        for (int r = 0; r < 4; ++r) {
          int kp = kvbase + nt * 16 + g * 4 + r;
          s[nt][r] = (kp <= qabs) ? s[nt][r] : -3e38f;
        }
    }

    float mx = s[0][0];
#pragma unroll
    for (int nt = 0; nt < 4; ++nt)
#pragma unroll
      for (int r = 0; r < 4; ++r) mx = fmaxf(mx, s[nt][r]);
    mx = fmaxf(mx, __shfl_xor(mx, 16));
    mx = fmaxf(mx, __shfl_xor(mx, 32));
    if (__any(mx > m_run + 11.54f)) {
      float mn = fmaxf(m_run, mx);
      float al = exp2fast(m_run - mn);
      m_run = mn;
      l_run *= al;
      float al0 = __shfl(al, g * 4 + 0);
      float al1 = __shfl(al, g * 4 + 1);
      float al2 = __shfl(al, g * 4 + 2);
      float al3 = __shfl(al, g * 4 + 3);
#pragma unroll
      for (int j = 0; j < 4; ++j) {
        o[j][0] *= al0; o[j][1] *= al1; o[j][2] *= al2; o[j][3] *= al3;
      }
    }
    float rs = 0.f;
#pragma unroll
    for (int nt = 0; nt < 4; ++nt)
#pragma unroll
      for (int r = 0; r < 4; ++r) {
        float p = exp2fast(s[nt][r] - m_run);
        s[nt][r] = p;
        rs += p;
      }
    rs += __shfl_xor(rs, 16);
    rs += __shfl_xor(rs, 32);
    l_run += rs;

    unsigned int pw[4][2];
#pragma unroll
    for (int nt = 0; nt < 4; ++nt)
#pragma unroll
      for (int pr = 0; pr < 2; ++pr)
        pw[nt][pr] = cvtpk(s[nt][2 * pr], s[nt][2 * pr + 1]);

#pragma unroll
    for (int c = 0; c < 2; ++c) {
      unsigned int a00 = __shfl(pw[c * 2 + 0][0], srcA);
      unsigned int a01 = __shfl(pw[c * 2 + 0][1], srcA);
      unsigned int a02 = __shfl(pw[c * 2 + 0][0], srcB);
      unsigned int a03 = __shfl(pw[c * 2 + 0][1], srcB);
      unsigned int a10 = __shfl(pw[c * 2 + 1][0], srcA);
      unsigned int a11 = __shfl(pw[c * 2 + 1][1], srcA);
      unsigned int a12 = __shfl(pw[c * 2 + 1][0], srcB);
      unsigned int a13 = __shfl(pw[c * 2 + 1][1], srcB);
      union { unsigned int u[4]; bf16x8 v; } pau;
      pau.u[0] = ghi ? a10 : a00;
      pau.u[1] = ghi ? a11 : a01;
      pau.u[2] = ghi ? a12 : a02;
      pau.u[3] = ghi ? a13 : a03;
#pragma unroll
      for (int j = 0; j < 4; ++j) {
        int vrow = j * 16 + lr;
        bf16x8 vf = *reinterpret_cast<const bf16x8*>(
            (char*)Vs[bi] + ((vrow * 128 + c * 64 + lkb * 2) ^ ((lr & 7) << 4)));
        o[j] = __builtin_amdgcn_mfma_f32_16x16x32_bf16(pau.v, vf, o[j], 0, 0, 0);
      }
    }
  }

  float inv = 1.0f / l_run;
  float i0 = __shfl(inv, g * 4 + 0);
  float i1 = __shfl(inv, g * 4 + 1);
  float i2 = __shfl(inv, g * 4 + 2);
  float i3 = __shfl(inv, g * 4 + 3);
#pragma unroll
  for (int r = 0; r < 4; ++r) {
    float ir = (r == 0) ? i0 : (r == 1) ? i1 : (r == 2) ? i2 : i3;
    size_t row = (size_t)(b * TT + qbase + w * 16 + g * 4 + r);
#pragma unroll
    for (int j = 0; j < 4; ++j)
      y[row * NE + h * HD + j * 16 + lr] = f2bf(o[j][r] * ir);
  }
}

extern "C" void kernel_launch(void* const* d_in, const int* in_sizes, int n_in,
                              void* d_out, int out_size, void* d_ws, size_t ws_size,
                              hipStream_t stream) {
  (void)in_sizes; (void)n_in; (void)out_size; (void)ws_size;
  const float* x       = (const float*)d_in[0];
  const float* ln1_g   = (const float*)d_in[1];
  const float* ln1_b   = (const float*)d_in[2];
  const float* w_attn  = (const float*)d_in[3];
  const float* b_attn  = (const float*)d_in[4];
  const float* w_aproj = (const float*)d_in[5];
  const float* b_aproj = (const float*)d_in[6];
  const float* ln2_g   = (const float*)d_in[7];
  const float* ln2_b   = (const float*)d_in[8];
  const float* w_fc    = (const float*)d_in[9];
  const float* b_fc    = (const float*)d_in[10];
  const float* w_mproj = (const float*)d_in[11];
  const float* b_mproj = (const float*)d_in[12];

  char* ws = (char*)d_ws;
  size_t off = 0;
  auto alloc = [&](size_t bytes) {
    char* p = ws + off;
    off += (bytes + 255) & ~(size_t)255;
    return p;
  };
  short* wt_attn  = (short*)alloc((size_t)2304 * 768 * 2);
  short* wt_aproj = (short*)alloc((size_t)768 * 768 * 2);
  short* wt_fc    = (short*)alloc((size_t)3072 * 768 * 2);
  short* wt_mproj = (short*)alloc((size_t)768 * 3072 * 2);
  short* lnb  = (short*)alloc((size_t)ROWS * 768 * 2);
  short* qkvb = (short*)alloc((size_t)ROWS * 3072 * 2);
  short* yb   = (short*)alloc((size_t)ROWS * 768 * 2);
  float* x2   = (float*)alloc((size_t)ROWS * 768 * 4);
  short* vtg = lnb;  // aliases dead lnb between qkv-GEMM and ln2

  wtrans_all_kernel<<<1728, 256, 0, stream>>>(
      w_attn, w_aproj, w_fc, w_mproj, wt_attn, wt_aproj, wt_fc, wt_mproj);

  ln_kernel<<<ROWS, 64, 0, stream>>>(x, ln1_g, ln1_b, lnb);
  gemm_kernel<0><<<64 * 18, 256, 0, stream>>>(
      lnb, wt_attn, b_attn, nullptr, qkvb, ROWS, 2304, 768, 18);
  vtrans_kernel<<<dim3(BB * NH, TT / 64), 256, 0, stream>>>(qkvb, vtg);
  attn_kernel<<<dim3(BB * NH, TT / 64), 256, 0, stream>>>(qkvb, vtg, yb);
  gemm64_kernel<2><<<64 * 12, 256, 0, stream>>>(
      yb, wt_aproj, b_aproj, x, x2, ROWS, 768, 768, 12);
  ln_kernel<<<ROWS, 64, 0, stream>>>(x2, ln2_g, ln2_b, lnb);
  gemm_kernel<1><<<64 * 24, 256, 0, stream>>>(
      lnb, wt_fc, b_fc, nullptr, qkvb, ROWS, 3072, 768, 24);
  gemm64_kernel<2><<<64 * 12, 256, 0, stream>>>(
      qkvb, wt_mproj, b_mproj, x2, (float*)d_out, ROWS, 768, 3072, 12);
}

// Round 13
// 282.113 us; speedup vs baseline: 1.5741x; 1.0032x over previous
//
#include <hip/hip_runtime.h>
#include <hip/hip_bf16.h>

#define NE 768
#define NH 12
#define HD 64
#define BB 4
#define TT 2048
#define ROWS (BB*TT)  // 8192
#define QSCALE 0.18033688011112042f  // 0.125 * log2(e): softmax in exp2 domain

typedef __attribute__((ext_vector_type(8))) short bf16x8;
typedef __attribute__((ext_vector_type(4))) float f32x4;

#define WAITV(N) asm volatile("s_waitcnt vmcnt(" #N ")" ::: "memory")
#define BARSYNC()                                   \
  do {                                              \
    __builtin_amdgcn_sched_barrier(0);              \
    __builtin_amdgcn_s_barrier();                   \
    __builtin_amdgcn_sched_barrier(0);              \
  } while (0)

__device__ __forceinline__ short f2bf(float f) {
  __hip_bfloat16 h = __float2bfloat16(f);
  union { __hip_bfloat16 h; short s; } u; u.h = h; return u.s;
}

__device__ __forceinline__ float exp2fast(float x) {
  float r;
  asm("v_exp_f32 %0, %1" : "=v"(r) : "v"(x));
  return r;
}

__device__ __forceinline__ float rcpfast(float x) {
  float r;
  asm("v_rcp_f32 %0, %1" : "=v"(r) : "v"(x));
  return r;
}

__device__ __forceinline__ unsigned int cvtpk(float lo, float hi) {
  unsigned int r;
  asm("v_cvt_pk_bf16_f32 %0, %1, %2" : "=v"(r) : "v"(lo), "v"(hi));
  return r;
}

// tanh-form GELU in exp2 domain: ~7 VALU ops vs ~25 for erff.
__device__ __forceinline__ float gelu_fast(float v) {
  float u = fmaf(0.044715f * v, v, 1.0f);
  float e = exp2fast(fminf(v * u * 2.3022079f, 80.f));
  return v * e * rcpfast(e + 1.f);
}

__device__ __forceinline__ void gload16(const void* g, void* l) {
  __builtin_amdgcn_global_load_lds(
      (const __attribute__((address_space(1))) void*)g,
      (__attribute__((address_space(3))) void*)l,
      16, 0, 0);
}

__device__ __forceinline__ void xcd_remap(int id, int nbn, int& bm, int& bn) {
  int x = id & 7;
  int j = id >> 3;
  bm = x * 8 + j / nbn;
  bn = j % nbn;
}

// ---------------- merged weight transpose: all 4 weights in one launch ------
__global__ __launch_bounds__(256) void wtrans_all_kernel(
    const float* __restrict__ w_attn, const float* __restrict__ w_aproj,
    const float* __restrict__ w_fc, const float* __restrict__ w_mproj,
    short* __restrict__ o_attn, short* __restrict__ o_aproj,
    short* __restrict__ o_fc, short* __restrict__ o_mproj) {
  __shared__ short tile[64 * 65];
  int id = blockIdx.x;
  const float* W; short* Wt; int K, N, bx, by;
  if (id < 432)       { W = w_attn;  Wt = o_attn;  K = 768;  N = 2304; bx = id % 12;  by = id / 12; }
  else if (id < 576)  { id -= 432;  W = w_aproj; Wt = o_aproj; K = 768;  N = 768;  bx = id % 12;  by = id / 12; }
  else if (id < 1152) { id -= 576;  W = w_fc;    Wt = o_fc;    K = 768;  N = 3072; bx = id % 12;  by = id / 12; }
  else                { id -= 1152; W = w_mproj; Wt = o_mproj; K = 3072; N = 768;  bx = id % 48;  by = id / 48; }
  int k0 = bx * 64, n0 = by * 64;
  int t = threadIdx.x;
#pragma unroll
  for (int p = 0; p < 16; ++p) {
    int idx = p * 256 + t;
    int r = idx >> 6, c = idx & 63;
    tile[r * 65 + c] = f2bf(W[(size_t)(k0 + r) * N + n0 + c]);
  }
  __syncthreads();
#pragma unroll
  for (int p = 0; p < 16; ++p) {
    int idx = p * 256 + t;
    int rr = idx >> 6, cc = idx & 63;
    Wt[(size_t)(n0 + rr) * K + k0 + cc] = tile[cc * 65 + rr];
  }
}

// ---------------- V transpose: qkv V-part -> Vt[bh][hd][tloc] bf16 ----------
__global__ __launch_bounds__(256) void vtrans_kernel(
    const short* __restrict__ qkv, short* __restrict__ vt) {
  __shared__ short tile[64 * 65];
  int bh = blockIdx.x;
  int b = bh / NH, h = bh % NH;
  int t0 = blockIdx.y * 64;
  int t = threadIdx.x;
#pragma unroll
  for (int p = 0; p < 16; ++p) {
    int idx = p * 256 + t;
    int r = idx >> 6, c = idx & 63;   // r = tloc, c = hd
    tile[r * 65 + c] =
        qkv[(size_t)(b * TT + t0 + r) * (3 * NE) + 2 * NE + h * HD + c];
  }
  __syncthreads();
#pragma unroll
  for (int p = 0; p < 16; ++p) {
    int idx = p * 256 + t;
    int rr = idx >> 6, cc = idx & 63; // rr = hd, cc = tloc
    vt[(size_t)bh * HD * TT + (size_t)rr * TT + t0 + cc] = tile[cc * 65 + rr];
  }
}

// ---------------- LayerNorm: fp32 in -> bf16 out, one wave per row ----------
__global__ __launch_bounds__(64) void ln_kernel(
    const float* __restrict__ x, const float* __restrict__ g,
    const float* __restrict__ b, short* __restrict__ out) {
  int row = blockIdx.x, l = threadIdx.x;
  const float* xr = x + (size_t)row * NE;
  float4 v[3];
  float s = 0.f, ss = 0.f;
#pragma unroll
  for (int i = 0; i < 3; ++i) {
    v[i] = *reinterpret_cast<const float4*>(xr + l * 4 + i * 256);
    s += v[i].x + v[i].y + v[i].z + v[i].w;
    ss += v[i].x * v[i].x + v[i].y * v[i].y + v[i].z * v[i].z + v[i].w * v[i].w;
  }
#pragma unroll
  for (int m = 1; m < 64; m <<= 1) {
    s += __shfl_xor(s, m);
    ss += __shfl_xor(ss, m);
  }
  float mu = s * (1.0f / NE);
  float var = ss * (1.0f / NE) - mu * mu;
  float rstd = rsqrtf(var + 1e-5f);
#pragma unroll
  for (int i = 0; i < 3; ++i) {
    float4 gv = *reinterpret_cast<const float4*>(g + l * 4 + i * 256);
    float4 bv = *reinterpret_cast<const float4*>(b + l * 4 + i * 256);
    short4 o;
    o.x = f2bf((v[i].x - mu) * rstd * gv.x + bv.x);
    o.y = f2bf((v[i].y - mu) * rstd * gv.y + bv.y);
    o.z = f2bf((v[i].z - mu) * rstd * gv.z + bv.z);
    o.w = f2bf((v[i].w - mu) * rstd * gv.w + bv.w);
    *reinterpret_cast<short4*>(out + (size_t)row * NE + l * 4 + i * 256) = o;
  }
}

// ---------------- GEMM 128x128, BK=32, 3-buf depth-2 pipeline, XCD remap ----
// 64x64 per wave: best LDS-bytes/FLOP of the 4-wave configs (0.046 B/FLOP).
template <int EPI>
__global__ __launch_bounds__(256) void gemm_kernel(
    const short* __restrict__ A, const short* __restrict__ Bt,
    const float* __restrict__ bias, const float* __restrict__ resid,
    void* __restrict__ Cout, int M, int N, int K, int nbn) {
  __shared__ short As[3][128 * 32];
  __shared__ short Bs[3][128 * 32];
  int t = threadIdx.x;
  int w = t >> 6, l = t & 63;
  int wr = w >> 1, wc = w & 1;
  int bm, bn;
  xcd_remap(blockIdx.x, nbn, bm, bn);
  int lr = l & 15, g4 = l >> 4;

  f32x4 acc[4][4];
#pragma unroll
  for (int i = 0; i < 4; ++i)
#pragma unroll
    for (int j = 0; j < 4; ++j) acc[i][j] = (f32x4){0.f, 0.f, 0.f, 0.f};

  int r0 = t >> 2;
  int cs = ((t & 3) ^ (r0 & 3)) * 8;
  const short* ga = A + (size_t)(bm * 128) * K;
  const short* gb = Bt + (size_t)(bn * 128) * K;

#pragma unroll
  for (int p = 0; p < 2; ++p) {
    int ko = p * 32;
    gload16(ga + (size_t)r0 * K + ko + cs, &As[p][t * 8]);
    gload16(ga + (size_t)(r0 + 64) * K + ko + cs, &As[p][(t + 256) * 8]);
    gload16(gb + (size_t)r0 * K + ko + cs, &Bs[p][t * 8]);
    gload16(gb + (size_t)(r0 + 64) * K + ko + cs, &Bs[p][(t + 256) * 8]);
  }

  int xorR = (lr & 3) << 4;
  int nk = K >> 5;
  int cur = 0, prv = 2;
  for (int kt = 0; kt < nk; ++kt) {
    if (kt < nk - 1) WAITV(4); else WAITV(0);
    BARSYNC();
    if (kt + 2 < nk) {
      int ko = (kt + 2) * 32;
      gload16(ga + (size_t)r0 * K + ko + cs, &As[prv][t * 8]);
      gload16(ga + (size_t)(r0 + 64) * K + ko + cs, &As[prv][(t + 256) * 8]);
      gload16(gb + (size_t)r0 * K + ko + cs, &Bs[prv][t * 8]);
      gload16(gb + (size_t)(r0 + 64) * K + ko + cs, &Bs[prv][(t + 256) * 8]);
    }
    __builtin_amdgcn_sched_barrier(0);
    const char* Ab = (const char*)As[cur];
    const char* Bb = (const char*)Bs[cur];
    bf16x8 af[4], bfr[4];
#pragma unroll
    for (int i = 0; i < 4; ++i)
      af[i] = *reinterpret_cast<const bf16x8*>(
          Ab + (((wr * 64 + i * 16 + lr) * 64 + g4 * 16) ^ xorR));
#pragma unroll
    for (int j = 0; j < 4; ++j)
      bfr[j] = *reinterpret_cast<const bf16x8*>(
          Bb + (((wc * 64 + j * 16 + lr) * 64 + g4 * 16) ^ xorR));
#pragma unroll
    for (int i = 0; i < 4; ++i)
#pragma unroll
      for (int j = 0; j < 4; ++j)
        acc[i][j] = __builtin_amdgcn_mfma_f32_16x16x32_bf16(af[i], bfr[j], acc[i][j], 0, 0, 0);
    prv = cur;
    cur = (cur == 2) ? 0 : cur + 1;
  }

  int rbase = bm * 128 + wr * 64;
  int cbase = bn * 128 + wc * 64;
#pragma unroll
  for (int i = 0; i < 4; ++i) {
#pragma unroll
    for (int r = 0; r < 4; ++r) {
      int row = rbase + i * 16 + g4 * 4 + r;
#pragma unroll
      for (int j = 0; j < 4; ++j) {
        int col = cbase + j * 16 + lr;
        float v = acc[i][j][r] + bias[col];
        if (EPI == 0) {
          if (col < NE) v *= QSCALE;   // Q pre-scale for exp2-domain softmax
          ((short*)Cout)[(size_t)row * N + col] = f2bf(v);
        } else if (EPI == 1) {
          ((short*)Cout)[(size_t)row * N + col] = f2bf(gelu_fast(v));
        } else {
          ((float*)Cout)[(size_t)row * N + col] = v + resid[(size_t)row * N + col];
        }
      }
    }
  }
}

// ---------------- causal flash attention, QBLK=64, KVBLK=64, dbuf -----------
__global__ __launch_bounds__(256, 4) void attn_kernel(
    const short* __restrict__ qkv, const short* __restrict__ vt,
    short* __restrict__ y) {
  __shared__ short Ks[2][64 * 64];   // [kpos][hd], XOR-swizzled
  __shared__ short Vs[2][64 * 64];   // [hd][kpos], XOR-swizzled
  int t = threadIdx.x, w = t >> 6, l = t & 63;
  int lr = l & 15, g = l >> 4, lkb = g * 8;
  int bh = blockIdx.x;               // XCD = bh % 8 (48 % 8 == 0)
  int b = bh / NH, h = bh % NH;
  int qt = ((int)gridDim.y - 1) - blockIdx.y;   // longest blocks first
  int qbase = qt * 64;
  const int rstride = 3 * NE;

  const short* qrow = qkv + (size_t)(b * TT + qbase + w * 16 + lr) * rstride + h * HD + lkb;
  bf16x8 qf0 = *reinterpret_cast<const bf16x8*>(qrow);
  bf16x8 qf1 = *reinterpret_cast<const bf16x8*>(qrow + 32);

  f32x4 o[4];
#pragma unroll
  for (int j = 0; j < 4; ++j) o[j] = (f32x4){0.f, 0.f, 0.f, 0.f};
  float m_run = -3e38f, l_run = 0.f;

  int ci0 = t, ci1 = t + 256;
  int row0 = ci0 >> 3, c0 = ((ci0 & 7) ^ (row0 & 7)) * 8;
  int row1 = ci1 >> 3, c1 = ((ci1 & 7) ^ (row1 & 7)) * 8;

  const short* kbase = qkv + (size_t)(b * TT) * rstride + NE + h * HD;
  const short* vtb = vt + (size_t)bh * HD * TT;

  gload16(kbase + (size_t)row0 * rstride + c0, &Ks[0][ci0 * 8]);
  gload16(kbase + (size_t)row1 * rstride + c1, &Ks[0][ci1 * 8]);
  gload16(vtb + (size_t)row0 * TT + c0, &Vs[0][ci0 * 8]);
  gload16(vtb + (size_t)row1 * TT + c1, &Vs[0][ci1 * 8]);

  int qmin = qbase + w * 16;
  int srcA = ((g & 1) * 2) * 16 + lr;
  int srcB = srcA + 16;
  bool ghi = (g >= 2);

  int nkv = qt + 1;
  for (int kt = 0; kt < nkv; ++kt) {
    int bi = kt & 1;
    int kvbase = kt * 64;
    bool pre = (kt + 1 < nkv);
    __syncthreads();

    if (pre) {
      int nb = kvbase + 64;
      gload16(kbase + (size_t)(nb + row0) * rstride + c0, &Ks[bi ^ 1][ci0 * 8]);
      gload16(kbase + (size_t)(nb + row1) * rstride + c1, &Ks[bi ^ 1][ci1 * 8]);
      gload16(vtb + (size_t)row0 * TT + nb + c0, &Vs[bi ^ 1][ci0 * 8]);
      gload16(vtb + (size_t)row1 * TT + nb + c1, &Vs[bi ^ 1][ci1 * 8]);
    }

    f32x4 s[4];
#pragma unroll
    for (int nt = 0; nt < 4; ++nt) {
      int row = nt * 16 + lr;
      bf16x8 kf0 = *reinterpret_cast<const bf16x8*>(
          (char*)Ks[bi] + ((row * 128 + lkb * 2) ^ ((lr & 7) << 4)));
      bf16x8 kf1 = *reinterpret_cast<const bf16x8*>(
          (char*)Ks[bi] + ((row * 128 + 64 + lkb * 2) ^ ((lr & 7) << 4)));
      f32x4 st = (f32x4){0.f, 0.f, 0.f, 0.f};
      st = __builtin_amdgcn_mfma_f32_16x16x32_bf16(kf0, qf0, st, 0, 0, 0);
      st = __builtin_amdgcn_mfma_f32_16x16x32_bf16(kf1, qf1, st, 0, 0, 0);
      s[nt] = st;
    }

    if (kvbase + 63 > qmin) {
      int qabs = qmin + lr;
#pragma unroll
      for (int nt = 0; nt < 4; ++nt)
#pragma unroll
        for (int r = 0; r < 4; ++r) {
          int kp = kvbase + nt * 16 + g * 4 + r;
          s[nt][r] = (kp <= qabs) ? s[nt][r] : -3e38f;
        }
    }

    float mx = s[0][0];
#pragma unroll
    for (int nt = 0; nt < 4; ++nt)
#pragma unroll
      for (int r = 0; r < 4; ++r) mx = fmaxf(mx, s[nt][r]);
    mx = fmaxf(mx, __shfl_xor(mx, 16));
    mx = fmaxf(mx, __shfl_xor(mx, 32));
    if (__any(mx > m_run + 11.54f)) {
      float mn = fmaxf(m_run, mx);
      float al = exp2fast(m_run - mn);
      m_run = mn;
      l_run *= al;
      float al0 = __shfl(al, g * 4 + 0);
      float al1 = __shfl(al, g * 4 + 1);
      float al2 = __shfl(al, g * 4 + 2);
      float al3 = __shfl(al, g * 4 + 3);
#pragma unroll
      for (int j = 0; j < 4; ++j) {
        o[j][0] *= al0; o[j][1] *= al1; o[j][2] *= al2; o[j][3] *= al3;
      }
    }
    float rs = 0.f;
#pragma unroll
    for (int nt = 0; nt < 4; ++nt)
#pragma unroll
      for (int r = 0; r < 4; ++r) {
        float p = exp2fast(s[nt][r] - m_run);
        s[nt][r] = p;
        rs += p;
      }
    rs += __shfl_xor(rs, 16);
    rs += __shfl_xor(rs, 32);
    l_run += rs;

    unsigned int pw[4][2];
#pragma unroll
    for (int nt = 0; nt < 4; ++nt)
#pragma unroll
      for (int pr = 0; pr < 2; ++pr)
        pw[nt][pr] = cvtpk(s[nt][2 * pr], s[nt][2 * pr + 1]);

#pragma unroll
    for (int c = 0; c < 2; ++c) {
      unsigned int a00 = __shfl(pw[c * 2 + 0][0], srcA);
      unsigned int a01 = __shfl(pw[c * 2 + 0][1], srcA);
      unsigned int a02 = __shfl(pw[c * 2 + 0][0], srcB);
      unsigned int a03 = __shfl(pw[c * 2 + 0][1], srcB);
      unsigned int a10 = __shfl(pw[c * 2 + 1][0], srcA);
      unsigned int a11 = __shfl(pw[c * 2 + 1][1], srcA);
      unsigned int a12 = __shfl(pw[c * 2 + 1][0], srcB);
      unsigned int a13 = __shfl(pw[c * 2 + 1][1], srcB);
      union { unsigned int u[4]; bf16x8 v; } pau;
      pau.u[0] = ghi ? a10 : a00;
      pau.u[1] = ghi ? a11 : a01;
      pau.u[2] = ghi ? a12 : a02;
      pau.u[3] = ghi ? a13 : a03;
#pragma unroll
      for (int j = 0; j < 4; ++j) {
        int vrow = j * 16 + lr;
        bf16x8 vf = *reinterpret_cast<const bf16x8*>(
            (char*)Vs[bi] + ((vrow * 128 + c * 64 + lkb * 2) ^ ((lr & 7) << 4)));
        o[j] = __builtin_amdgcn_mfma_f32_16x16x32_bf16(pau.v, vf, o[j], 0, 0, 0);
      }
    }
  }

  float inv = 1.0f / l_run;
  float i0 = __shfl(inv, g * 4 + 0);
  float i1 = __shfl(inv, g * 4 + 1);
  float i2 = __shfl(inv, g * 4 + 2);
  float i3 = __shfl(inv, g * 4 + 3);
#pragma unroll
  for (int r = 0; r < 4; ++r) {
    float ir = (r == 0) ? i0 : (r == 1) ? i1 : (r == 2) ? i2 : i3;
    size_t row = (size_t)(b * TT + qbase + w * 16 + g * 4 + r);
#pragma unroll
    for (int j = 0; j < 4; ++j)
      y[row * NE + h * HD + j * 16 + lr] = f2bf(o[j][r] * ir);
  }
}

extern "C" void kernel_launch(void* const* d_in, const int* in_sizes, int n_in,
                              void* d_out, int out_size, void* d_ws, size_t ws_size,
                              hipStream_t stream) {
  (void)in_sizes; (void)n_in; (void)out_size; (void)ws_size;
  const float* x       = (const float*)d_in[0];
  const float* ln1_g   = (const float*)d_in[1];
  const float* ln1_b   = (const float*)d_in[2];
  const float* w_attn  = (const float*)d_in[3];
  const float* b_attn  = (const float*)d_in[4];
  const float* w_aproj = (const float*)d_in[5];
  const float* b_aproj = (const float*)d_in[6];
  const float* ln2_g   = (const float*)d_in[7];
  const float* ln2_b   = (const float*)d_in[8];
  const float* w_fc    = (const float*)d_in[9];
  const float* b_fc    = (const float*)d_in[10];
  const float* w_mproj = (const float*)d_in[11];
  const float* b_mproj = (const float*)d_in[12];

  char* ws = (char*)d_ws;
  size_t off = 0;
  auto alloc = [&](size_t bytes) {
    char* p = ws + off;
    off += (bytes + 255) & ~(size_t)255;
    return p;
  };
  short* wt_attn  = (short*)alloc((size_t)2304 * 768 * 2);
  short* wt_aproj = (short*)alloc((size_t)768 * 768 * 2);
  short* wt_fc    = (short*)alloc((size_t)3072 * 768 * 2);
  short* wt_mproj = (short*)alloc((size_t)768 * 3072 * 2);
  short* lnb  = (short*)alloc((size_t)ROWS * 768 * 2);
  short* qkvb = (short*)alloc((size_t)ROWS * 3072 * 2);
  short* yb   = (short*)alloc((size_t)ROWS * 768 * 2);
  float* x2   = (float*)alloc((size_t)ROWS * 768 * 4);
  short* vtg = lnb;  // aliases dead lnb between qkv-GEMM and ln2

  wtrans_all_kernel<<<1728, 256, 0, stream>>>(
      w_attn, w_aproj, w_fc, w_mproj, wt_attn, wt_aproj, wt_fc, wt_mproj);

  ln_kernel<<<ROWS, 64, 0, stream>>>(x, ln1_g, ln1_b, lnb);
  gemm_kernel<0><<<64 * 18, 256, 0, stream>>>(
      lnb, wt_attn, b_attn, nullptr, qkvb, ROWS, 2304, 768, 18);
  vtrans_kernel<<<dim3(BB * NH, TT / 64), 256, 0, stream>>>(qkvb, vtg);
  attn_kernel<<<dim3(BB * NH, TT / 64), 256, 0, stream>>>(qkvb, vtg, yb);
  gemm_kernel<2><<<64 * 6, 256, 0, stream>>>(
      yb, wt_aproj, b_aproj, x, x2, ROWS, 768, 768, 6);
  ln_kernel<<<ROWS, 64, 0, stream>>>(x2, ln2_g, ln2_b, lnb);
  gemm_kernel<1><<<64 * 24, 256, 0, stream>>>(
      lnb, wt_fc, b_fc, nullptr, qkvb, ROWS, 3072, 768, 24);
  gemm_kernel<2><<<64 * 6, 256, 0, stream>>>(
      qkvb, wt_mproj, b_mproj, x2, (float*)d_out, ROWS, 768, 3072, 6);
}